// Round 2
// baseline (3161.713 us; speedup 1.0000x reference)
//
#include <hip/hip_runtime.h>
#include <cstdint>
#include <cstddef>

// ---------------- model constants ----------------
#define BSZ   64
#define L_IN  168
#define S1    222
#define SKV   390
#define DM    512
#define HD    768
#define NHD   6
#define DK    128

typedef unsigned short u16;
typedef unsigned int u32;
typedef __attribute__((ext_vector_type(8))) short bf16x8;
typedef __attribute__((ext_vector_type(4))) float f32x4v;

// ---------------- bf16 helpers ----------------
__device__ inline float b2f(u16 u){
  union { u32 i; float f; } v; v.i = ((u32)u) << 16; return v.f;
}
__device__ inline u16 f2b(float f){
  union { float f; u32 i; } v; v.f = f;
  u32 x = v.i;
  return (u16)((x + 0x7fffu + ((x >> 16) & 1u)) >> 16);
}
__device__ inline u32 pk2(float a, float b){
  return ((u32)f2b(b) << 16) | (u32)f2b(a);
}
__device__ inline float ldv(const void* p, long long i, bool f32){
  return f32 ? ((const float*)p)[i] : b2f(((const u16*)p)[i]);
}
__device__ inline float4 ldv4(const void* p, long long i, bool f32){
  if (f32) return *(const float4*)((const float*)p + i);
  ushort4 w = *(const ushort4*)((const u16*)p + i);
  return make_float4(b2f(w.x), b2f(w.y), b2f(w.z), b2f(w.w));
}
__device__ inline bool is_f32(const u16* det){ return det[0] != 0x3F80; }
__device__ inline void unpack8(uint4 w, float* f){
  union { u32 i; float fl; } a;
  a.i = w.x << 16;          f[0] = a.fl;
  a.i = w.x & 0xffff0000u;  f[1] = a.fl;
  a.i = w.y << 16;          f[2] = a.fl;
  a.i = w.y & 0xffff0000u;  f[3] = a.fl;
  a.i = w.z << 16;          f[4] = a.fl;
  a.i = w.z & 0xffff0000u;  f[5] = a.fl;
  a.i = w.w << 16;          f[6] = a.fl;
  a.i = w.w & 0xffff0000u;  f[7] = a.fl;
}

// ---------------- workspace layout (float-equivalent offsets) ----------------
constexpr size_t OFF_ENCX = 0;
constexpr size_t OFF_DECX = OFF_ENCX + (size_t)BSZ*S1*DM;
constexpr size_t OFF_QB   = OFF_DECX + (size_t)BSZ*L_IN*DM;
constexpr size_t OFF_KB   = OFF_QB   + (size_t)BSZ*S1*HD/2;
constexpr size_t OFF_VB   = OFF_KB   + (size_t)BSZ*SKV*HD/2;
constexpr size_t OFF_NBR  = OFF_VB   + (size_t)BSZ*SKV*HD/2;
constexpr size_t OFF_ENCB = OFF_NBR  + 4096;
constexpr size_t OFF_DECB = OFF_ENCB + (size_t)BSZ*S1*DM/2;
constexpr size_t OFF_WT   = OFF_DECB + (size_t)BSZ*L_IN*DM/2;     // all-layer Wt: 8 slots x 2,097,152 u16
constexpr size_t WT_SLOT  = 2097152;                               // u16 per layer slot
constexpr size_t WS_NEED  = (OFF_WT) * 4;                          // shadow path
constexpr size_t WS_NEED2 = (OFF_WT + 8*WT_SLOT/2) * 4;            // + wt_all region

// ---------------- PAM sparsity ----------------
__device__ inline int scale_of(int i, int& ii){
  if (i < 168){ ii = i;       return 0; }
  if (i < 210){ ii = i - 168; return 1; }
  if (i < 220){ ii = i - 210; return 2; }
  ii = i - 220; return 3;
}
__device__ inline bool pam_ok(int i, int j){
  int ii, jj;
  int li = scale_of(i, ii);
  int lj = scale_of(j, jj);
  const int n[4] = {168, 42, 10, 2};
  if (li == lj){ int d = ii - jj; return (d <= 1 && d >= -1); }
  if (li == lj + 1){ int lo = ii*4, hi = (ii == n[li]-1) ? n[lj] : ii*4+4; return (jj >= lo && jj < hi); }
  if (lj == li + 1){ int lo = jj*4, hi = (jj == n[lj]-1) ? n[li] : jj*4+4; return (ii >= lo && ii < hi); }
  return false;
}
__global__ void build_nbr_kernel(int* __restrict__ nbr){
  int q = blockIdx.x * 256 + threadIdx.x;
  if (q >= S1) return;
  int cnt = 0;
  int list[12];
  for (int j = 0; j < S1; ++j)
    if (pam_ok(q, j) && cnt < 12) list[cnt++] = j;
  #pragma unroll
  for (int t = 0; t < 12; ++t) nbr[q*12 + t] = (t < cnt) ? list[t] : -1;
}

// ---------------- embedding: register-resident weights, grid-stride rows ----
__global__ __launch_bounds__(256)
void embed_fast(const void* __restrict__ x, const void* __restrict__ t,
                const void* __restrict__ cw, const void* __restrict__ tw,
                const void* __restrict__ tb, const u16* __restrict__ det,
                float* __restrict__ out, u16* __restrict__ out2)
{
  bool f32 = is_f32(det);
  int d0 = threadIdx.x;
  int d1 = threadIdx.x + 256;

  float w0[21], w1[21];
  #pragma unroll
  for (int i = 0; i < 21; ++i){
    w0[i] = ldv(cw, (long long)d0*21 + i, f32);
    w1[i] = ldv(cw, (long long)d1*21 + i, f32);
  }
  float tw0[4], tw1[4];
  #pragma unroll
  for (int f = 0; f < 4; ++f){
    tw0[f] = ldv(tw, (long long)f*DM + d0, f32);
    tw1[f] = ldv(tw, (long long)f*DM + d1, f32);
  }
  float tb0 = ldv(tb, d0, f32);
  float tb1 = ldv(tb, d1, f32);
  float dv0 = __expf(-(float)(d0 & ~1) * (9.210340371976184f/512.f));
  float dv1 = __expf(-(float)(d1 & ~1) * (9.210340371976184f/512.f));
  bool odd0 = (d0 & 1), odd1 = (d1 & 1);

  const int nRows = BSZ * L_IN;
  for (int row = blockIdx.x; row < nRows; row += gridDim.x){
    int b = row / L_IN, l = row - b*L_IN;
    float acc0 = 0.f, acc1 = 0.f;
    #pragma unroll
    for (int tt = 0; tt < 3; ++tt){
      int ls = l + tt - 1;
      ls = (ls < 0) ? ls + L_IN : (ls >= L_IN ? ls - L_IN : ls);
      long long xo = ((long long)(b*L_IN + ls))*7;
      #pragma unroll
      for (int c = 0; c < 7; ++c){
        float xv = ldv(x, xo + c, f32);
        acc0 += xv * w0[c*3 + tt];
        acc1 += xv * w1[c*3 + tt];
      }
    }
    float ang0 = (float)l * dv0;
    float ang1 = (float)l * dv1;
    acc0 += odd0 ? __cosf(ang0) : __sinf(ang0);
    acc1 += odd1 ? __cosf(ang1) : __sinf(ang1);
    long long to = ((long long)row)*4;
    #pragma unroll
    for (int f = 0; f < 4; ++f){
      float tv = ldv(t, to + f, f32);
      acc0 += tv * tw0[f];
      acc1 += tv * tw1[f];
    }
    acc0 += tb0;
    acc1 += tb1;
    size_t o = (size_t)row*DM;
    out[o + d0] = acc0;
    out[o + d1] = acc1;
    if (out2){
      out2[o + d0] = f2b(acc0);
      out2[o + d1] = f2b(acc1);
    }
  }
}

// ---------------- weight transpose helpers ----------------
__device__ inline void trans32(const void* W, long long wOff, int K, int N, int k0, int n0,
                               u16* __restrict__ Wt, bool f32, float* tb, int tid)
{
  int c = tid & 31, r0 = tid >> 5;
  #pragma unroll
  for (int rr = 0; rr < 32; rr += 8)
    tb[(r0+rr)*33 + c] = ldv(W, wOff + (long long)(k0+r0+rr)*N + n0 + c, f32);
  __syncthreads();
  #pragma unroll
  for (int rr = 0; rr < 32; rr += 8)
    Wt[(size_t)(n0+r0+rr)*K + k0 + c] = f2b(tb[c*33 + r0+rr]);
}

__device__ inline void wt_layer_body(int t, const void* wq, const void* wk, const void* wv,
                                     const void* wo, const void* w1, const void* w2,
                                     long long wO, long long oO, long long fO,
                                     u16* Wt3, u16* WtO, u16* Wt1, u16* Wt2,
                                     bool f32, float* tb, int tid)
{
  if (t < 384)       trans32(wq, wO, 512, 768, (t/24)*32, (t%24)*32, Wt3,               f32, tb, tid);
  else if (t < 768)  { int u = t-384;  trans32(wk, wO, 512, 768, (u/24)*32, (u%24)*32, Wt3 + (size_t)768*512,  f32, tb, tid); }
  else if (t < 1152) { int u = t-768;  trans32(wv, wO, 512, 768, (u/24)*32, (u%24)*32, Wt3 + (size_t)1536*512, f32, tb, tid); }
  else if (t < 1536) { int u = t-1152; trans32(wo, oO, 768, 512, (u/16)*32, (u%16)*32, WtO, f32, tb, tid); }
  else if (t < 1792) { int u = t-1536; trans32(w1, fO, 512, 512, (u/16)*32, (u%16)*32, Wt1, f32, tb, tid); }
  else               { int u = t-1792; trans32(w2, fO, 512, 512, (u/16)*32, (u%16)*32, Wt2, f32, tb, tid); }
}

// per-layer fallback
__global__ __launch_bounds__(256)
void wt_batch(const void* wq, const void* wk, const void* wv,
              const void* wo, const void* w1, const void* w2,
              long long wO, long long oO, long long fO,
              u16* __restrict__ Wt3, u16* __restrict__ WtO,
              u16* __restrict__ Wt1, u16* __restrict__ Wt2,
              const u16* __restrict__ det)
{
  __shared__ float tb[32*33];
  bool f32 = is_f32(det);
  wt_layer_body(blockIdx.x, wq, wk, wv, wo, w1, w2, wO, oO, fO, Wt3, WtO, Wt1, Wt2,
                f32, tb, threadIdx.x);
}

// all 8 layers in one launch: slots 0..5 = enc layers, 6..7 = dec layers
__global__ __launch_bounds__(256)
void wt_all(const void* ewq, const void* ewk, const void* ewv, const void* ewo,
            const void* ew1, const void* ew2,
            const void* dwq, const void* dwk, const void* dwv, const void* dwo,
            const void* dw1, const void* dw2,
            u16* __restrict__ WtAll, const u16* __restrict__ det)
{
  __shared__ float tb[32*33];
  bool f32 = is_f32(det);
  int s = blockIdx.x >> 11;
  int t = blockIdx.x & 2047;
  bool enc = s < 6;
  int li = enc ? s : s - 6;
  long long wO = (long long)li*512*768, oO = (long long)li*768*512, fO = (long long)li*512*512;
  u16* base = WtAll + (size_t)s*WT_SLOT;
  wt_layer_body(t,
                enc ? ewq : dwq, enc ? ewk : dwk, enc ? ewv : dwv,
                enc ? ewo : dwo, enc ? ew1 : dw1, enc ? ew2 : dw2,
                wO, oO, fO,
                base, base + (size_t)2304*512,
                base + (size_t)2304*512 + (size_t)512*768,
                base + (size_t)2304*512 + (size_t)512*768 + (size_t)512*512,
                f32, tb, threadIdx.x);
}

// ---------------- XCD-exclusive row-panel swizzle ----------------
__device__ inline bool swz(int t, int RP, int CP, int rpx, int& row0, int& col0){
  int xcd = t & 7, j = t >> 3;
  int rp = xcd + 8*(j % rpx);
  int cp = j / rpx;
  if (rp >= RP || cp >= CP) return false;
  row0 = rp*128; col0 = cp*128;
  return true;
}

// ---------------- MFMA GEMM: C = A[M,K] @ W via Wt bf16 [N,K] ----------------
template<int EPI, int ABF, int CBF>
__global__ __launch_bounds__(256)
void gemm_mfma(const void* __restrict__ Av, const u16* __restrict__ Wt,
               const void* __restrict__ bias, long long bOff, const float* __restrict__ R,
               void* __restrict__ Cv, const u16* __restrict__ det,
               int K, int N, int La, int Lc, int off, int RP, int CP, int rpx)
{
  __shared__ u16 As[128][64];
  __shared__ u16 Bs[128][64];
  bool f32 = is_f32(det);
  int tid = threadIdx.x;
  int row0, col0;
  if (!swz(blockIdx.x, RP, CP, rpx, row0, col0)) return;
  int wave = tid >> 6, lane = tid & 63;
  int wm = (wave >> 1)*64, wn = (wave & 1)*64;
  int lm = lane & 15, quad = lane >> 4;
  int sr = tid >> 1;
  int sh = (tid & 1) * 32;
  int swzS = (sr & 7) * 8;
  f32x4v acc[4][4];
  #pragma unroll
  for (int i = 0; i < 4; ++i)
    #pragma unroll
    for (int j = 0; j < 4; ++j) acc[i][j] = (f32x4v){0.f,0.f,0.f,0.f};

  for (int k0 = 0; k0 < K; k0 += 64){
    if (ABF){
      const u16* src = (const u16*)Av + (size_t)(row0+sr)*K + k0 + sh;
      uint4 v0 = *(const uint4*)(src+0);
      uint4 v1 = *(const uint4*)(src+8);
      uint4 v2 = *(const uint4*)(src+16);
      uint4 v3 = *(const uint4*)(src+24);
      *(uint4*)&As[sr][(sh+0)^swzS]  = v0;
      *(uint4*)&As[sr][(sh+8)^swzS]  = v1;
      *(uint4*)&As[sr][(sh+16)^swzS] = v2;
      *(uint4*)&As[sr][(sh+24)^swzS] = v3;
    } else {
      const float* src = (const float*)Av + (size_t)(row0+sr)*K + k0 + sh;
      #pragma unroll
      for (int j = 0; j < 4; ++j){
        float4 f0 = *(const float4*)(src + 8*j);
        float4 f1 = *(const float4*)(src + 8*j + 4);
        uint4 o;
        o.x = pk2(f0.x, f0.y); o.y = pk2(f0.z, f0.w);
        o.z = pk2(f1.x, f1.y); o.w = pk2(f1.z, f1.w);
        *(uint4*)&As[sr][(sh + 8*j)^swzS] = o;
      }
    }
    {
      const u16* src = Wt + (size_t)(col0+sr)*K + k0 + sh;
      uint4 v0 = *(const uint4*)(src+0);
      uint4 v1 = *(const uint4*)(src+8);
      uint4 v2 = *(const uint4*)(src+16);
      uint4 v3 = *(const uint4*)(src+24);
      *(uint4*)&Bs[sr][(sh+0)^swzS]  = v0;
      *(uint4*)&Bs[sr][(sh+8)^swzS]  = v1;
      *(uint4*)&Bs[sr][(sh+16)^swzS] = v2;
      *(uint4*)&Bs[sr][(sh+24)^swzS] = v3;
    }
    __syncthreads();
    bf16x8 af[4][2], bfr[4][2];
    #pragma unroll
    for (int mi = 0; mi < 4; ++mi){
      int m = wm + mi*16 + lm;
      int sz = (m & 7)*8;
      af[mi][0] = *(const bf16x8*)&As[m][(quad*8) ^ sz];
      af[mi][1] = *(const bf16x8*)&As[m][(32 + quad*8) ^ sz];
    }
    #pragma unroll
    for (int ni = 0; ni < 4; ++ni){
      int n = wn + ni*16 + lm;
      int sz = (n & 7)*8;
      bfr[ni][0] = *(const bf16x8*)&Bs[n][(quad*8) ^ sz];
      bfr[ni][1] = *(const bf16x8*)&Bs[n][(32 + quad*8) ^ sz];
    }
    #pragma unroll
    for (int mi = 0; mi < 4; ++mi)
      #pragma unroll
      for (int ni = 0; ni < 4; ++ni){
        acc[mi][ni] = __builtin_amdgcn_mfma_f32_16x16x32_bf16(af[mi][0], bfr[ni][0], acc[mi][ni], 0, 0, 0);
        acc[mi][ni] = __builtin_amdgcn_mfma_f32_16x16x32_bf16(af[mi][1], bfr[ni][1], acc[mi][ni], 0, 0, 0);
      }
    __syncthreads();
  }
  #pragma unroll
  for (int mi = 0; mi < 4; ++mi){
    #pragma unroll
    for (int r = 0; r < 4; ++r){
      int row = row0 + wm + mi*16 + quad*4 + r;
      int bb = row / La, l = row - bb*La;
      size_t crow = ((size_t)bb*Lc + off + l)*(size_t)N;
      #pragma unroll
      for (int ni = 0; ni < 4; ++ni){
        int col = col0 + wn + ni*16 + lm;
        float vv = acc[mi][ni][r] + ldv(bias, bOff + col, f32);
        if (EPI == 1) vv = 0.5f*vv*(1.f + erff(vv*0.70710678118654752f));
        if (EPI == 2) vv += R[crow + col];
        if (CBF) ((u16*)Cv)[crow + col] = f2b(vv);
        else     ((float*)Cv)[crow + col] = vv;
      }
    }
  }
}

// ---------------- fused QKV / KV MFMA GEMM (K=512), swizzled ----------------
template<int ABF>
__global__ __launch_bounds__(256)
void gemm_qkv(const void* __restrict__ Av, const u16* __restrict__ Wt,
              const void* __restrict__ b0, const void* __restrict__ b1, const void* __restrict__ b2,
              long long bOff, u16* __restrict__ o0, u16* __restrict__ o1, u16* __restrict__ o2,
              const u16* __restrict__ det, int La, int Lc, int off, int RP, int CP, int rpx)
{
  __shared__ u16 As[128][64];
  __shared__ u16 Bs[128][64];
  bool f32 = is_f32(det);
  const int K = 512;
  int tid = threadIdx.x;
  int row0, col0;
  if (!swz(blockIdx.x, RP, CP, rpx, row0, col0)) return;
  int wave = tid >> 6, lane = tid & 63;
  int wm = (wave >> 1)*64, wn = (wave & 1)*64;
  int lm = lane & 15, quad = lane >> 4;
  int sr = tid >> 1;
  int sh = (tid & 1) * 32;
  int swzS = (sr & 7) * 8;
  f32x4v acc[4][4];
  #pragma unroll
  for (int i = 0; i < 4; ++i)
    #pragma unroll
    for (int j = 0; j < 4; ++j) acc[i][j] = (f32x4v){0.f,0.f,0.f,0.f};

  for (int k0 = 0; k0 < K; k0 += 64){
    if (ABF){
      const u16* src = (const u16*)Av + (size_t)(row0+sr)*K + k0 + sh;
      uint4 v0 = *(const uint4*)(src+0);
      uint4 v1 = *(const uint4*)(src+8);
      uint4 v2 = *(const uint4*)(src+16);
      uint4 v3 = *(const uint4*)(src+24);
      *(uint4*)&As[sr][(sh+0)^swzS]  = v0;
      *(uint4*)&As[sr][(sh+8)^swzS]  = v1;
      *(uint4*)&As[sr][(sh+16)^swzS] = v2;
      *(uint4*)&As[sr][(sh+24)^swzS] = v3;
    } else {
      const float* src = (const float*)Av + (size_t)(row0+sr)*K + k0 + sh;
      #pragma unroll
      for (int j = 0; j < 4; ++j){
        float4 f0 = *(const float4*)(src + 8*j);
        float4 f1 = *(const float4*)(src + 8*j + 4);
        uint4 o;
        o.x = pk2(f0.x, f0.y); o.y = pk2(f0.z, f0.w);
        o.z = pk2(f1.x, f1.y); o.w = pk2(f1.z, f1.w);
        *(uint4*)&As[sr][(sh + 8*j)^swzS] = o;
      }
    }
    {
      const u16* src = Wt + (size_t)(col0+sr)*K + k0 + sh;
      uint4 v0 = *(const uint4*)(src+0);
      uint4 v1 = *(const uint4*)(src+8);
      uint4 v2 = *(const uint4*)(src+16);
      uint4 v3 = *(const uint4*)(src+24);
      *(uint4*)&Bs[sr][(sh+0)^swzS]  = v0;
      *(uint4*)&Bs[sr][(sh+8)^swzS]  = v1;
      *(uint4*)&Bs[sr][(sh+16)^swzS] = v2;
      *(uint4*)&Bs[sr][(sh+24)^swzS] = v3;
    }
    __syncthreads();
    bf16x8 af[4][2], bfr[4][2];
    #pragma unroll
    for (int mi = 0; mi < 4; ++mi){
      int m = wm + mi*16 + lm;
      int sz = (m & 7)*8;
      af[mi][0] = *(const bf16x8*)&As[m][(quad*8) ^ sz];
      af[mi][1] = *(const bf16x8*)&As[m][(32 + quad*8) ^ sz];
    }
    #pragma unroll
    for (int ni = 0; ni < 4; ++ni){
      int n = wn + ni*16 + lm;
      int sz = (n & 7)*8;
      bfr[ni][0] = *(const bf16x8*)&Bs[n][(quad*8) ^ sz];
      bfr[ni][1] = *(const bf16x8*)&Bs[n][(32 + quad*8) ^ sz];
    }
    #pragma unroll
    for (int mi = 0; mi < 4; ++mi)
      #pragma unroll
      for (int ni = 0; ni < 4; ++ni){
        acc[mi][ni] = __builtin_amdgcn_mfma_f32_16x16x32_bf16(af[mi][0], bfr[ni][0], acc[mi][ni], 0, 0, 0);
        acc[mi][ni] = __builtin_amdgcn_mfma_f32_16x16x32_bf16(af[mi][1], bfr[ni][1], acc[mi][ni], 0, 0, 0);
      }
    __syncthreads();
  }
  #pragma unroll
  for (int mi = 0; mi < 4; ++mi){
    #pragma unroll
    for (int r = 0; r < 4; ++r){
      int row = row0 + wm + mi*16 + quad*4 + r;
      int bb = row / La, l = row - bb*La;
      size_t crow = ((size_t)bb*Lc + off + l)*(size_t)HD;
      #pragma unroll
      for (int ni = 0; ni < 4; ++ni){
        int col = col0 + wn + ni*16 + lm;
        int sel = (col >= 1536) ? 2 : (col >= 768 ? 1 : 0);
        int colr = col - sel*768;
        const void* bp = (sel == 0) ? b0 : (sel == 1) ? b1 : b2;
        u16* dst = (sel == 0) ? o0 : (sel == 1) ? o1 : o2;
        float vv = acc[mi][ni][r] + ldv(bp, bOff + colr, f32);
        dst[crow + colr] = f2b(vv);
      }
    }
  }
}

// ---------------- SIMT GEMM (bottleneck) ----------------
#define BM 64
#define BN 64
#define BK 16
__global__ __launch_bounds__(256)
void gemm_k(const float* __restrict__ A, const void* __restrict__ W, long long wOff,
            const void* __restrict__ bias, long long bOff,
            float* __restrict__ C, const u16* __restrict__ det, int K, int N)
{
  __shared__ float As2[BK][BM+4];
  __shared__ float Bs2[BK][BN+4];
  bool f32 = is_f32(det);
  int tid = threadIdx.x;
  int row0 = blockIdx.y * BM, col0 = blockIdx.x * BN;
  int ty = tid >> 4, tx = tid & 15;
  int lr = tid >> 2, lc4 = (tid & 3) << 2;
  int wr = tid >> 4, wc4 = (tid & 15) << 2;
  float acc[4][4] = {};
  for (int k0 = 0; k0 < K; k0 += BK){
    float4 av = *(const float4*)(A + (size_t)(row0 + lr)*K + k0 + lc4);
    As2[lc4+0][lr] = av.x; As2[lc4+1][lr] = av.y;
    As2[lc4+2][lr] = av.z; As2[lc4+3][lr] = av.w;
    float4 wv = ldv4(W, wOff + (long long)(k0 + wr)*N + col0 + wc4, f32);
    *(float4*)&Bs2[wr][wc4] = wv;
    __syncthreads();
    #pragma unroll
    for (int kk = 0; kk < BK; ++kk){
      float4 a  = *(const float4*)&As2[kk][ty << 2];
      float4 bb = *(const float4*)&Bs2[kk][tx << 2];
      acc[0][0] += a.x*bb.x; acc[0][1] += a.x*bb.y; acc[0][2] += a.x*bb.z; acc[0][3] += a.x*bb.w;
      acc[1][0] += a.y*bb.x; acc[1][1] += a.y*bb.y; acc[1][2] += a.y*bb.z; acc[1][3] += a.y*bb.w;
      acc[2][0] += a.z*bb.x; acc[2][1] += a.z*bb.y; acc[2][2] += a.z*bb.z; acc[2][3] += a.z*bb.w;
      acc[3][0] += a.w*bb.x; acc[3][1] += a.w*bb.y; acc[3][2] += a.w*bb.z; acc[3][3] += a.w*bb.w;
    }
    __syncthreads();
  }
  #pragma unroll
  for (int i = 0; i < 4; ++i){
    int r = row0 + (ty << 2) + i;
    size_t crow = (size_t)r*(size_t)N;
    #pragma unroll
    for (int j = 0; j < 4; ++j){
      int c = col0 + (tx << 2) + j;
      C[crow + c] = acc[i][j] + ldv(bias, bOff + c, f32);
    }
  }
}

// ---------------- conv weight reorder ----------------
__global__ void wc_kernel(const void* __restrict__ w, float* __restrict__ Wc,
                          const u16* __restrict__ det)
{
  bool f32 = is_f32(det);
  int idx = blockIdx.x * 256 + threadIdx.x;
  if (idx >= 3*512*128) return;
  int co = idx & 127;
  int kk = (idx >> 7) & 511;
  int lay = idx >> 16;
  int tt = kk >> 7, ci = kk & 127;
  Wc[idx] = ldv(w, (long long)lay*65536 + co*512 + ci*4 + tt, f32);
}

// ---------------- bottleneck conv as GEMM + BN + ELU ----------------
__global__ __launch_bounds__(256)
void conv_gemm(const float* __restrict__ in, int inStride, int inOff,
               float* __restrict__ out, int outStride, int outOff, int Lout,
               const float* __restrict__ Wc,
               const void* __restrict__ cb, const void* __restrict__ bg,
               const void* __restrict__ bb, const void* __restrict__ bm,
               const void* __restrict__ bv, const u16* __restrict__ det, int lay)
{
  __shared__ float As2[BK][BM+4];
  __shared__ float Bs2[BK][BN+4];
  bool f32 = is_f32(det);
  int tid = threadIdx.x;
  int row0 = blockIdx.y * BM, col0 = blockIdx.x * BN;
  int ty = tid >> 4, tx = tid & 15;
  int lr = tid >> 2, lc4 = (tid & 3) << 2;
  int wr = tid >> 4, wc4 = (tid & 15) << 2;
  int rs = row0 + lr;
  int bs = rs / Lout, js = rs - bs*Lout;
  const float* arow = in + ((size_t)(bs*inStride + inOff + js*4))*128;
  float acc[4][4] = {};
  for (int k0 = 0; k0 < 512; k0 += BK){
    float4 av = *(const float4*)(arow + k0 + lc4);
    As2[lc4+0][lr] = av.x; As2[lc4+1][lr] = av.y;
    As2[lc4+2][lr] = av.z; As2[lc4+3][lr] = av.w;
    float4 wv = *(const float4*)(Wc + (size_t)(k0 + wr)*128 + col0 + wc4);
    *(float4*)&Bs2[wr][wc4] = wv;
    __syncthreads();
    #pragma unroll
    for (int kk = 0; kk < BK; ++kk){
      float4 a  = *(const float4*)&As2[kk][ty << 2];
      float4 bb2 = *(const float4*)&Bs2[kk][tx << 2];
      acc[0][0] += a.x*bb2.x; acc[0][1] += a.x*bb2.y; acc[0][2] += a.x*bb2.z; acc[0][3] += a.x*bb2.w;
      acc[1][0] += a.y*bb2.x; acc[1][1] += a.y*bb2.y; acc[1][2] += a.y*bb2.z; acc[1][3] += a.y*bb2.w;
      acc[2][0] += a.z*bb2.x; acc[2][1] += a.z*bb2.y; acc[2][2] += a.z*bb2.z; acc[2][3] += a.z*bb2.w;
      acc[3][0] += a.w*bb2.x; acc[3][1] += a.w*bb2.y; acc[3][2] += a.w*bb2.z; acc[3][3] += a.w*bb2.w;
    }
    __syncthreads();
  }
  #pragma unroll
  for (int i = 0; i < 4; ++i){
    int r = row0 + (ty << 2) + i;
    int b = r / Lout, j = r - b*Lout;
    float* orow = out + ((size_t)(b*outStride + outOff + j))*128;
    #pragma unroll
    for (int jj = 0; jj < 4; ++jj){
      int co = col0 + (tx << 2) + jj;
      long long po = (long long)lay*128 + co;
      float a = acc[i][jj] + ldv(cb, po, f32);
      a = (a - ldv(bm, po, f32)) * rsqrtf(ldv(bv, po, f32) + 1e-5f) * ldv(bg, po, f32) + ldv(bb, po, f32);
      a = a > 0.f ? a : (__expf(a) - 1.f);
      orow[co] = a;
    }
  }
}

// ---------------- LayerNorm (4 rows/block, optional bf16 shadow) ----------------
__global__ __launch_bounds__(256)
void ln_kernel(const float* __restrict__ X, const void* __restrict__ g, long long gOff,
               const void* __restrict__ bt, long long bOff, float eps,
               float* __restrict__ Out, u16* __restrict__ OutB, const u16* __restrict__ det)
{
  bool f32 = is_f32(det);
  int row = blockIdx.x*4 + (threadIdx.x >> 6);
  int lane = threadIdx.x & 63;
  const float* xr = X + (size_t)row*DM;
  float v[8]; float s = 0.f;
  #pragma unroll
  for (int i = 0; i < 8; ++i){ v[i] = xr[lane + i*64]; s += v[i]; }
  #pragma unroll
  for (int o = 32; o > 0; o >>= 1) s += __shfl_xor(s, o);
  float mean = s * (1.f/512.f);
  float q = 0.f;
  #pragma unroll
  for (int i = 0; i < 8; ++i){ float d = v[i]-mean; q += d*d; }
  #pragma unroll
  for (int o = 32; o > 0; o >>= 1) q += __shfl_xor(q, o);
  float inv = rsqrtf(q*(1.f/512.f) + eps);
  float* orow = Out + (size_t)row*DM;
  #pragma unroll
  for (int i = 0; i < 8; ++i){
    int c = lane + i*64;
    float val = (v[i]-mean)*inv*ldv(g, gOff + c, f32) + ldv(bt, bOff + c, f32);
    orow[c] = val;
    if (OutB) OutB[(size_t)row*DM + c] = f2b(val);
  }
}

// ---------------- concat + LayerNorm(1e-5), 4 rows/block, optional shadow ----------------
__global__ __launch_bounds__(256)
void concat_ln_kernel(const float* __restrict__ emb, const float* __restrict__ up,
                      const void* __restrict__ g, const void* __restrict__ bt,
                      float* __restrict__ Out, u16* __restrict__ OutB, const u16* __restrict__ det)
{
  bool f32 = is_f32(det);
  int row = blockIdx.x*4 + (threadIdx.x >> 6);
  int lane = threadIdx.x & 63;
  int b = row / S1, l = row - b*S1;
  const float* xr = (l < L_IN) ? emb + ((size_t)(b*L_IN + l))*DM
                               : up  + ((size_t)(b*54 + (l - L_IN)))*DM;
  float v[8]; float s = 0.f;
  #pragma unroll
  for (int i = 0; i < 8; ++i){ v[i] = xr[lane + i*64]; s += v[i]; }
  #pragma unroll
  for (int o = 32; o > 0; o >>= 1) s += __shfl_xor(s, o);
  float mean = s * (1.f/512.f);
  float q = 0.f;
  #pragma unroll
  for (int i = 0; i < 8; ++i){ float d = v[i]-mean; q += d*d; }
  #pragma unroll
  for (int o = 32; o > 0; o >>= 1) q += __shfl_xor(q, o);
  float inv = rsqrtf(q*(1.f/512.f) + 1e-5f);
  float* orow = Out + (size_t)row*DM;
  #pragma unroll
  for (int i = 0; i < 8; ++i){
    int c = lane + i*64;
    float val = (v[i]-mean)*inv*ldv(g, c, f32) + ldv(bt, c, f32);
    orow[c] = val;
    if (OutB) OutB[(size_t)row*DM + c] = f2b(val);
  }
}

// ---------------- encoder attention: PAM-sparse, 16-lane unit per (b,q,h) ----------------
__global__ __launch_bounds__(256)
void attn_enc_sparse(u16* __restrict__ q, const u16* __restrict__ k,
                     const u16* __restrict__ v, const int* __restrict__ nbr)
{
  int u = blockIdx.x * 16 + (threadIdx.x >> 4);
  int lane16 = threadIdx.x & 15;
  int h = u % NHD;
  int bq = u / NHD;
  int b = bq / S1, qr = bq - b*S1;
  const float scale = 0.088388347648318447f;
  size_t rowoff = (size_t)bq*HD + h*DK + lane16*8;
  uint4 qw = *(const uint4*)(q + rowoff);
  float qd[8]; unpack8(qw, qd);
  const int* nb = nbr + qr*12;
  size_t base = (size_t)b*S1*HD + h*DK + lane16*8;
  float pj[12];
  #pragma unroll
  for (int j = 0; j < 12; ++j){
    int kg = nb[j];
    int kgc = kg < 0 ? 0 : kg;
    uint4 kw = *(const uint4*)(k + (size_t)kgc*HD + base);
    float kd[8]; unpack8(kw, kd);
    float p = qd[0]*kd[0] + qd[1]*kd[1] + qd[2]*kd[2] + qd[3]*kd[3]
            + qd[4]*kd[4] + qd[5]*kd[5] + qd[6]*kd[6] + qd[7]*kd[7];
    p += __shfl_xor(p, 1); p += __shfl_xor(p, 2);
    p += __shfl_xor(p, 4); p += __shfl_xor(p, 8);
    pj[j] = (kg >= 0) ? p*scale : -1e30f;
  }
  float m = -1e30f;
  #pragma unroll
  for (int j = 0; j < 12; ++j) m = fmaxf(m, pj[j]);
  float s = 0.f;
  #pragma unroll
  for (int j = 0; j < 12; ++j){ pj[j] = __expf(pj[j] - m); s += pj[j]; }
  float inv = 1.f / s;
  float o[8];
  #pragma unroll
  for (int i = 0; i < 8; ++i) o[i] = 0.f;
  #pragma unroll
  for (int j = 0; j < 12; ++j){
    int kg = nb[j];
    int kgc = kg < 0 ? 0 : kg;
    uint4 vw = *(const uint4*)(v + (size_t)kgc*HD + base);
    float vd[8]; unpack8(vw, vd);
    #pragma unroll
    for (int i = 0; i < 8; ++i) o[i] += pj[j]*vd[i];
  }
  uint4 ow;
  ow.x = pk2(o[0]*inv, o[1]*inv);
  ow.y = pk2(o[2]*inv, o[3]*inv);
  ow.z = pk2(o[4]*inv, o[5]*inv);
  ow.w = pk2(o[6]*inv, o[7]*inv);
  *(uint4*)(q + rowoff) = ow;
}

// ---------------- decoder attention: MFMA flash (v2) ----------------
// Changes vs v1: Q fragments straight from global (no Qs LDS, -17.4 KB);
// V staged as u32 Vt[16][132] colpair-major (ds_write_b128, conflict-free;
// colpair p packs kv kt0+p (lo) and kt0+p+16 (hi));
// P staged as packed u32 Pls[4][16][16] (4-way instead of 8-way, half the writes).
// k-slot permutation kv = quad*4+(j>>1)+16*(j&1) is identical in P (A-op) and
// V (B-op), so the MFMA contraction is unchanged.
#define FQT 64
__global__ __launch_bounds__(256)
void attn_dec_mfma(u16* __restrict__ q, const u16* __restrict__ k,
                   const u16* __restrict__ v)
{
  __shared__ __align__(16) u16 Ks[32][136];
  __shared__ __align__(16) u32 Vt[16][132];
  __shared__ __align__(16) u32 Pls[4][16][16];
  int b = blockIdx.z, h = blockIdx.y;
  int qt0 = blockIdx.x * FQT;
  int tid = threadIdx.x;
  int wave = tid >> 6, lane = tid & 63;
  int lm = lane & 15, quad = lane >> 4;
  const float scale = 0.088388347648318447f;
  const size_t qb0 = (size_t)b*L_IN*HD + (size_t)h*DK;
  const size_t kb0 = (size_t)b*SKV*HD + (size_t)h*DK;

  // Q fragments (A-operand rows = wave*16 + lm) directly from global
  bf16x8 qf[4];
  {
    int qg = qt0 + wave*16 + lm;
    if (qg < L_IN){
      #pragma unroll
      for (int ks = 0; ks < 4; ++ks)
        qf[ks] = *(const bf16x8*)(q + qb0 + (size_t)qg*HD + ks*32 + quad*8);
    } else {
      #pragma unroll
      for (int ks = 0; ks < 4; ++ks) qf[ks] = (bf16x8){0,0,0,0,0,0,0,0};
    }
  }

  float mold[4], lsum[4];
  #pragma unroll
  for (int r = 0; r < 4; ++r){ mold[r] = -1e30f; lsum[r] = 0.f; }
  f32x4v oacc[8];
  #pragma unroll
  for (int f = 0; f < 8; ++f) oacc[f] = (f32x4v){0.f,0.f,0.f,0.f};

  int kEnd = S1 + qt0 + FQT; if (kEnd > SKV) kEnd = SKV;
  for (int kt0 = 0; kt0 < kEnd; kt0 += 32){
    __syncthreads();
    // stage K rows (row-major, conflict-free pattern)
    for (int i = tid*4; i < 32*128; i += 1024){
      int kk = i >> 7, d = i & 127;
      int kg = kt0 + kk;
      ushort4 w = make_ushort4(0,0,0,0);
      if (kg < SKV) w = *(const ushort4*)(k + kb0 + (size_t)kg*HD + d);
      *(ushort4*)&Ks[kk][d] = w;
    }
    // stage V: colpair p packs rows kt0+p (lo) and kt0+p+16 (hi); one b128 write
    for (int t2 = tid; t2 < 512; t2 += 256){
      int g = t2 & 31, p = t2 >> 5;
      int d0 = g*4;
      int kg0 = kt0 + p, kg1 = kt0 + p + 16;
      ushort4 a = make_ushort4(0,0,0,0), c = make_ushort4(0,0,0,0);
      if (kg0 < SKV) a = *(const ushort4*)(v + kb0 + (size_t)kg0*HD + d0);
      if (kg1 < SKV) c = *(const ushort4*)(v + kb0 + (size_t)kg1*HD + d0);
      uint4 o;
      o.x = (u32)a.x | ((u32)c.x << 16);
      o.y = (u32)a.y | ((u32)c.y << 16);
      o.z = (u32)a.z | ((u32)c.z << 16);
      o.w = (u32)a.w | ((u32)c.w << 16);
      *(uint4*)&Vt[p][d0] = o;
    }
    __syncthreads();
    f32x4v sacc[2];
    sacc[0] = (f32x4v){0.f,0.f,0.f,0.f};
    sacc[1] = (f32x4v){0.f,0.f,0.f,0.f};
    #pragma unroll
    for (int t = 0; t < 2; ++t)
      #pragma unroll
      for (int ks = 0; ks < 4; ++ks){
        bf16x8 kf = *(const bf16x8*)&Ks[t*16 + lm][ks*32 + quad*8];
        sacc[t] = __builtin_amdgcn_mfma_f32_16x16x32_bf16(qf[ks], kf, sacc[t], 0, 0, 0);
      }
    float p[2][4];
    #pragma unroll
    for (int r = 0; r < 4; ++r){
      int qg = qt0 + wave*16 + quad*4 + r;
      float s0, s1;
      {
        int kg = kt0 + lm;
        bool ok = (kg < SKV) && (qg < L_IN) && (kg <= S1 + qg);
        s0 = ok ? sacc[0][r]*scale : -1e30f;
      }
      {
        int kg = kt0 + 16 + lm;
        bool ok = (kg < SKV) && (qg < L_IN) && (kg <= S1 + qg);
        s1 = ok ? sacc[1][r]*scale : -1e30f;
      }
      float mn = fmaxf(s0, s1);
      #pragma unroll
      for (int o = 8; o > 0; o >>= 1) mn = fmaxf(mn, __shfl_xor(mn, o));
      float mi = fmaxf(mold[r], mn);
      float alpha = __expf(mold[r] - mi);
      mold[r] = mi;
      p[0][r] = __expf(s0 - mi);
      p[1][r] = __expf(s1 - mi);
      float rs = p[0][r] + p[1][r];
      #pragma unroll
      for (int o = 8; o > 0; o >>= 1) rs += __shfl_xor(rs, o);
      lsum[r] = lsum[r]*alpha + rs;
      #pragma unroll
      for (int f = 0; f < 8; ++f) oacc[f][r] *= alpha;
    }
    // packed P write: u32 {lo = kv kt0+lm, hi = kv kt0+16+lm}
    #pragma unroll
    for (int r = 0; r < 4; ++r)
      Pls[wave][quad*4+r][lm] = pk2(p[0][r], p[1][r]);
    bf16x8 pa = *(const bf16x8*)&Pls[wave][lm][quad*4];
    #pragma unroll
    for (int f = 0; f < 8; ++f){
      union { u32 u[4]; bf16x8 v8; } vv;
      vv.u[0] = Vt[quad*4+0][f*16 + lm];
      vv.u[1] = Vt[quad*4+1][f*16 + lm];
      vv.u[2] = Vt[quad*4+2][f*16 + lm];
      vv.u[3] = Vt[quad*4+3][f*16 + lm];
      oacc[f] = __builtin_amdgcn_mfma_f32_16x16x32_bf16(pa, vv.v8, oacc[f], 0, 0, 0);
    }
  }
  #pragma unroll
  for (int r = 0; r < 4; ++r){
    int qg = qt0 + wave*16 + quad*4 + r;
    if (qg < L_IN){
      float inv = 1.f / lsum[r];
      #pragma unroll
      for (int f = 0; f < 8; ++f)
        q[qb0 + (size_t)qg*HD + f*16 + lm] = f2b(oacc[f][r]*inv);
    }
  }
}

// ---------------- prediction head: one wave per row, shfl-reduce ----------------
__global__ __launch_bounds__(256)
void pred_kernel(const float* __restrict__ X, const void* __restrict__ w,
                 void* __restrict__ out, const u16* __restrict__ det)
{
  bool f32 = is_f32(det);
  int row = blockIdx.x*4 + (threadIdx.x >> 6);
  int lane = threadIdx.x & 63;
  if (row >= BSZ*L_IN) return;
  const float* xr = X + (size_t)row*DM;
  float a0=0.f,a1=0.f,a2=0.f,a3=0.f,a4=0.f,a5=0.f,a6=0.f;
  #pragma unroll
  for (int i = 0; i < 8; ++i){
    int kk = lane + i*64;
    float xv = xr[kk];
    long long wo = (long long)kk*7;
    a0 += xv*ldv(w, wo+0, f32);
    a1 += xv*ldv(w, wo+1, f32);
    a2 += xv*ldv(w, wo+2, f32);
    a3 += xv*ldv(w, wo+3, f32);
    a4 += xv*ldv(w, wo+4, f32);
    a5 += xv*ldv(w, wo+5, f32);
    a6 += xv*ldv(w, wo+6, f32);
  }
  #pragma unroll
  for (int o = 32; o > 0; o >>= 1){
    a0 += __shfl_xor(a0, o); a1 += __shfl_xor(a1, o); a2 += __shfl_xor(a2, o);
    a3 += __shfl_xor(a3, o); a4 += __shfl_xor(a4, o); a5 += __shfl_xor(a5, o);
    a6 += __shfl_xor(a6, o);
  }
  if (lane == 0){
    long long o0 = (long long)row*7;
    if (f32){
      float* op = (float*)out;
      op[o0+0]=a0; op[o0+1]=a1; op[o0+2]=a2; op[o0+3]=a3;
      op[o0+4]=a4; op[o0+5]=a5; op[o0+6]=a6;
    } else {
      u16* op = (u16*)out;
      op[o0+0]=f2b(a0); op[o0+1]=f2b(a1); op[o0+2]=f2b(a2); op[o0+3]=f2b(a3);
      op[o0+4]=f2b(a4); op[o0+5]=f2b(a5); op[o0+6]=f2b(a6);
    }
  }
}

// ---------------- launch ----------------
extern "C" void kernel_launch(void* const* d_in, const int* in_sizes, int n_in,
                              void* d_out, int out_size, void* d_ws, size_t ws_size,
                              hipStream_t stream)
{
  (void)in_sizes; (void)n_in; (void)out_size;
  #define IN(i) ((const void*)d_in[i])
  const u16* det = (const u16*)d_in[20];
  float* ws   = (float*)d_ws;
  float* encx = ws + OFF_ENCX;
  float* decx = ws + OFF_DECX;
  u16*   qb   = (u16*)(ws + OFF_QB);
  u16*   kb   = (u16*)(ws + OFF_KB);
  u16*   vb   = (u16*)(ws + OFF_VB);
  int*   nbr  = (int*)(ws + OFF_NBR);
  bool haveShadow = ws_size >= WS_NEED;
  bool haveWtAll  = ws_size >= WS_NEED2;
  u16*   encb = haveShadow ? (u16*)(ws + OFF_ENCB) : nullptr;
  u16*   decb = haveShadow ? (u16*)(ws + OFF_DECB) : nullptr;
  u16*   WtAll = (u16*)(ws + OFF_WT);
  // phase-disjoint aliases (fallback path + temporaries)
  float* tmp1  = ws + OFF_VB;
  u16*   WtE3f = (u16*)(ws + OFF_VB + (size_t)BSZ*S1*DM);
  u16*   WtEOf = WtE3f + (size_t)2304*512;
  u16*   WtE1f = WtEOf + (size_t)768*512;
  u16*   WtE2f = WtE1f + (size_t)512*512;
  u16*   WtD3f = (u16*)(ws + OFF_QB + (size_t)BSZ*L_IN*HD/2);
  u16*   WtDOf = WtD3f + (size_t)2304*512;
  u16*   WtD1f = WtDOf + (size_t)768*512;
  u16*   WtD2f = WtD1f + (size_t)512*512;
  u16*   tmph  = (u16*)(ws + OFF_KB);
  float* embE  = ws + OFF_VB;
  float* Wc    = ws + OFF_QB;
  float* bdown = ws + OFF_KB;
  float* bconv = bdown + (size_t)BSZ*L_IN*128;
  float* bup   = bconv + (size_t)BSZ*54*128;

  const int RPe = 111, rpxE = 14;
  const int RPd = 84,  rpxD = 11;

  build_nbr_kernel<<<1, 256, 0, stream>>>(nbr);
  if (haveWtAll)
    wt_all<<<8*2048, 256, 0, stream>>>(IN(22), IN(24), IN(26), IN(28), IN(32), IN(34),
                                       IN(38), IN(40), IN(42), IN(44), IN(48), IN(50),
                                       WtAll, det);

  embed_fast<<<1344, 256, 0, stream>>>(IN(0), IN(1), IN(4), IN(5), IN(6), det, embE, nullptr);
  embed_fast<<<1344, 256, 0, stream>>>(IN(2), IN(3), IN(7), IN(8), IN(9), det, decx, decb);

  // bottleneck
  wc_kernel<<<(3*512*128)/256, 256, 0, stream>>>(IN(12), Wc, det);
  gemm_k<<<dim3(128/BN, (BSZ*L_IN)/BM), 256, 0, stream>>>(
      embE, IN(10), 0, IN(11), 0, bdown, det, 512, 128);
  conv_gemm<<<dim3(2, (BSZ*42)/BM), 256, 0, stream>>>(
      bdown, L_IN, 0, bconv, 54, 0, 42, Wc, IN(13), IN(14), IN(15), IN(16), IN(17), det, 0);
  conv_gemm<<<dim3(2, (BSZ*10)/BM), 256, 0, stream>>>(
      bconv, 54, 0, bconv, 54, 42, 10, Wc + 65536, IN(13), IN(14), IN(15), IN(16), IN(17), det, 1);
  conv_gemm<<<dim3(2, (BSZ*2)/BM), 256, 0, stream>>>(
      bconv, 54, 42, bconv, 54, 52, 2, Wc + 131072, IN(13), IN(14), IN(15), IN(16), IN(17), det, 2);
  gemm_k<<<dim3(512/BN, (BSZ*54)/BM), 256, 0, stream>>>(
      bconv, IN(18), 0, IN(19), 0, bup, det, 128, 512);
  concat_ln_kernel<<<(BSZ*S1)/4, 256, 0, stream>>>(embE, bup, IN(20), IN(21), encx, encb, det);

  // encoder layers
  for (int i = 0; i < 6; ++i){
    long long wO = (long long)i*512*768, oO = (long long)i*768*512;
    long long bO = (long long)i*768, dO = (long long)i*512;
    long long fO = (long long)i*512*512;
    u16 *Wt3, *WtO, *Wt1, *Wt2;
    if (haveWtAll){
      u16* base = WtAll + (size_t)i*WT_SLOT;
      Wt3 = base;
      WtO = base + (size_t)2304*512;
      Wt1 = WtO + (size_t)512*768;
      Wt2 = Wt1 + (size_t)512*512;
    } else {
      wt_batch<<<2048, 256, 0, stream>>>(IN(22), IN(24), IN(26), IN(28), IN(32), IN(34),
                                         wO, oO, fO, WtE3f, WtEOf, WtE1f, WtE2f, det);
      Wt3 = WtE3f; WtO = WtEOf; Wt1 = WtE1f; Wt2 = WtE2f;
    }
    if (haveShadow)
      gemm_qkv<1><<<8*rpxE*18, 256, 0, stream>>>(
          encb, Wt3, IN(23), IN(25), IN(27), bO, qb, kb, vb, det, S1, S1, 0, RPe, 18, rpxE);
    else
      gemm_qkv<0><<<8*rpxE*18, 256, 0, stream>>>(
          encx, Wt3, IN(23), IN(25), IN(27), bO, qb, kb, vb, det, S1, S1, 0, RPe, 18, rpxE);
    attn_enc_sparse<<<(BSZ*S1*NHD)/16, 256, 0, stream>>>(qb, kb, vb, nbr);
    gemm_mfma<2,1,0><<<8*rpxE*4, 256, 0, stream>>>(
        qb, WtO, IN(29), dO, encx, tmp1, det, 768, 512, S1, S1, 0, RPe, 4, rpxE);
    ln_kernel<<<(BSZ*S1)/4, 256, 0, stream>>>(tmp1, IN(30), dO, IN(31), dO, 1e-6f, encx, encb, det);
    if (haveShadow)
      gemm_mfma<1,1,1><<<8*rpxE*4, 256, 0, stream>>>(
          encb, Wt1, IN(33), dO, nullptr, tmph, det, 512, 512, S1, S1, 0, RPe, 4, rpxE);
    else
      gemm_mfma<1,0,1><<<8*rpxE*4, 256, 0, stream>>>(
          encx, Wt1, IN(33), dO, nullptr, tmph, det, 512, 512, S1, S1, 0, RPe, 4, rpxE);
    gemm_mfma<2,1,0><<<8*rpxE*4, 256, 0, stream>>>(
        tmph, Wt2, IN(35), dO, encx, tmp1, det, 512, 512, S1, S1, 0, RPe, 4, rpxE);
    ln_kernel<<<(BSZ*S1)/4, 256, 0, stream>>>(tmp1, IN(36), dO, IN(37), dO, 1e-6f, encx, encb, det);
  }

  // decoder layers
  for (int i = 0; i < 2; ++i){
    long long wO = (long long)i*512*768, oO = (long long)i*768*512;
    long long bO = (long long)i*768, dO = (long long)i*512;
    long long fO = (long long)i*512*512;
    u16 *Wt3, *WtO, *Wt1, *Wt2;
    if (haveWtAll){
      u16* base = WtAll + (size_t)(6+i)*WT_SLOT;
      Wt3 = base;
      WtO = base + (size_t)2304*512;
      Wt1 = WtO + (size_t)512*768;
      Wt2 = Wt1 + (size_t)512*512;
    } else {
      wt_batch<<<2048, 256, 0, stream>>>(IN(38), IN(40), IN(42), IN(44), IN(48), IN(50),
                                         wO, oO, fO, WtD3f, WtDOf, WtD1f, WtD2f, det);
      Wt3 = WtD3f; WtO = WtDOf; Wt1 = WtD1f; Wt2 = WtD2f;
    }
    if (haveShadow){
      gemm_mfma<0,1,1><<<8*rpxD*6, 256, 0, stream>>>(
          decb, Wt3, IN(39), bO, nullptr, qb, det, 512, 768, L_IN, L_IN, 0, RPd, 6, rpxD);
      gemm_qkv<1><<<8*rpxE*12, 256, 0, stream>>>(
          encb, Wt3 + (size_t)768*512, IN(41), IN(43), IN(43), bO, kb, vb, vb, det, S1, SKV, 0, RPe, 12, rpxE);
      gemm_qkv<1><<<8*rpxD*12, 256, 0, stream>>>(
          decb, Wt3 + (size_t)768*512, IN(41), IN(43), IN(43), bO, kb, vb, vb, det, L_IN, SKV, S1, RPd, 12, rpxD);
    } else {
      gemm_mfma<0,0,1><<<8*rpxD*6, 256, 0, stream>>>(
          decx, Wt3, IN(39), bO, nullptr, qb, det, 512, 768, L_IN, L_IN, 0, RPd, 6, rpxD);
      gemm_qkv<0><<<8*rpxE*12, 256, 0, stream>>>(
          encx, Wt3 + (size_t)768*512, IN(41), IN(43), IN(43), bO, kb, vb, vb, det, S1, SKV, 0, RPe, 12, rpxE);
      gemm_qkv<0><<<8*rpxD*12, 256, 0, stream>>>(
          decx, Wt3 + (size_t)768*512, IN(41), IN(43), IN(43), bO, kb, vb, vb, det, L_IN, SKV, S1, RPd, 12, rpxD);
    }
    attn_dec_mfma<<<dim3(3, NHD, BSZ), 256, 0, stream>>>(qb, kb, vb);
    gemm_mfma<2,1,0><<<8*rpxD*4, 256, 0, stream>>>(
        qb, WtO, IN(45), dO, decx, tmp1, det, 768, 512, L_IN, L_IN, 0, RPd, 4, rpxD);
    ln_kernel<<<(BSZ*L_IN)/4, 256, 0, stream>>>(tmp1, IN(46), dO, IN(47), dO, 1e-6f, decx, decb, det);
    if (haveShadow)
      gemm_mfma<1,1,1><<<8*rpxD*4, 256, 0, stream>>>(
          decb, Wt1, IN(49), dO, nullptr, tmph, det, 512, 512, L_IN, L_IN, 0, RPd, 4, rpxD);
    else
      gemm_mfma<1,0,1><<<8*rpxD*4, 256, 0, stream>>>(
          decx, Wt1, IN(49), dO, nullptr, tmph, det, 512, 512, L_IN, L_IN, 0, RPd, 4, rpxD);
    gemm_mfma<2,1,0><<<8*rpxD*4, 256, 0, stream>>>(
        tmph, Wt2, IN(51), dO, decx, tmp1, det, 512, 512, L_IN, L_IN, 0, RPd, 4, rpxD);
    ln_kernel<<<(BSZ*L_IN)/4, 256, 0, stream>>>(tmp1, IN(52), dO, IN(53), dO, 1e-6f, decx, decb, det);
  }

  pred_kernel<<<((BSZ*L_IN+3)/4), 256, 0, stream>>>(decx, IN(54), d_out, det);
  #undef IN
}

// Round 3
// 2870.588 us; speedup vs baseline: 1.1014x; 1.1014x over previous
//
#include <hip/hip_runtime.h>
#include <cstdint>
#include <cstddef>

// ---------------- model constants ----------------
#define BSZ   64
#define L_IN  168
#define S1    222
#define SKV   390
#define DM    512
#define HD    768
#define NHD   6
#define DK    128

typedef unsigned short u16;
typedef unsigned int u32;
typedef __attribute__((ext_vector_type(8))) short bf16x8;
typedef __attribute__((ext_vector_type(4))) float f32x4v;

// ---------------- bf16 helpers ----------------
__device__ inline float b2f(u16 u){
  union { u32 i; float f; } v; v.i = ((u32)u) << 16; return v.f;
}
__device__ inline u16 f2b(float f){
  union { float f; u32 i; } v; v.f = f;
  u32 x = v.i;
  return (u16)((x + 0x7fffu + ((x >> 16) & 1u)) >> 16);
}
__device__ inline u32 pk2(float a, float b){
  return ((u32)f2b(b) << 16) | (u32)f2b(a);
}
__device__ inline float ldv(const void* p, long long i, bool f32){
  return f32 ? ((const float*)p)[i] : b2f(((const u16*)p)[i]);
}
__device__ inline float4 ldv4(const void* p, long long i, bool f32){
  if (f32) return *(const float4*)((const float*)p + i);
  ushort4 w = *(const ushort4*)((const u16*)p + i);
  return make_float4(b2f(w.x), b2f(w.y), b2f(w.z), b2f(w.w));
}
__device__ inline bool is_f32(const u16* det){ return det[0] != 0x3F80; }
__device__ inline void unpack8(uint4 w, float* f){
  union { u32 i; float fl; } a;
  a.i = w.x << 16;          f[0] = a.fl;
  a.i = w.x & 0xffff0000u;  f[1] = a.fl;
  a.i = w.y << 16;          f[2] = a.fl;
  a.i = w.y & 0xffff0000u;  f[3] = a.fl;
  a.i = w.z << 16;          f[4] = a.fl;
  a.i = w.z & 0xffff0000u;  f[5] = a.fl;
  a.i = w.w << 16;          f[6] = a.fl;
  a.i = w.w & 0xffff0000u;  f[7] = a.fl;
}

// async global->LDS, 16B per lane; dest must be wave-uniform (HW: base + lane*16)
__device__ inline void gload_lds16(const void* g, void* l){
  __builtin_amdgcn_global_load_lds((const __attribute__((address_space(1))) void*)g,
                                   (__attribute__((address_space(3))) void*)l, 16, 0, 0);
}

// ---------------- workspace layout (float-equivalent offsets) ----------------
constexpr size_t OFF_ENCX = 0;
constexpr size_t OFF_DECX = OFF_ENCX + (size_t)BSZ*S1*DM;
constexpr size_t OFF_QB   = OFF_DECX + (size_t)BSZ*L_IN*DM;
constexpr size_t OFF_KB   = OFF_QB   + (size_t)BSZ*S1*HD/2;
constexpr size_t OFF_VB   = OFF_KB   + (size_t)BSZ*SKV*HD/2;
constexpr size_t OFF_NBR  = OFF_VB   + (size_t)BSZ*SKV*HD/2;
constexpr size_t OFF_ENCB = OFF_NBR  + 4096;
constexpr size_t OFF_DECB = OFF_ENCB + (size_t)BSZ*S1*DM/2;
constexpr size_t OFF_WT   = OFF_DECB + (size_t)BSZ*L_IN*DM/2;     // all-layer Wt: 8 slots x 2,097,152 u16
constexpr size_t WT_SLOT  = 2097152;                               // u16 per layer slot
constexpr size_t WS_NEED  = (OFF_WT) * 4;                          // shadow path
constexpr size_t WS_NEED2 = (OFF_WT + 8*WT_SLOT/2) * 4;            // + wt_all region

// ---------------- PAM sparsity ----------------
__device__ inline int scale_of(int i, int& ii){
  if (i < 168){ ii = i;       return 0; }
  if (i < 210){ ii = i - 168; return 1; }
  if (i < 220){ ii = i - 210; return 2; }
  ii = i - 220; return 3;
}
__device__ inline bool pam_ok(int i, int j){
  int ii, jj;
  int li = scale_of(i, ii);
  int lj = scale_of(j, jj);
  const int n[4] = {168, 42, 10, 2};
  if (li == lj){ int d = ii - jj; return (d <= 1 && d >= -1); }
  if (li == lj + 1){ int lo = ii*4, hi = (ii == n[li]-1) ? n[lj] : ii*4+4; return (jj >= lo && jj < hi); }
  if (lj == li + 1){ int lo = jj*4, hi = (jj == n[lj]-1) ? n[li] : jj*4+4; return (ii >= lo && ii < hi); }
  return false;
}
__global__ void build_nbr_kernel(int* __restrict__ nbr){
  int q = blockIdx.x * 256 + threadIdx.x;
  if (q >= S1) return;
  int cnt = 0;
  int list[12];
  for (int j = 0; j < S1; ++j)
    if (pam_ok(q, j) && cnt < 12) list[cnt++] = j;
  #pragma unroll
  for (int t = 0; t < 12; ++t) nbr[q*12 + t] = (t < cnt) ? list[t] : -1;
}

// ---------------- embedding: register-resident weights, grid-stride rows ----
__global__ __launch_bounds__(256)
void embed_fast(const void* __restrict__ x, const void* __restrict__ t,
                const void* __restrict__ cw, const void* __restrict__ tw,
                const void* __restrict__ tb, const u16* __restrict__ det,
                float* __restrict__ out, u16* __restrict__ out2)
{
  bool f32 = is_f32(det);
  int d0 = threadIdx.x;
  int d1 = threadIdx.x + 256;

  float w0[21], w1[21];
  #pragma unroll
  for (int i = 0; i < 21; ++i){
    w0[i] = ldv(cw, (long long)d0*21 + i, f32);
    w1[i] = ldv(cw, (long long)d1*21 + i, f32);
  }
  float tw0[4], tw1[4];
  #pragma unroll
  for (int f = 0; f < 4; ++f){
    tw0[f] = ldv(tw, (long long)f*DM + d0, f32);
    tw1[f] = ldv(tw, (long long)f*DM + d1, f32);
  }
  float tb0 = ldv(tb, d0, f32);
  float tb1 = ldv(tb, d1, f32);
  float dv0 = __expf(-(float)(d0 & ~1) * (9.210340371976184f/512.f));
  float dv1 = __expf(-(float)(d1 & ~1) * (9.210340371976184f/512.f));
  bool odd0 = (d0 & 1), odd1 = (d1 & 1);

  const int nRows = BSZ * L_IN;
  for (int row = blockIdx.x; row < nRows; row += gridDim.x){
    int b = row / L_IN, l = row - b*L_IN;
    float acc0 = 0.f, acc1 = 0.f;
    #pragma unroll
    for (int tt = 0; tt < 3; ++tt){
      int ls = l + tt - 1;
      ls = (ls < 0) ? ls + L_IN : (ls >= L_IN ? ls - L_IN : ls);
      long long xo = ((long long)(b*L_IN + ls))*7;
      #pragma unroll
      for (int c = 0; c < 7; ++c){
        float xv = ldv(x, xo + c, f32);
        acc0 += xv * w0[c*3 + tt];
        acc1 += xv * w1[c*3 + tt];
      }
    }
    float ang0 = (float)l * dv0;
    float ang1 = (float)l * dv1;
    acc0 += odd0 ? __cosf(ang0) : __sinf(ang0);
    acc1 += odd1 ? __cosf(ang1) : __sinf(ang1);
    long long to = ((long long)row)*4;
    #pragma unroll
    for (int f = 0; f < 4; ++f){
      float tv = ldv(t, to + f, f32);
      acc0 += tv * tw0[f];
      acc1 += tv * tw1[f];
    }
    acc0 += tb0;
    acc1 += tb1;
    size_t o = (size_t)row*DM;
    out[o + d0] = acc0;
    out[o + d1] = acc1;
    if (out2){
      out2[o + d0] = f2b(acc0);
      out2[o + d1] = f2b(acc1);
    }
  }
}

// ---------------- weight transpose helpers ----------------
__device__ inline void trans32(const void* W, long long wOff, int K, int N, int k0, int n0,
                               u16* __restrict__ Wt, bool f32, float* tb, int tid)
{
  int c = tid & 31, r0 = tid >> 5;
  #pragma unroll
  for (int rr = 0; rr < 32; rr += 8)
    tb[(r0+rr)*33 + c] = ldv(W, wOff + (long long)(k0+r0+rr)*N + n0 + c, f32);
  __syncthreads();
  #pragma unroll
  for (int rr = 0; rr < 32; rr += 8)
    Wt[(size_t)(n0+r0+rr)*K + k0 + c] = f2b(tb[c*33 + r0+rr]);
}

__device__ inline void wt_layer_body(int t, const void* wq, const void* wk, const void* wv,
                                     const void* wo, const void* w1, const void* w2,
                                     long long wO, long long oO, long long fO,
                                     u16* Wt3, u16* WtO, u16* Wt1, u16* Wt2,
                                     bool f32, float* tb, int tid)
{
  if (t < 384)       trans32(wq, wO, 512, 768, (t/24)*32, (t%24)*32, Wt3,               f32, tb, tid);
  else if (t < 768)  { int u = t-384;  trans32(wk, wO, 512, 768, (u/24)*32, (u%24)*32, Wt3 + (size_t)768*512,  f32, tb, tid); }
  else if (t < 1152) { int u = t-768;  trans32(wv, wO, 512, 768, (u/24)*32, (u%24)*32, Wt3 + (size_t)1536*512, f32, tb, tid); }
  else if (t < 1536) { int u = t-1152; trans32(wo, oO, 768, 512, (u/16)*32, (u%16)*32, WtO, f32, tb, tid); }
  else if (t < 1792) { int u = t-1536; trans32(w1, fO, 512, 512, (u/16)*32, (u%16)*32, Wt1, f32, tb, tid); }
  else               { int u = t-1792; trans32(w2, fO, 512, 512, (u/16)*32, (u%16)*32, Wt2, f32, tb, tid); }
}

// per-layer fallback
__global__ __launch_bounds__(256)
void wt_batch(const void* wq, const void* wk, const void* wv,
              const void* wo, const void* w1, const void* w2,
              long long wO, long long oO, long long fO,
              u16* __restrict__ Wt3, u16* __restrict__ WtO,
              u16* __restrict__ Wt1, u16* __restrict__ Wt2,
              const u16* __restrict__ det)
{
  __shared__ float tb[32*33];
  bool f32 = is_f32(det);
  wt_layer_body(blockIdx.x, wq, wk, wv, wo, w1, w2, wO, oO, fO, Wt3, WtO, Wt1, Wt2,
                f32, tb, threadIdx.x);
}

// all 8 layers in one launch: slots 0..5 = enc layers, 6..7 = dec layers
__global__ __launch_bounds__(256)
void wt_all(const void* ewq, const void* ewk, const void* ewv, const void* ewo,
            const void* ew1, const void* ew2,
            const void* dwq, const void* dwk, const void* dwv, const void* dwo,
            const void* dw1, const void* dw2,
            u16* __restrict__ WtAll, const u16* __restrict__ det)
{
  __shared__ float tb[32*33];
  bool f32 = is_f32(det);
  int s = blockIdx.x >> 11;
  int t = blockIdx.x & 2047;
  bool enc = s < 6;
  int li = enc ? s : s - 6;
  long long wO = (long long)li*512*768, oO = (long long)li*768*512, fO = (long long)li*512*512;
  u16* base = WtAll + (size_t)s*WT_SLOT;
  wt_layer_body(t,
                enc ? ewq : dwq, enc ? ewk : dwk, enc ? ewv : dwv,
                enc ? ewo : dwo, enc ? ew1 : dw1, enc ? ew2 : dw2,
                wO, oO, fO,
                base, base + (size_t)2304*512,
                base + (size_t)2304*512 + (size_t)512*768,
                base + (size_t)2304*512 + (size_t)512*768 + (size_t)512*512,
                f32, tb, threadIdx.x);
}

// ---------------- XCD-exclusive row-panel swizzle ----------------
__device__ inline bool swz(int t, int RP, int CP, int rpx, int& row0, int& col0){
  int xcd = t & 7, j = t >> 3;
  int rp = xcd + 8*(j % rpx);
  int cp = j / rpx;
  if (rp >= RP || cp >= CP) return false;
  row0 = rp*128; col0 = cp*128;
  return true;
}

// ---------------- MFMA GEMM: C = A[M,K] @ W via Wt bf16 [N,K] ----------------
// bf16 staging via global_load_lds w=16 with pre-swizzled SOURCE (linear LDS dest);
// source col swizzle per lane: sc = c ^ (r8*8) with c=(lane&7)*8, r8=lane>>3 —
// identical involution to the ds_read-side XOR, so fragment reads are unchanged.
template<int EPI, int ABF, int CBF>
__global__ __launch_bounds__(256)
void gemm_mfma(const void* __restrict__ Av, const u16* __restrict__ Wt,
               const void* __restrict__ bias, long long bOff, const float* __restrict__ R,
               void* __restrict__ Cv, const u16* __restrict__ det,
               int K, int N, int La, int Lc, int off, int RP, int CP, int rpx)
{
  __shared__ u16 As[128][64];
  __shared__ u16 Bs[128][64];
  bool f32 = is_f32(det);
  int tid = threadIdx.x;
  int row0, col0;
  if (!swz(blockIdx.x, RP, CP, rpx, row0, col0)) return;
  int wave = tid >> 6, lane = tid & 63;
  int wm = (wave >> 1)*64, wn = (wave & 1)*64;
  int lm = lane & 15, quad = lane >> 4;
  int sr = tid >> 1;
  int sh = (tid & 1) * 32;
  int swzS = (sr & 7) * 8;
  int r8 = lane >> 3;                 // 0..7 (row within 8-row wave chunk)
  int scw = ((lane & 7)*8) ^ (r8*8);  // pre-swizzled source col (u16 units)
  f32x4v acc[4][4];
  #pragma unroll
  for (int i = 0; i < 4; ++i)
    #pragma unroll
    for (int j = 0; j < 4; ++j) acc[i][j] = (f32x4v){0.f,0.f,0.f,0.f};

  for (int k0 = 0; k0 < K; k0 += 64){
    if (ABF){
      const u16* base = (const u16*)Av + (size_t)row0*K + k0 + scw;
      #pragma unroll
      for (int j = 0; j < 4; ++j){
        int r = wave*32 + j*8;
        gload_lds16(base + (size_t)(r + r8)*K, &As[r][0]);
      }
    } else {
      const float* src = (const float*)Av + (size_t)(row0+sr)*K + k0 + sh;
      #pragma unroll
      for (int j = 0; j < 4; ++j){
        float4 f0 = *(const float4*)(src + 8*j);
        float4 f1 = *(const float4*)(src + 8*j + 4);
        uint4 o;
        o.x = pk2(f0.x, f0.y); o.y = pk2(f0.z, f0.w);
        o.z = pk2(f1.x, f1.y); o.w = pk2(f1.z, f1.w);
        *(uint4*)&As[sr][(sh + 8*j)^swzS] = o;
      }
    }
    {
      const u16* base = Wt + (size_t)col0*K + k0 + scw;
      #pragma unroll
      for (int j = 0; j < 4; ++j){
        int r = wave*32 + j*8;
        gload_lds16(base + (size_t)(r + r8)*K, &Bs[r][0]);
      }
    }
    __syncthreads();
    bf16x8 af[4][2], bfr[4][2];
    #pragma unroll
    for (int mi = 0; mi < 4; ++mi){
      int m = wm + mi*16 + lm;
      int sz = (m & 7)*8;
      af[mi][0] = *(const bf16x8*)&As[m][(quad*8) ^ sz];
      af[mi][1] = *(const bf16x8*)&As[m][(32 + quad*8) ^ sz];
    }
    #pragma unroll
    for (int ni = 0; ni < 4; ++ni){
      int n = wn + ni*16 + lm;
      int sz = (n & 7)*8;
      bfr[ni][0] = *(const bf16x8*)&Bs[n][(quad*8) ^ sz];
      bfr[ni][1] = *(const bf16x8*)&Bs[n][(32 + quad*8) ^ sz];
    }
    #pragma unroll
    for (int mi = 0; mi < 4; ++mi)
      #pragma unroll
      for (int ni = 0; ni < 4; ++ni){
        acc[mi][ni] = __builtin_amdgcn_mfma_f32_16x16x32_bf16(af[mi][0], bfr[ni][0], acc[mi][ni], 0, 0, 0);
        acc[mi][ni] = __builtin_amdgcn_mfma_f32_16x16x32_bf16(af[mi][1], bfr[ni][1], acc[mi][ni], 0, 0, 0);
      }
    __syncthreads();
  }
  #pragma unroll
  for (int mi = 0; mi < 4; ++mi){
    #pragma unroll
    for (int r = 0; r < 4; ++r){
      int row = row0 + wm + mi*16 + quad*4 + r;
      int bb = row / La, l = row - bb*La;
      size_t crow = ((size_t)bb*Lc + off + l)*(size_t)N;
      #pragma unroll
      for (int ni = 0; ni < 4; ++ni){
        int col = col0 + wn + ni*16 + lm;
        float vv = acc[mi][ni][r] + ldv(bias, bOff + col, f32);
        if (EPI == 1) vv = 0.5f*vv*(1.f + erff(vv*0.70710678118654752f));
        if (EPI == 2) vv += R[crow + col];
        if (CBF) ((u16*)Cv)[crow + col] = f2b(vv);
        else     ((float*)Cv)[crow + col] = vv;
      }
    }
  }
}

// ---------------- fused QKV / KV MFMA GEMM (K=512), swizzled ----------------
template<int ABF>
__global__ __launch_bounds__(256)
void gemm_qkv(const void* __restrict__ Av, const u16* __restrict__ Wt,
              const void* __restrict__ b0, const void* __restrict__ b1, const void* __restrict__ b2,
              long long bOff, u16* __restrict__ o0, u16* __restrict__ o1, u16* __restrict__ o2,
              const u16* __restrict__ det, int La, int Lc, int off, int RP, int CP, int rpx)
{
  __shared__ u16 As[128][64];
  __shared__ u16 Bs[128][64];
  bool f32 = is_f32(det);
  const int K = 512;
  int tid = threadIdx.x;
  int row0, col0;
  if (!swz(blockIdx.x, RP, CP, rpx, row0, col0)) return;
  int wave = tid >> 6, lane = tid & 63;
  int wm = (wave >> 1)*64, wn = (wave & 1)*64;
  int lm = lane & 15, quad = lane >> 4;
  int sr = tid >> 1;
  int sh = (tid & 1) * 32;
  int swzS = (sr & 7) * 8;
  int r8 = lane >> 3;
  int scw = ((lane & 7)*8) ^ (r8*8);
  f32x4v acc[4][4];
  #pragma unroll
  for (int i = 0; i < 4; ++i)
    #pragma unroll
    for (int j = 0; j < 4; ++j) acc[i][j] = (f32x4v){0.f,0.f,0.f,0.f};

  for (int k0 = 0; k0 < K; k0 += 64){
    if (ABF){
      const u16* base = (const u16*)Av + (size_t)row0*K + k0 + scw;
      #pragma unroll
      for (int j = 0; j < 4; ++j){
        int r = wave*32 + j*8;
        gload_lds16(base + (size_t)(r + r8)*K, &As[r][0]);
      }
    } else {
      const float* src = (const float*)Av + (size_t)(row0+sr)*K + k0 + sh;
      #pragma unroll
      for (int j = 0; j < 4; ++j){
        float4 f0 = *(const float4*)(src + 8*j);
        float4 f1 = *(const float4*)(src + 8*j + 4);
        uint4 o;
        o.x = pk2(f0.x, f0.y); o.y = pk2(f0.z, f0.w);
        o.z = pk2(f1.x, f1.y); o.w = pk2(f1.z, f1.w);
        *(uint4*)&As[sr][(sh + 8*j)^swzS] = o;
      }
    }
    {
      const u16* base = Wt + (size_t)col0*K + k0 + scw;
      #pragma unroll
      for (int j = 0; j < 4; ++j){
        int r = wave*32 + j*8;
        gload_lds16(base + (size_t)(r + r8)*K, &Bs[r][0]);
      }
    }
    __syncthreads();
    bf16x8 af[4][2], bfr[4][2];
    #pragma unroll
    for (int mi = 0; mi < 4; ++mi){
      int m = wm + mi*16 + lm;
      int sz = (m & 7)*8;
      af[mi][0] = *(const bf16x8*)&As[m][(quad*8) ^ sz];
      af[mi][1] = *(const bf16x8*)&As[m][(32 + quad*8) ^ sz];
    }
    #pragma unroll
    for (int ni = 0; ni < 4; ++ni){
      int n = wn + ni*16 + lm;
      int sz = (n & 7)*8;
      bfr[ni][0] = *(const bf16x8*)&Bs[n][(quad*8) ^ sz];
      bfr[ni][1] = *(const bf16x8*)&Bs[n][(32 + quad*8) ^ sz];
    }
    #pragma unroll
    for (int mi = 0; mi < 4; ++mi)
      #pragma unroll
      for (int ni = 0; ni < 4; ++ni){
        acc[mi][ni] = __builtin_amdgcn_mfma_f32_16x16x32_bf16(af[mi][0], bfr[ni][0], acc[mi][ni], 0, 0, 0);
        acc[mi][ni] = __builtin_amdgcn_mfma_f32_16x16x32_bf16(af[mi][1], bfr[ni][1], acc[mi][ni], 0, 0, 0);
      }
    __syncthreads();
  }
  #pragma unroll
  for (int mi = 0; mi < 4; ++mi){
    #pragma unroll
    for (int r = 0; r < 4; ++r){
      int row = row0 + wm + mi*16 + quad*4 + r;
      int bb = row / La, l = row - bb*La;
      size_t crow = ((size_t)bb*Lc + off + l)*(size_t)HD;
      #pragma unroll
      for (int ni = 0; ni < 4; ++ni){
        int col = col0 + wn + ni*16 + lm;
        int sel = (col >= 1536) ? 2 : (col >= 768 ? 1 : 0);
        int colr = col - sel*768;
        const void* bp = (sel == 0) ? b0 : (sel == 1) ? b1 : b2;
        u16* dst = (sel == 0) ? o0 : (sel == 1) ? o1 : o2;
        float vv = acc[mi][ni][r] + ldv(bp, bOff + colr, f32);
        dst[crow + colr] = f2b(vv);
      }
    }
  }
}

// ---------------- SIMT GEMM (bottleneck) ----------------
#define BM 64
#define BN 64
#define BK 16
__global__ __launch_bounds__(256)
void gemm_k(const float* __restrict__ A, const void* __restrict__ W, long long wOff,
            const void* __restrict__ bias, long long bOff,
            float* __restrict__ C, const u16* __restrict__ det, int K, int N)
{
  __shared__ float As2[BK][BM+4];
  __shared__ float Bs2[BK][BN+4];
  bool f32 = is_f32(det);
  int tid = threadIdx.x;
  int row0 = blockIdx.y * BM, col0 = blockIdx.x * BN;
  int ty = tid >> 4, tx = tid & 15;
  int lr = tid >> 2, lc4 = (tid & 3) << 2;
  int wr = tid >> 4, wc4 = (tid & 15) << 2;
  float acc[4][4] = {};
  for (int k0 = 0; k0 < K; k0 += BK){
    float4 av = *(const float4*)(A + (size_t)(row0 + lr)*K + k0 + lc4);
    As2[lc4+0][lr] = av.x; As2[lc4+1][lr] = av.y;
    As2[lc4+2][lr] = av.z; As2[lc4+3][lr] = av.w;
    float4 wv = ldv4(W, wOff + (long long)(k0 + wr)*N + col0 + wc4, f32);
    *(float4*)&Bs2[wr][wc4] = wv;
    __syncthreads();
    #pragma unroll
    for (int kk = 0; kk < BK; ++kk){
      float4 a  = *(const float4*)&As2[kk][ty << 2];
      float4 bb = *(const float4*)&Bs2[kk][tx << 2];
      acc[0][0] += a.x*bb.x; acc[0][1] += a.x*bb.y; acc[0][2] += a.x*bb.z; acc[0][3] += a.x*bb.w;
      acc[1][0] += a.y*bb.x; acc[1][1] += a.y*bb.y; acc[1][2] += a.y*bb.z; acc[1][3] += a.y*bb.w;
      acc[2][0] += a.z*bb.x; acc[2][1] += a.z*bb.y; acc[2][2] += a.z*bb.z; acc[2][3] += a.z*bb.w;
      acc[3][0] += a.w*bb.x; acc[3][1] += a.w*bb.y; acc[3][2] += a.w*bb.z; acc[3][3] += a.w*bb.w;
    }
    __syncthreads();
  }
  #pragma unroll
  for (int i = 0; i < 4; ++i){
    int r = row0 + (ty << 2) + i;
    size_t crow = (size_t)r*(size_t)N;
    #pragma unroll
    for (int j = 0; j < 4; ++j){
      int c = col0 + (tx << 2) + j;
      C[crow + c] = acc[i][j] + ldv(bias, bOff + c, f32);
    }
  }
}

// ---------------- conv weight reorder ----------------
__global__ void wc_kernel(const void* __restrict__ w, float* __restrict__ Wc,
                          const u16* __restrict__ det)
{
  bool f32 = is_f32(det);
  int idx = blockIdx.x * 256 + threadIdx.x;
  if (idx >= 3*512*128) return;
  int co = idx & 127;
  int kk = (idx >> 7) & 511;
  int lay = idx >> 16;
  int tt = kk >> 7, ci = kk & 127;
  Wc[idx] = ldv(w, (long long)lay*65536 + co*512 + ci*4 + tt, f32);
}

// ---------------- bottleneck conv as GEMM + BN + ELU ----------------
__global__ __launch_bounds__(256)
void conv_gemm(const float* __restrict__ in, int inStride, int inOff,
               float* __restrict__ out, int outStride, int outOff, int Lout,
               const float* __restrict__ Wc,
               const void* __restrict__ cb, const void* __restrict__ bg,
               const void* __restrict__ bb, const void* __restrict__ bm,
               const void* __restrict__ bv, const u16* __restrict__ det, int lay)
{
  __shared__ float As2[BK][BM+4];
  __shared__ float Bs2[BK][BN+4];
  bool f32 = is_f32(det);
  int tid = threadIdx.x;
  int row0 = blockIdx.y * BM, col0 = blockIdx.x * BN;
  int ty = tid >> 4, tx = tid & 15;
  int lr = tid >> 2, lc4 = (tid & 3) << 2;
  int wr = tid >> 4, wc4 = (tid & 15) << 2;
  int rs = row0 + lr;
  int bs = rs / Lout, js = rs - bs*Lout;
  const float* arow = in + ((size_t)(bs*inStride + inOff + js*4))*128;
  float acc[4][4] = {};
  for (int k0 = 0; k0 < 512; k0 += BK){
    float4 av = *(const float4*)(arow + k0 + lc4);
    As2[lc4+0][lr] = av.x; As2[lc4+1][lr] = av.y;
    As2[lc4+2][lr] = av.z; As2[lc4+3][lr] = av.w;
    float4 wv = *(const float4*)(Wc + (size_t)(k0 + wr)*128 + col0 + wc4);
    *(float4*)&Bs2[wr][wc4] = wv;
    __syncthreads();
    #pragma unroll
    for (int kk = 0; kk < BK; ++kk){
      float4 a  = *(const float4*)&As2[kk][ty << 2];
      float4 bb2 = *(const float4*)&Bs2[kk][tx << 2];
      acc[0][0] += a.x*bb2.x; acc[0][1] += a.x*bb2.y; acc[0][2] += a.x*bb2.z; acc[0][3] += a.x*bb2.w;
      acc[1][0] += a.y*bb2.x; acc[1][1] += a.y*bb2.y; acc[1][2] += a.y*bb2.z; acc[1][3] += a.y*bb2.w;
      acc[2][0] += a.z*bb2.x; acc[2][1] += a.z*bb2.y; acc[2][2] += a.z*bb2.z; acc[2][3] += a.z*bb2.w;
      acc[3][0] += a.w*bb2.x; acc[3][1] += a.w*bb2.y; acc[3][2] += a.w*bb2.z; acc[3][3] += a.w*bb2.w;
    }
    __syncthreads();
  }
  #pragma unroll
  for (int i = 0; i < 4; ++i){
    int r = row0 + (ty << 2) + i;
    int b = r / Lout, j = r - b*Lout;
    float* orow = out + ((size_t)(b*outStride + outOff + j))*128;
    #pragma unroll
    for (int jj = 0; jj < 4; ++jj){
      int co = col0 + (tx << 2) + jj;
      long long po = (long long)lay*128 + co;
      float a = acc[i][jj] + ldv(cb, po, f32);
      a = (a - ldv(bm, po, f32)) * rsqrtf(ldv(bv, po, f32) + 1e-5f) * ldv(bg, po, f32) + ldv(bb, po, f32);
      a = a > 0.f ? a : (__expf(a) - 1.f);
      orow[co] = a;
    }
  }
}

// ---------------- LayerNorm (4 rows/block, optional bf16 shadow) ----------------
__global__ __launch_bounds__(256)
void ln_kernel(const float* __restrict__ X, const void* __restrict__ g, long long gOff,
               const void* __restrict__ bt, long long bOff, float eps,
               float* __restrict__ Out, u16* __restrict__ OutB, const u16* __restrict__ det)
{
  bool f32 = is_f32(det);
  int row = blockIdx.x*4 + (threadIdx.x >> 6);
  int lane = threadIdx.x & 63;
  const float* xr = X + (size_t)row*DM;
  float v[8]; float s = 0.f;
  #pragma unroll
  for (int i = 0; i < 8; ++i){ v[i] = xr[lane + i*64]; s += v[i]; }
  #pragma unroll
  for (int o = 32; o > 0; o >>= 1) s += __shfl_xor(s, o);
  float mean = s * (1.f/512.f);
  float q = 0.f;
  #pragma unroll
  for (int i = 0; i < 8; ++i){ float d = v[i]-mean; q += d*d; }
  #pragma unroll
  for (int o = 32; o > 0; o >>= 1) q += __shfl_xor(q, o);
  float inv = rsqrtf(q*(1.f/512.f) + eps);
  float* orow = Out + (size_t)row*DM;
  #pragma unroll
  for (int i = 0; i < 8; ++i){
    int c = lane + i*64;
    float val = (v[i]-mean)*inv*ldv(g, gOff + c, f32) + ldv(bt, bOff + c, f32);
    orow[c] = val;
    if (OutB) OutB[(size_t)row*DM + c] = f2b(val);
  }
}

// ---------------- concat + LayerNorm(1e-5), 4 rows/block, optional shadow ----------------
__global__ __launch_bounds__(256)
void concat_ln_kernel(const float* __restrict__ emb, const float* __restrict__ up,
                      const void* __restrict__ g, const void* __restrict__ bt,
                      float* __restrict__ Out, u16* __restrict__ OutB, const u16* __restrict__ det)
{
  bool f32 = is_f32(det);
  int row = blockIdx.x*4 + (threadIdx.x >> 6);
  int lane = threadIdx.x & 63;
  int b = row / S1, l = row - b*S1;
  const float* xr = (l < L_IN) ? emb + ((size_t)(b*L_IN + l))*DM
                               : up  + ((size_t)(b*54 + (l - L_IN)))*DM;
  float v[8]; float s = 0.f;
  #pragma unroll
  for (int i = 0; i < 8; ++i){ v[i] = xr[lane + i*64]; s += v[i]; }
  #pragma unroll
  for (int o = 32; o > 0; o >>= 1) s += __shfl_xor(s, o);
  float mean = s * (1.f/512.f);
  float q = 0.f;
  #pragma unroll
  for (int i = 0; i < 8; ++i){ float d = v[i]-mean; q += d*d; }
  #pragma unroll
  for (int o = 32; o > 0; o >>= 1) q += __shfl_xor(q, o);
  float inv = rsqrtf(q*(1.f/512.f) + 1e-5f);
  float* orow = Out + (size_t)row*DM;
  #pragma unroll
  for (int i = 0; i < 8; ++i){
    int c = lane + i*64;
    float val = (v[i]-mean)*inv*ldv(g, c, f32) + ldv(bt, c, f32);
    orow[c] = val;
    if (OutB) OutB[(size_t)row*DM + c] = f2b(val);
  }
}

// ---------------- encoder attention: PAM-sparse, 16-lane unit per (b,q,h) ----------------
__global__ __launch_bounds__(256)
void attn_enc_sparse(u16* __restrict__ q, const u16* __restrict__ k,
                     const u16* __restrict__ v, const int* __restrict__ nbr)
{
  int u = blockIdx.x * 16 + (threadIdx.x >> 4);
  int lane16 = threadIdx.x & 15;
  int h = u % NHD;
  int bq = u / NHD;
  int b = bq / S1, qr = bq - b*S1;
  const float scale = 0.088388347648318447f;
  size_t rowoff = (size_t)bq*HD + h*DK + lane16*8;
  uint4 qw = *(const uint4*)(q + rowoff);
  float qd[8]; unpack8(qw, qd);
  const int* nb = nbr + qr*12;
  size_t base = (size_t)b*S1*HD + h*DK + lane16*8;
  float pj[12];
  #pragma unroll
  for (int j = 0; j < 12; ++j){
    int kg = nb[j];
    int kgc = kg < 0 ? 0 : kg;
    uint4 kw = *(const uint4*)(k + (size_t)kgc*HD + base);
    float kd[8]; unpack8(kw, kd);
    float p = qd[0]*kd[0] + qd[1]*kd[1] + qd[2]*kd[2] + qd[3]*kd[3]
            + qd[4]*kd[4] + qd[5]*kd[5] + qd[6]*kd[6] + qd[7]*kd[7];
    p += __shfl_xor(p, 1); p += __shfl_xor(p, 2);
    p += __shfl_xor(p, 4); p += __shfl_xor(p, 8);
    pj[j] = (kg >= 0) ? p*scale : -1e30f;
  }
  float m = -1e30f;
  #pragma unroll
  for (int j = 0; j < 12; ++j) m = fmaxf(m, pj[j]);
  float s = 0.f;
  #pragma unroll
  for (int j = 0; j < 12; ++j){ pj[j] = __expf(pj[j] - m); s += pj[j]; }
  float inv = 1.f / s;
  float o[8];
  #pragma unroll
  for (int i = 0; i < 8; ++i) o[i] = 0.f;
  #pragma unroll
  for (int j = 0; j < 12; ++j){
    int kg = nb[j];
    int kgc = kg < 0 ? 0 : kg;
    uint4 vw = *(const uint4*)(v + (size_t)kgc*HD + base);
    float vd[8]; unpack8(vw, vd);
    #pragma unroll
    for (int i = 0; i < 8; ++i) o[i] += pj[j]*vd[i];
  }
  uint4 ow;
  ow.x = pk2(o[0]*inv, o[1]*inv);
  ow.y = pk2(o[2]*inv, o[3]*inv);
  ow.z = pk2(o[4]*inv, o[5]*inv);
  ow.w = pk2(o[6]*inv, o[7]*inv);
  *(uint4*)(q + rowoff) = ow;
}

// ---------------- decoder attention: MFMA flash (v2) ----------------
#define FQT 64
__global__ __launch_bounds__(256)
void attn_dec_mfma(u16* __restrict__ q, const u16* __restrict__ k,
                   const u16* __restrict__ v)
{
  __shared__ __align__(16) u16 Ks[32][136];
  __shared__ __align__(16) u32 Vt[16][132];
  __shared__ __align__(16) u32 Pls[4][16][16];
  int b = blockIdx.z, h = blockIdx.y;
  int qt0 = blockIdx.x * FQT;
  int tid = threadIdx.x;
  int wave = tid >> 6, lane = tid & 63;
  int lm = lane & 15, quad = lane >> 4;
  const float scale = 0.088388347648318447f;
  const size_t qb0 = (size_t)b*L_IN*HD + (size_t)h*DK;
  const size_t kb0 = (size_t)b*SKV*HD + (size_t)h*DK;

  bf16x8 qf[4];
  {
    int qg = qt0 + wave*16 + lm;
    if (qg < L_IN){
      #pragma unroll
      for (int ks = 0; ks < 4; ++ks)
        qf[ks] = *(const bf16x8*)(q + qb0 + (size_t)qg*HD + ks*32 + quad*8);
    } else {
      #pragma unroll
      for (int ks = 0; ks < 4; ++ks) qf[ks] = (bf16x8){0,0,0,0,0,0,0,0};
    }
  }

  float mold[4], lsum[4];
  #pragma unroll
  for (int r = 0; r < 4; ++r){ mold[r] = -1e30f; lsum[r] = 0.f; }
  f32x4v oacc[8];
  #pragma unroll
  for (int f = 0; f < 8; ++f) oacc[f] = (f32x4v){0.f,0.f,0.f,0.f};

  int kEnd = S1 + qt0 + FQT; if (kEnd > SKV) kEnd = SKV;
  for (int kt0 = 0; kt0 < kEnd; kt0 += 32){
    __syncthreads();
    for (int i = tid*4; i < 32*128; i += 1024){
      int kk = i >> 7, d = i & 127;
      int kg = kt0 + kk;
      ushort4 w = make_ushort4(0,0,0,0);
      if (kg < SKV) w = *(const ushort4*)(k + kb0 + (size_t)kg*HD + d);
      *(ushort4*)&Ks[kk][d] = w;
    }
    for (int t2 = tid; t2 < 512; t2 += 256){
      int g = t2 & 31, p = t2 >> 5;
      int d0 = g*4;
      int kg0 = kt0 + p, kg1 = kt0 + p + 16;
      ushort4 a = make_ushort4(0,0,0,0), c = make_ushort4(0,0,0,0);
      if (kg0 < SKV) a = *(const ushort4*)(v + kb0 + (size_t)kg0*HD + d0);
      if (kg1 < SKV) c = *(const ushort4*)(v + kb0 + (size_t)kg1*HD + d0);
      uint4 o;
      o.x = (u32)a.x | ((u32)c.x << 16);
      o.y = (u32)a.y | ((u32)c.y << 16);
      o.z = (u32)a.z | ((u32)c.z << 16);
      o.w = (u32)a.w | ((u32)c.w << 16);
      *(uint4*)&Vt[p][d0] = o;
    }
    __syncthreads();
    f32x4v sacc[2];
    sacc[0] = (f32x4v){0.f,0.f,0.f,0.f};
    sacc[1] = (f32x4v){0.f,0.f,0.f,0.f};
    #pragma unroll
    for (int t = 0; t < 2; ++t)
      #pragma unroll
      for (int ks = 0; ks < 4; ++ks){
        bf16x8 kf = *(const bf16x8*)&Ks[t*16 + lm][ks*32 + quad*8];
        sacc[t] = __builtin_amdgcn_mfma_f32_16x16x32_bf16(qf[ks], kf, sacc[t], 0, 0, 0);
      }
    float p[2][4];
    #pragma unroll
    for (int r = 0; r < 4; ++r){
      int qg = qt0 + wave*16 + quad*4 + r;
      float s0, s1;
      {
        int kg = kt0 + lm;
        bool ok = (kg < SKV) && (qg < L_IN) && (kg <= S1 + qg);
        s0 = ok ? sacc[0][r]*scale : -1e30f;
      }
      {
        int kg = kt0 + 16 + lm;
        bool ok = (kg < SKV) && (qg < L_IN) && (kg <= S1 + qg);
        s1 = ok ? sacc[1][r]*scale : -1e30f;
      }
      float mn = fmaxf(s0, s1);
      #pragma unroll
      for (int o = 8; o > 0; o >>= 1) mn = fmaxf(mn, __shfl_xor(mn, o));
      float mi = fmaxf(mold[r], mn);
      float alpha = __expf(mold[r] - mi);
      mold[r] = mi;
      p[0][r] = __expf(s0 - mi);
      p[1][r] = __expf(s1 - mi);
      float rs = p[0][r] + p[1][r];
      #pragma unroll
      for (int o = 8; o > 0; o >>= 1) rs += __shfl_xor(rs, o);
      lsum[r] = lsum[r]*alpha + rs;
      #pragma unroll
      for (int f = 0; f < 8; ++f) oacc[f][r] *= alpha;
    }
    #pragma unroll
    for (int r = 0; r < 4; ++r)
      Pls[wave][quad*4+r][lm] = pk2(p[0][r], p[1][r]);
    bf16x8 pa = *(const bf16x8*)&Pls[wave][lm][quad*4];
    #pragma unroll
    for (int f = 0; f < 8; ++f){
      union { u32 u[4]; bf16x8 v8; } vv;
      vv.u[0] = Vt[quad*4+0][f*16 + lm];
      vv.u[1] = Vt[quad*4+1][f*16 + lm];
      vv.u[2] = Vt[quad*4+2][f*16 + lm];
      vv.u[3] = Vt[quad*4+3][f*16 + lm];
      oacc[f] = __builtin_amdgcn_mfma_f32_16x16x32_bf16(pa, vv.v8, oacc[f], 0, 0, 0);
    }
  }
  #pragma unroll
  for (int r = 0; r < 4; ++r){
    int qg = qt0 + wave*16 + quad*4 + r;
    if (qg < L_IN){
      float inv = 1.f / lsum[r];
      #pragma unroll
      for (int f = 0; f < 8; ++f)
        q[qb0 + (size_t)qg*HD + f*16 + lm] = f2b(oacc[f][r]*inv);
    }
  }
}

// ---------------- prediction head: one wave per row, shfl-reduce ----------------
__global__ __launch_bounds__(256)
void pred_kernel(const float* __restrict__ X, const void* __restrict__ w,
                 void* __restrict__ out, const u16* __restrict__ det)
{
  bool f32 = is_f32(det);
  int row = blockIdx.x*4 + (threadIdx.x >> 6);
  int lane = threadIdx.x & 63;
  if (row >= BSZ*L_IN) return;
  const float* xr = X + (size_t)row*DM;
  float a0=0.f,a1=0.f,a2=0.f,a3=0.f,a4=0.f,a5=0.f,a6=0.f;
  #pragma unroll
  for (int i = 0; i < 8; ++i){
    int kk = lane + i*64;
    float xv = xr[kk];
    long long wo = (long long)kk*7;
    a0 += xv*ldv(w, wo+0, f32);
    a1 += xv*ldv(w, wo+1, f32);
    a2 += xv*ldv(w, wo+2, f32);
    a3 += xv*ldv(w, wo+3, f32);
    a4 += xv*ldv(w, wo+4, f32);
    a5 += xv*ldv(w, wo+5, f32);
    a6 += xv*ldv(w, wo+6, f32);
  }
  #pragma unroll
  for (int o = 32; o > 0; o >>= 1){
    a0 += __shfl_xor(a0, o); a1 += __shfl_xor(a1, o); a2 += __shfl_xor(a2, o);
    a3 += __shfl_xor(a3, o); a4 += __shfl_xor(a4, o); a5 += __shfl_xor(a5, o);
    a6 += __shfl_xor(a6, o);
  }
  if (lane == 0){
    long long o0 = (long long)row*7;
    if (f32){
      float* op = (float*)out;
      op[o0+0]=a0; op[o0+1]=a1; op[o0+2]=a2; op[o0+3]=a3;
      op[o0+4]=a4; op[o0+5]=a5; op[o0+6]=a6;
    } else {
      u16* op = (u16*)out;
      op[o0+0]=f2b(a0); op[o0+1]=f2b(a1); op[o0+2]=f2b(a2); op[o0+3]=f2b(a3);
      op[o0+4]=f2b(a4); op[o0+5]=f2b(a5); op[o0+6]=f2b(a6);
    }
  }
}

// ---------------- launch ----------------
extern "C" void kernel_launch(void* const* d_in, const int* in_sizes, int n_in,
                              void* d_out, int out_size, void* d_ws, size_t ws_size,
                              hipStream_t stream)
{
  (void)in_sizes; (void)n_in; (void)out_size;
  #define IN(i) ((const void*)d_in[i])
  const u16* det = (const u16*)d_in[20];
  float* ws   = (float*)d_ws;
  float* encx = ws + OFF_ENCX;
  float* decx = ws + OFF_DECX;
  u16*   qb   = (u16*)(ws + OFF_QB);
  u16*   kb   = (u16*)(ws + OFF_KB);
  u16*   vb   = (u16*)(ws + OFF_VB);
  int*   nbr  = (int*)(ws + OFF_NBR);
  bool haveShadow = ws_size >= WS_NEED;
  bool haveWtAll  = ws_size >= WS_NEED2;
  u16*   encb = haveShadow ? (u16*)(ws + OFF_ENCB) : nullptr;
  u16*   decb = haveShadow ? (u16*)(ws + OFF_DECB) : nullptr;
  u16*   WtAll = (u16*)(ws + OFF_WT);
  // phase-disjoint aliases (fallback path + temporaries)
  float* tmp1  = ws + OFF_VB;
  u16*   WtE3f = (u16*)(ws + OFF_VB + (size_t)BSZ*S1*DM);
  u16*   WtEOf = WtE3f + (size_t)2304*512;
  u16*   WtE1f = WtEOf + (size_t)768*512;
  u16*   WtE2f = WtE1f + (size_t)512*512;
  u16*   WtD3f = (u16*)(ws + OFF_QB + (size_t)BSZ*L_IN*HD/2);
  u16*   WtDOf = WtD3f + (size_t)2304*512;
  u16*   WtD1f = WtDOf + (size_t)768*512;
  u16*   WtD2f = WtD1f + (size_t)512*512;
  u16*   tmph  = (u16*)(ws + OFF_KB);
  float* embE  = ws + OFF_VB;
  float* Wc    = ws + OFF_QB;
  float* bdown = ws + OFF_KB;
  float* bconv = bdown + (size_t)BSZ*L_IN*128;
  float* bup   = bconv + (size_t)BSZ*54*128;

  const int RPe = 111, rpxE = 14;
  const int RPd = 84,  rpxD = 11;

  build_nbr_kernel<<<1, 256, 0, stream>>>(nbr);
  if (haveWtAll)
    wt_all<<<8*2048, 256, 0, stream>>>(IN(22), IN(24), IN(26), IN(28), IN(32), IN(34),
                                       IN(38), IN(40), IN(42), IN(44), IN(48), IN(50),
                                       WtAll, det);

  embed_fast<<<1344, 256, 0, stream>>>(IN(0), IN(1), IN(4), IN(5), IN(6), det, embE, nullptr);
  embed_fast<<<1344, 256, 0, stream>>>(IN(2), IN(3), IN(7), IN(8), IN(9), det, decx, decb);

  // bottleneck
  wc_kernel<<<(3*512*128)/256, 256, 0, stream>>>(IN(12), Wc, det);
  gemm_k<<<dim3(128/BN, (BSZ*L_IN)/BM), 256, 0, stream>>>(
      embE, IN(10), 0, IN(11), 0, bdown, det, 512, 128);
  conv_gemm<<<dim3(2, (BSZ*42)/BM), 256, 0, stream>>>(
      bdown, L_IN, 0, bconv, 54, 0, 42, Wc, IN(13), IN(14), IN(15), IN(16), IN(17), det, 0);
  conv_gemm<<<dim3(2, (BSZ*10)/BM), 256, 0, stream>>>(
      bconv, 54, 0, bconv, 54, 42, 10, Wc + 65536, IN(13), IN(14), IN(15), IN(16), IN(17), det, 1);
  conv_gemm<<<dim3(2, (BSZ*2)/BM), 256, 0, stream>>>(
      bconv, 54, 42, bconv, 54, 52, 2, Wc + 131072, IN(13), IN(14), IN(15), IN(16), IN(17), det, 2);
  gemm_k<<<dim3(512/BN, (BSZ*54)/BM), 256, 0, stream>>>(
      bconv, IN(18), 0, IN(19), 0, bup, det, 128, 512);
  concat_ln_kernel<<<(BSZ*S1)/4, 256, 0, stream>>>(embE, bup, IN(20), IN(21), encx, encb, det);

  // encoder layers
  for (int i = 0; i < 6; ++i){
    long long wO = (long long)i*512*768, oO = (long long)i*768*512;
    long long bO = (long long)i*768, dO = (long long)i*512;
    long long fO = (long long)i*512*512;
    u16 *Wt3, *WtO, *Wt1, *Wt2;
    if (haveWtAll){
      u16* base = WtAll + (size_t)i*WT_SLOT;
      Wt3 = base;
      WtO = base + (size_t)2304*512;
      Wt1 = WtO + (size_t)512*768;
      Wt2 = Wt1 + (size_t)512*512;
    } else {
      wt_batch<<<2048, 256, 0, stream>>>(IN(22), IN(24), IN(26), IN(28), IN(32), IN(34),
                                         wO, oO, fO, WtE3f, WtEOf, WtE1f, WtE2f, det);
      Wt3 = WtE3f; WtO = WtEOf; Wt1 = WtE1f; Wt2 = WtE2f;
    }
    if (haveShadow)
      gemm_qkv<1><<<8*rpxE*18, 256, 0, stream>>>(
          encb, Wt3, IN(23), IN(25), IN(27), bO, qb, kb, vb, det, S1, S1, 0, RPe, 18, rpxE);
    else
      gemm_qkv<0><<<8*rpxE*18, 256, 0, stream>>>(
          encx, Wt3, IN(23), IN(25), IN(27), bO, qb, kb, vb, det, S1, S1, 0, RPe, 18, rpxE);
    attn_enc_sparse<<<(BSZ*S1*NHD)/16, 256, 0, stream>>>(qb, kb, vb, nbr);
    gemm_mfma<2,1,0><<<8*rpxE*4, 256, 0, stream>>>(
        qb, WtO, IN(29), dO, encx, tmp1, det, 768, 512, S1, S1, 0, RPe, 4, rpxE);
    ln_kernel<<<(BSZ*S1)/4, 256, 0, stream>>>(tmp1, IN(30), dO, IN(31), dO, 1e-6f, encx, encb, det);
    if (haveShadow)
      gemm_mfma<1,1,1><<<8*rpxE*4, 256, 0, stream>>>(
          encb, Wt1, IN(33), dO, nullptr, tmph, det, 512, 512, S1, S1, 0, RPe, 4, rpxE);
    else
      gemm_mfma<1,0,1><<<8*rpxE*4, 256, 0, stream>>>(
          encx, Wt1, IN(33), dO, nullptr, tmph, det, 512, 512, S1, S1, 0, RPe, 4, rpxE);
    gemm_mfma<2,1,0><<<8*rpxE*4, 256, 0, stream>>>(
        tmph, Wt2, IN(35), dO, encx, tmp1, det, 512, 512, S1, S1, 0, RPe, 4, rpxE);
    ln_kernel<<<(BSZ*S1)/4, 256, 0, stream>>>(tmp1, IN(36), dO, IN(37), dO, 1e-6f, encx, encb, det);
  }

  // decoder layers
  for (int i = 0; i < 2; ++i){
    long long wO = (long long)i*512*768, oO = (long long)i*768*512;
    long long bO = (long long)i*768, dO = (long long)i*512;
    long long fO = (long long)i*512*512;
    u16 *Wt3, *WtO, *Wt1, *Wt2;
    if (haveWtAll){
      u16* base = WtAll + (size_t)(6+i)*WT_SLOT;
      Wt3 = base;
      WtO = base + (size_t)2304*512;
      Wt1 = WtO + (size_t)512*768;
      Wt2 = Wt1 + (size_t)512*512;
    } else {
      wt_batch<<<2048, 256, 0, stream>>>(IN(38), IN(40), IN(42), IN(44), IN(48), IN(50),
                                         wO, oO, fO, WtD3f, WtDOf, WtD1f, WtD2f, det);
      Wt3 = WtD3f; WtO = WtDOf; Wt1 = WtD1f; Wt2 = WtD2f;
    }
    if (haveShadow){
      gemm_mfma<0,1,1><<<8*rpxD*6, 256, 0, stream>>>(
          decb, Wt3, IN(39), bO, nullptr, qb, det, 512, 768, L_IN, L_IN, 0, RPd, 6, rpxD);
      gemm_qkv<1><<<8*rpxE*12, 256, 0, stream>>>(
          encb, Wt3 + (size_t)768*512, IN(41), IN(43), IN(43), bO, kb, vb, vb, det, S1, SKV, 0, RPe, 12, rpxE);
      gemm_qkv<1><<<8*rpxD*12, 256, 0, stream>>>(
          decb, Wt3 + (size_t)768*512, IN(41), IN(43), IN(43), bO, kb, vb, vb, det, L_IN, SKV, S1, RPd, 12, rpxD);
    } else {
      gemm_mfma<0,0,1><<<8*rpxD*6, 256, 0, stream>>>(
          decx, Wt3, IN(39), bO, nullptr, qb, det, 512, 768, L_IN, L_IN, 0, RPd, 6, rpxD);
      gemm_qkv<0><<<8*rpxE*12, 256, 0, stream>>>(
          encx, Wt3 + (size_t)768*512, IN(41), IN(43), IN(43), bO, kb, vb, vb, det, S1, SKV, 0, RPe, 12, rpxE);
      gemm_qkv<0><<<8*rpxD*12, 256, 0, stream>>>(
          decx, Wt3 + (size_t)768*512, IN(41), IN(43), IN(43), bO, kb, vb, vb, det, L_IN, SKV, S1, RPd, 12, rpxD);
    }
    attn_dec_mfma<<<dim3(3, NHD, BSZ), 256, 0, stream>>>(qb, kb, vb);
    gemm_mfma<2,1,0><<<8*rpxD*4, 256, 0, stream>>>(
        qb, WtO, IN(45), dO, decx, tmp1, det, 768, 512, L_IN, L_IN, 0, RPd, 4, rpxD);
    ln_kernel<<<(BSZ*L_IN)/4, 256, 0, stream>>>(tmp1, IN(46), dO, IN(47), dO, 1e-6f, decx, decb, det);
    if (haveShadow)
      gemm_mfma<1,1,1><<<8*rpxD*4, 256, 0, stream>>>(
          decb, Wt1, IN(49), dO, nullptr, tmph, det, 512, 512, L_IN, L_IN, 0, RPd, 4, rpxD);
    else
      gemm_mfma<1,0,1><<<8*rpxD*4, 256, 0, stream>>>(
          decx, Wt1, IN(49), dO, nullptr, tmph, det, 512, 512, L_IN, L_IN, 0, RPd, 4, rpxD);
    gemm_mfma<2,1,0><<<8*rpxD*4, 256, 0, stream>>>(
        tmph, Wt2, IN(51), dO, decx, tmp1, det, 512, 512, L_IN, L_IN, 0, RPd, 4, rpxD);
    ln_kernel<<<(BSZ*L_IN)/4, 256, 0, stream>>>(tmp1, IN(52), dO, IN(53), dO, 1e-6f, decx, decb, det);
  }

  pred_kernel<<<((BSZ*L_IN+3)/4), 256, 0, stream>>>(decx, IN(54), d_out, det);
  #undef IN
}

// Round 4
// 2753.456 us; speedup vs baseline: 1.1483x; 1.0425x over previous
//
#include <hip/hip_runtime.h>
#include <cstdint>
#include <cstddef>

// ---------------- model constants ----------------
#define BSZ   64
#define L_IN  168
#define S1    222
#define SKV   390
#define DM    512
#define HD    768
#define NHD   6
#define DK    128

typedef unsigned short u16;
typedef unsigned int u32;
typedef __attribute__((ext_vector_type(8))) short bf16x8;
typedef __attribute__((ext_vector_type(4))) float f32x4v;

// ---------------- bf16 helpers ----------------
__device__ inline float b2f(u16 u){
  union { u32 i; float f; } v; v.i = ((u32)u) << 16; return v.f;
}
__device__ inline u16 f2b(float f){
  union { float f; u32 i; } v; v.f = f;
  u32 x = v.i;
  return (u16)((x + 0x7fffu + ((x >> 16) & 1u)) >> 16);
}
__device__ inline u32 pk2(float a, float b){
  return ((u32)f2b(b) << 16) | (u32)f2b(a);
}
__device__ inline float ldv(const void* p, long long i, bool f32){
  return f32 ? ((const float*)p)[i] : b2f(((const u16*)p)[i]);
}
__device__ inline float4 ldv4(const void* p, long long i, bool f32){
  if (f32) return *(const float4*)((const float*)p + i);
  ushort4 w = *(const ushort4*)((const u16*)p + i);
  return make_float4(b2f(w.x), b2f(w.y), b2f(w.z), b2f(w.w));
}
__device__ inline bool is_f32(const u16* det){ return det[0] != 0x3F80; }
__device__ inline void unpack8(uint4 w, float* f){
  union { u32 i; float fl; } a;
  a.i = w.x << 16;          f[0] = a.fl;
  a.i = w.x & 0xffff0000u;  f[1] = a.fl;
  a.i = w.y << 16;          f[2] = a.fl;
  a.i = w.y & 0xffff0000u;  f[3] = a.fl;
  a.i = w.z << 16;          f[4] = a.fl;
  a.i = w.z & 0xffff0000u;  f[5] = a.fl;
  a.i = w.w << 16;          f[6] = a.fl;
  a.i = w.w & 0xffff0000u;  f[7] = a.fl;
}

// async global->LDS, 16B per lane; dest must be wave-uniform (HW: base + lane*16)
__device__ inline void gload_lds16(const void* g, void* l){
  __builtin_amdgcn_global_load_lds((const __attribute__((address_space(1))) void*)g,
                                   (__attribute__((address_space(3))) void*)l, 16, 0, 0);
}

// ---------------- workspace layout (float-equivalent offsets) ----------------
constexpr size_t OFF_ENCX = 0;
constexpr size_t OFF_DECX = OFF_ENCX + (size_t)BSZ*S1*DM;
constexpr size_t OFF_QB   = OFF_DECX + (size_t)BSZ*L_IN*DM;
constexpr size_t OFF_KB   = OFF_QB   + (size_t)BSZ*S1*HD/2;
constexpr size_t OFF_VB   = OFF_KB   + (size_t)BSZ*SKV*HD/2;
constexpr size_t OFF_NBR  = OFF_VB   + (size_t)BSZ*SKV*HD/2;
constexpr size_t OFF_ENCB = OFF_NBR  + 4096;
constexpr size_t OFF_DECB = OFF_ENCB + (size_t)BSZ*S1*DM/2;
constexpr size_t OFF_WT   = OFF_DECB + (size_t)BSZ*L_IN*DM/2;     // all-layer Wt: 8 slots x 2,097,152 u16
constexpr size_t WT_SLOT  = 2097152;                               // u16 per layer slot
constexpr size_t WS_NEED  = (OFF_WT) * 4;                          // shadow path
constexpr size_t WS_NEED2 = (OFF_WT + 8*WT_SLOT/2) * 4;            // + wt_all region

// ---------------- PAM sparsity ----------------
__device__ inline int scale_of(int i, int& ii){
  if (i < 168){ ii = i;       return 0; }
  if (i < 210){ ii = i - 168; return 1; }
  if (i < 220){ ii = i - 210; return 2; }
  ii = i - 220; return 3;
}
__device__ inline bool pam_ok(int i, int j){
  int ii, jj;
  int li = scale_of(i, ii);
  int lj = scale_of(j, jj);
  const int n[4] = {168, 42, 10, 2};
  if (li == lj){ int d = ii - jj; return (d <= 1 && d >= -1); }
  if (li == lj + 1){ int lo = ii*4, hi = (ii == n[li]-1) ? n[lj] : ii*4+4; return (jj >= lo && jj < hi); }
  if (lj == li + 1){ int lo = jj*4, hi = (jj == n[lj]-1) ? n[li] : jj*4+4; return (ii >= lo && ii < hi); }
  return false;
}
__global__ void build_nbr_kernel(int* __restrict__ nbr){
  int q = blockIdx.x * 256 + threadIdx.x;
  if (q >= S1) return;
  int cnt = 0;
  int list[12];
  for (int j = 0; j < S1; ++j)
    if (pam_ok(q, j) && cnt < 12) list[cnt++] = j;
  #pragma unroll
  for (int t = 0; t < 12; ++t) nbr[q*12 + t] = (t < cnt) ? list[t] : -1;
}

// ---------------- embedding: register-resident weights, grid-stride rows ----
__global__ __launch_bounds__(256)
void embed_fast(const void* __restrict__ x, const void* __restrict__ t,
                const void* __restrict__ cw, const void* __restrict__ tw,
                const void* __restrict__ tb, const u16* __restrict__ det,
                float* __restrict__ out, u16* __restrict__ out2)
{
  bool f32 = is_f32(det);
  int d0 = threadIdx.x;
  int d1 = threadIdx.x + 256;

  float w0[21], w1[21];
  #pragma unroll
  for (int i = 0; i < 21; ++i){
    w0[i] = ldv(cw, (long long)d0*21 + i, f32);
    w1[i] = ldv(cw, (long long)d1*21 + i, f32);
  }
  float tw0[4], tw1[4];
  #pragma unroll
  for (int f = 0; f < 4; ++f){
    tw0[f] = ldv(tw, (long long)f*DM + d0, f32);
    tw1[f] = ldv(tw, (long long)f*DM + d1, f32);
  }
  float tb0 = ldv(tb, d0, f32);
  float tb1 = ldv(tb, d1, f32);
  float dv0 = __expf(-(float)(d0 & ~1) * (9.210340371976184f/512.f));
  float dv1 = __expf(-(float)(d1 & ~1) * (9.210340371976184f/512.f));
  bool odd0 = (d0 & 1), odd1 = (d1 & 1);

  const int nRows = BSZ * L_IN;
  for (int row = blockIdx.x; row < nRows; row += gridDim.x){
    int b = row / L_IN, l = row - b*L_IN;
    float acc0 = 0.f, acc1 = 0.f;
    #pragma unroll
    for (int tt = 0; tt < 3; ++tt){
      int ls = l + tt - 1;
      ls = (ls < 0) ? ls + L_IN : (ls >= L_IN ? ls - L_IN : ls);
      long long xo = ((long long)(b*L_IN + ls))*7;
      #pragma unroll
      for (int c = 0; c < 7; ++c){
        float xv = ldv(x, xo + c, f32);
        acc0 += xv * w0[c*3 + tt];
        acc1 += xv * w1[c*3 + tt];
      }
    }
    float ang0 = (float)l * dv0;
    float ang1 = (float)l * dv1;
    acc0 += odd0 ? __cosf(ang0) : __sinf(ang0);
    acc1 += odd1 ? __cosf(ang1) : __sinf(ang1);
    long long to = ((long long)row)*4;
    #pragma unroll
    for (int f = 0; f < 4; ++f){
      float tv = ldv(t, to + f, f32);
      acc0 += tv * tw0[f];
      acc1 += tv * tw1[f];
    }
    acc0 += tb0;
    acc1 += tb1;
    size_t o = (size_t)row*DM;
    out[o + d0] = acc0;
    out[o + d1] = acc1;
    if (out2){
      out2[o + d0] = f2b(acc0);
      out2[o + d1] = f2b(acc1);
    }
  }
}

// ---------------- weight transpose helpers ----------------
__device__ inline void trans32(const void* W, long long wOff, int K, int N, int k0, int n0,
                               u16* __restrict__ Wt, bool f32, float* tb, int tid)
{
  int c = tid & 31, r0 = tid >> 5;
  #pragma unroll
  for (int rr = 0; rr < 32; rr += 8)
    tb[(r0+rr)*33 + c] = ldv(W, wOff + (long long)(k0+r0+rr)*N + n0 + c, f32);
  __syncthreads();
  #pragma unroll
  for (int rr = 0; rr < 32; rr += 8)
    Wt[(size_t)(n0+r0+rr)*K + k0 + c] = f2b(tb[c*33 + r0+rr]);
}

__device__ inline void wt_layer_body(int t, const void* wq, const void* wk, const void* wv,
                                     const void* wo, const void* w1, const void* w2,
                                     long long wO, long long oO, long long fO,
                                     u16* Wt3, u16* WtO, u16* Wt1, u16* Wt2,
                                     bool f32, float* tb, int tid)
{
  if (t < 384)       trans32(wq, wO, 512, 768, (t/24)*32, (t%24)*32, Wt3,               f32, tb, tid);
  else if (t < 768)  { int u = t-384;  trans32(wk, wO, 512, 768, (u/24)*32, (u%24)*32, Wt3 + (size_t)768*512,  f32, tb, tid); }
  else if (t < 1152) { int u = t-768;  trans32(wv, wO, 512, 768, (u/24)*32, (u%24)*32, Wt3 + (size_t)1536*512, f32, tb, tid); }
  else if (t < 1536) { int u = t-1152; trans32(wo, oO, 768, 512, (u/16)*32, (u%16)*32, WtO, f32, tb, tid); }
  else if (t < 1792) { int u = t-1536; trans32(w1, fO, 512, 512, (u/16)*32, (u%16)*32, Wt1, f32, tb, tid); }
  else               { int u = t-1792; trans32(w2, fO, 512, 512, (u/16)*32, (u%16)*32, Wt2, f32, tb, tid); }
}

// per-layer fallback
__global__ __launch_bounds__(256)
void wt_batch(const void* wq, const void* wk, const void* wv,
              const void* wo, const void* w1, const void* w2,
              long long wO, long long oO, long long fO,
              u16* __restrict__ Wt3, u16* __restrict__ WtO,
              u16* __restrict__ Wt1, u16* __restrict__ Wt2,
              const u16* __restrict__ det)
{
  __shared__ float tb[32*33];
  bool f32 = is_f32(det);
  wt_layer_body(blockIdx.x, wq, wk, wv, wo, w1, w2, wO, oO, fO, Wt3, WtO, Wt1, Wt2,
                f32, tb, threadIdx.x);
}

// all 8 layers in one launch: slots 0..5 = enc layers, 6..7 = dec layers
__global__ __launch_bounds__(256)
void wt_all(const void* ewq, const void* ewk, const void* ewv, const void* ewo,
            const void* ew1, const void* ew2,
            const void* dwq, const void* dwk, const void* dwv, const void* dwo,
            const void* dw1, const void* dw2,
            u16* __restrict__ WtAll, const u16* __restrict__ det)
{
  __shared__ float tb[32*33];
  bool f32 = is_f32(det);
  int s = blockIdx.x >> 11;
  int t = blockIdx.x & 2047;
  bool enc = s < 6;
  int li = enc ? s : s - 6;
  long long wO = (long long)li*512*768, oO = (long long)li*768*512, fO = (long long)li*512*512;
  u16* base = WtAll + (size_t)s*WT_SLOT;
  wt_layer_body(t,
                enc ? ewq : dwq, enc ? ewk : dwk, enc ? ewv : dwv,
                enc ? ewo : dwo, enc ? ew1 : dw1, enc ? ew2 : dw2,
                wO, oO, fO,
                base, base + (size_t)2304*512,
                base + (size_t)2304*512 + (size_t)512*768,
                base + (size_t)2304*512 + (size_t)512*768 + (size_t)512*512,
                f32, tb, threadIdx.x);
}

// ---------------- XCD-exclusive row-panel swizzle (CN-wide col panels) --------
template<int CN>
__device__ inline bool swzT(int t, int RP, int CP, int rpx, int& row0, int& col0){
  int xcd = t & 7, j = t >> 3;
  int rp = xcd + 8*(j % rpx);
  int cp = j / rpx;
  if (rp >= RP || cp >= CP) return false;
  row0 = rp*128; col0 = cp*CN;
  return true;
}

// ---------------- MFMA GEMM: C = A[M,K] @ W via Wt bf16 [N,K] ----------------
// Tile 128 x CN (CN = 128 or 64). CN=64 doubles the grid for narrow-N GEMMs
// (N<=768) which were grid-starved at 1.7 blocks/CU with 128-wide tiles.
// bf16 staging via global_load_lds w=16 with pre-swizzled SOURCE (linear LDS dest).
template<int EPI, int ABF, int CBF, int CN>
__global__ __launch_bounds__(256)
void gemm_mfma(const void* __restrict__ Av, const u16* __restrict__ Wt,
               const void* __restrict__ bias, long long bOff, const float* __restrict__ R,
               void* __restrict__ Cv, const u16* __restrict__ det,
               int K, int N, int La, int Lc, int off, int RP, int CP, int rpx)
{
  constexpr int NF = CN/32;                  // n-frags (16-wide) per wave
  __shared__ u16 As[128][64];
  __shared__ u16 Bs[CN][64];
  bool f32 = is_f32(det);
  int tid = threadIdx.x;
  int row0, col0;
  if (!swzT<CN>(blockIdx.x, RP, CP, rpx, row0, col0)) return;
  int wave = tid >> 6, lane = tid & 63;
  int wm = (wave >> 1)*64, wn = (wave & 1)*(CN/2);
  int lm = lane & 15, quad = lane >> 4;
  int sr = tid >> 1;
  int sh = (tid & 1) * 32;
  int swzS = (sr & 7) * 8;
  int r8 = lane >> 3;                 // 0..7 (row within 8-row wave chunk)
  int scw = ((lane & 7)*8) ^ (r8*8);  // pre-swizzled source col (u16 units)
  f32x4v acc[4][NF];
  #pragma unroll
  for (int i = 0; i < 4; ++i)
    #pragma unroll
    for (int j = 0; j < NF; ++j) acc[i][j] = (f32x4v){0.f,0.f,0.f,0.f};

  for (int k0 = 0; k0 < K; k0 += 64){
    if (ABF){
      const u16* base = (const u16*)Av + (size_t)row0*K + k0 + scw;
      #pragma unroll
      for (int j = 0; j < 4; ++j){
        int r = wave*32 + j*8;
        gload_lds16(base + (size_t)(r + r8)*K, &As[r][0]);
      }
    } else {
      const float* src = (const float*)Av + (size_t)(row0+sr)*K + k0 + sh;
      #pragma unroll
      for (int j = 0; j < 4; ++j){
        float4 f0 = *(const float4*)(src + 8*j);
        float4 f1 = *(const float4*)(src + 8*j + 4);
        uint4 o;
        o.x = pk2(f0.x, f0.y); o.y = pk2(f0.z, f0.w);
        o.z = pk2(f1.x, f1.y); o.w = pk2(f1.z, f1.w);
        *(uint4*)&As[sr][(sh + 8*j)^swzS] = o;
      }
    }
    {
      const u16* base = Wt + (size_t)col0*K + k0 + scw;
      #pragma unroll
      for (int j = 0; j < CN/32; ++j){
        int r = wave*(CN/4) + j*8;
        gload_lds16(base + (size_t)(r + r8)*K, &Bs[r][0]);
      }
    }
    __syncthreads();
    bf16x8 af[4][2], bfr[NF][2];
    #pragma unroll
    for (int mi = 0; mi < 4; ++mi){
      int m = wm + mi*16 + lm;
      int sz = (m & 7)*8;
      af[mi][0] = *(const bf16x8*)&As[m][(quad*8) ^ sz];
      af[mi][1] = *(const bf16x8*)&As[m][(32 + quad*8) ^ sz];
    }
    #pragma unroll
    for (int ni = 0; ni < NF; ++ni){
      int n = wn + ni*16 + lm;
      int sz = (n & 7)*8;
      bfr[ni][0] = *(const bf16x8*)&Bs[n][(quad*8) ^ sz];
      bfr[ni][1] = *(const bf16x8*)&Bs[n][(32 + quad*8) ^ sz];
    }
    #pragma unroll
    for (int mi = 0; mi < 4; ++mi)
      #pragma unroll
      for (int ni = 0; ni < NF; ++ni){
        acc[mi][ni] = __builtin_amdgcn_mfma_f32_16x16x32_bf16(af[mi][0], bfr[ni][0], acc[mi][ni], 0, 0, 0);
        acc[mi][ni] = __builtin_amdgcn_mfma_f32_16x16x32_bf16(af[mi][1], bfr[ni][1], acc[mi][ni], 0, 0, 0);
      }
    __syncthreads();
  }
  #pragma unroll
  for (int mi = 0; mi < 4; ++mi){
    #pragma unroll
    for (int r = 0; r < 4; ++r){
      int row = row0 + wm + mi*16 + quad*4 + r;
      int bb = row / La, l = row - bb*La;
      size_t crow = ((size_t)bb*Lc + off + l)*(size_t)N;
      #pragma unroll
      for (int ni = 0; ni < NF; ++ni){
        int col = col0 + wn + ni*16 + lm;
        float vv = acc[mi][ni][r] + ldv(bias, bOff + col, f32);
        if (EPI == 1) vv = 0.5f*vv*(1.f + erff(vv*0.70710678118654752f));
        if (EPI == 2) vv += R[crow + col];
        if (CBF) ((u16*)Cv)[crow + col] = f2b(vv);
        else     ((float*)Cv)[crow + col] = vv;
      }
    }
  }
}

// ---------------- fused QKV / KV MFMA GEMM (K=512), swizzled ----------------
template<int ABF>
__global__ __launch_bounds__(256)
void gemm_qkv(const void* __restrict__ Av, const u16* __restrict__ Wt,
              const void* __restrict__ b0, const void* __restrict__ b1, const void* __restrict__ b2,
              long long bOff, u16* __restrict__ o0, u16* __restrict__ o1, u16* __restrict__ o2,
              const u16* __restrict__ det, int La, int Lc, int off, int RP, int CP, int rpx)
{
  __shared__ u16 As[128][64];
  __shared__ u16 Bs[128][64];
  bool f32 = is_f32(det);
  const int K = 512;
  int tid = threadIdx.x;
  int row0, col0;
  if (!swzT<128>(blockIdx.x, RP, CP, rpx, row0, col0)) return;
  int wave = tid >> 6, lane = tid & 63;
  int wm = (wave >> 1)*64, wn = (wave & 1)*64;
  int lm = lane & 15, quad = lane >> 4;
  int sr = tid >> 1;
  int sh = (tid & 1) * 32;
  int swzS = (sr & 7) * 8;
  int r8 = lane >> 3;
  int scw = ((lane & 7)*8) ^ (r8*8);
  f32x4v acc[4][4];
  #pragma unroll
  for (int i = 0; i < 4; ++i)
    #pragma unroll
    for (int j = 0; j < 4; ++j) acc[i][j] = (f32x4v){0.f,0.f,0.f,0.f};

  for (int k0 = 0; k0 < K; k0 += 64){
    if (ABF){
      const u16* base = (const u16*)Av + (size_t)row0*K + k0 + scw;
      #pragma unroll
      for (int j = 0; j < 4; ++j){
        int r = wave*32 + j*8;
        gload_lds16(base + (size_t)(r + r8)*K, &As[r][0]);
      }
    } else {
      const float* src = (const float*)Av + (size_t)(row0+sr)*K + k0 + sh;
      #pragma unroll
      for (int j = 0; j < 4; ++j){
        float4 f0 = *(const float4*)(src + 8*j);
        float4 f1 = *(const float4*)(src + 8*j + 4);
        uint4 o;
        o.x = pk2(f0.x, f0.y); o.y = pk2(f0.z, f0.w);
        o.z = pk2(f1.x, f1.y); o.w = pk2(f1.z, f1.w);
        *(uint4*)&As[sr][(sh + 8*j)^swzS] = o;
      }
    }
    {
      const u16* base = Wt + (size_t)col0*K + k0 + scw;
      #pragma unroll
      for (int j = 0; j < 4; ++j){
        int r = wave*32 + j*8;
        gload_lds16(base + (size_t)(r + r8)*K, &Bs[r][0]);
      }
    }
    __syncthreads();
    bf16x8 af[4][2], bfr[4][2];
    #pragma unroll
    for (int mi = 0; mi < 4; ++mi){
      int m = wm + mi*16 + lm;
      int sz = (m & 7)*8;
      af[mi][0] = *(const bf16x8*)&As[m][(quad*8) ^ sz];
      af[mi][1] = *(const bf16x8*)&As[m][(32 + quad*8) ^ sz];
    }
    #pragma unroll
    for (int ni = 0; ni < 4; ++ni){
      int n = wn + ni*16 + lm;
      int sz = (n & 7)*8;
      bfr[ni][0] = *(const bf16x8*)&Bs[n][(quad*8) ^ sz];
      bfr[ni][1] = *(const bf16x8*)&Bs[n][(32 + quad*8) ^ sz];
    }
    #pragma unroll
    for (int mi = 0; mi < 4; ++mi)
      #pragma unroll
      for (int ni = 0; ni < 4; ++ni){
        acc[mi][ni] = __builtin_amdgcn_mfma_f32_16x16x32_bf16(af[mi][0], bfr[ni][0], acc[mi][ni], 0, 0, 0);
        acc[mi][ni] = __builtin_amdgcn_mfma_f32_16x16x32_bf16(af[mi][1], bfr[ni][1], acc[mi][ni], 0, 0, 0);
      }
    __syncthreads();
  }
  #pragma unroll
  for (int mi = 0; mi < 4; ++mi){
    #pragma unroll
    for (int r = 0; r < 4; ++r){
      int row = row0 + wm + mi*16 + quad*4 + r;
      int bb = row / La, l = row - bb*La;
      size_t crow = ((size_t)bb*Lc + off + l)*(size_t)HD;
      #pragma unroll
      for (int ni = 0; ni < 4; ++ni){
        int col = col0 + wn + ni*16 + lm;
        int sel = (col >= 1536) ? 2 : (col >= 768 ? 1 : 0);
        int colr = col - sel*768;
        const void* bp = (sel == 0) ? b0 : (sel == 1) ? b1 : b2;
        u16* dst = (sel == 0) ? o0 : (sel == 1) ? o1 : o2;
        float vv = acc[mi][ni][r] + ldv(bp, bOff + colr, f32);
        dst[crow + colr] = f2b(vv);
      }
    }
  }
}

// ---------------- SIMT GEMM (bottleneck) ----------------
#define BM 64
#define BN 64
#define BK 16
__global__ __launch_bounds__(256)
void gemm_k(const float* __restrict__ A, const void* __restrict__ W, long long wOff,
            const void* __restrict__ bias, long long bOff,
            float* __restrict__ C, const u16* __restrict__ det, int K, int N)
{
  __shared__ float As2[BK][BM+4];
  __shared__ float Bs2[BK][BN+4];
  bool f32 = is_f32(det);
  int tid = threadIdx.x;
  int row0 = blockIdx.y * BM, col0 = blockIdx.x * BN;
  int ty = tid >> 4, tx = tid & 15;
  int lr = tid >> 2, lc4 = (tid & 3) << 2;
  int wr = tid >> 4, wc4 = (tid & 15) << 2;
  float acc[4][4] = {};
  for (int k0 = 0; k0 < K; k0 += BK){
    float4 av = *(const float4*)(A + (size_t)(row0 + lr)*K + k0 + lc4);
    As2[lc4+0][lr] = av.x; As2[lc4+1][lr] = av.y;
    As2[lc4+2][lr] = av.z; As2[lc4+3][lr] = av.w;
    float4 wv = ldv4(W, wOff + (long long)(k0 + wr)*N + col0 + wc4, f32);
    *(float4*)&Bs2[wr][wc4] = wv;
    __syncthreads();
    #pragma unroll
    for (int kk = 0; kk < BK; ++kk){
      float4 a  = *(const float4*)&As2[kk][ty << 2];
      float4 bb = *(const float4*)&Bs2[kk][tx << 2];
      acc[0][0] += a.x*bb.x; acc[0][1] += a.x*bb.y; acc[0][2] += a.x*bb.z; acc[0][3] += a.x*bb.w;
      acc[1][0] += a.y*bb.x; acc[1][1] += a.y*bb.y; acc[1][2] += a.y*bb.z; acc[1][3] += a.y*bb.w;
      acc[2][0] += a.z*bb.x; acc[2][1] += a.z*bb.y; acc[2][2] += a.z*bb.z; acc[2][3] += a.z*bb.w;
      acc[3][0] += a.w*bb.x; acc[3][1] += a.w*bb.y; acc[3][2] += a.w*bb.z; acc[3][3] += a.w*bb.w;
    }
    __syncthreads();
  }
  #pragma unroll
  for (int i = 0; i < 4; ++i){
    int r = row0 + (ty << 2) + i;
    size_t crow = (size_t)r*(size_t)N;
    #pragma unroll
    for (int j = 0; j < 4; ++j){
      int c = col0 + (tx << 2) + j;
      C[crow + c] = acc[i][j] + ldv(bias, bOff + c, f32);
    }
  }
}

// ---------------- conv weight reorder ----------------
__global__ void wc_kernel(const void* __restrict__ w, float* __restrict__ Wc,
                          const u16* __restrict__ det)
{
  bool f32 = is_f32(det);
  int idx = blockIdx.x * 256 + threadIdx.x;
  if (idx >= 3*512*128) return;
  int co = idx & 127;
  int kk = (idx >> 7) & 511;
  int lay = idx >> 16;
  int tt = kk >> 7, ci = kk & 127;
  Wc[idx] = ldv(w, (long long)lay*65536 + co*512 + ci*4 + tt, f32);
}

// ---------------- bottleneck conv as GEMM + BN + ELU ----------------
__global__ __launch_bounds__(256)
void conv_gemm(const float* __restrict__ in, int inStride, int inOff,
               float* __restrict__ out, int outStride, int outOff, int Lout,
               const float* __restrict__ Wc,
               const void* __restrict__ cb, const void* __restrict__ bg,
               const void* __restrict__ bb, const void* __restrict__ bm,
               const void* __restrict__ bv, const u16* __restrict__ det, int lay)
{
  __shared__ float As2[BK][BM+4];
  __shared__ float Bs2[BK][BN+4];
  bool f32 = is_f32(det);
  int tid = threadIdx.x;
  int row0 = blockIdx.y * BM, col0 = blockIdx.x * BN;
  int ty = tid >> 4, tx = tid & 15;
  int lr = tid >> 2, lc4 = (tid & 3) << 2;
  int wr = tid >> 4, wc4 = (tid & 15) << 2;
  int rs = row0 + lr;
  int bs = rs / Lout, js = rs - bs*Lout;
  const float* arow = in + ((size_t)(bs*inStride + inOff + js*4))*128;
  float acc[4][4] = {};
  for (int k0 = 0; k0 < 512; k0 += BK){
    float4 av = *(const float4*)(arow + k0 + lc4);
    As2[lc4+0][lr] = av.x; As2[lc4+1][lr] = av.y;
    As2[lc4+2][lr] = av.z; As2[lc4+3][lr] = av.w;
    float4 wv = *(const float4*)(Wc + (size_t)(k0 + wr)*128 + col0 + wc4);
    *(float4*)&Bs2[wr][wc4] = wv;
    __syncthreads();
    #pragma unroll
    for (int kk = 0; kk < BK; ++kk){
      float4 a  = *(const float4*)&As2[kk][ty << 2];
      float4 bb2 = *(const float4*)&Bs2[kk][tx << 2];
      acc[0][0] += a.x*bb2.x; acc[0][1] += a.x*bb2.y; acc[0][2] += a.x*bb2.z; acc[0][3] += a.x*bb2.w;
      acc[1][0] += a.y*bb2.x; acc[1][1] += a.y*bb2.y; acc[1][2] += a.y*bb2.z; acc[1][3] += a.y*bb2.w;
      acc[2][0] += a.z*bb2.x; acc[2][1] += a.z*bb2.y; acc[2][2] += a.z*bb2.z; acc[2][3] += a.z*bb2.w;
      acc[3][0] += a.w*bb2.x; acc[3][1] += a.w*bb2.y; acc[3][2] += a.w*bb2.z; acc[3][3] += a.w*bb2.w;
    }
    __syncthreads();
  }
  #pragma unroll
  for (int i = 0; i < 4; ++i){
    int r = row0 + (ty << 2) + i;
    int b = r / Lout, j = r - b*Lout;
    float* orow = out + ((size_t)(b*outStride + outOff + j))*128;
    #pragma unroll
    for (int jj = 0; jj < 4; ++jj){
      int co = col0 + (tx << 2) + jj;
      long long po = (long long)lay*128 + co;
      float a = acc[i][jj] + ldv(cb, po, f32);
      a = (a - ldv(bm, po, f32)) * rsqrtf(ldv(bv, po, f32) + 1e-5f) * ldv(bg, po, f32) + ldv(bb, po, f32);
      a = a > 0.f ? a : (__expf(a) - 1.f);
      orow[co] = a;
    }
  }
}

// ---------------- LayerNorm (4 rows/block, optional bf16 shadow) ----------------
__global__ __launch_bounds__(256)
void ln_kernel(const float* __restrict__ X, const void* __restrict__ g, long long gOff,
               const void* __restrict__ bt, long long bOff, float eps,
               float* __restrict__ Out, u16* __restrict__ OutB, const u16* __restrict__ det)
{
  bool f32 = is_f32(det);
  int row = blockIdx.x*4 + (threadIdx.x >> 6);
  int lane = threadIdx.x & 63;
  const float* xr = X + (size_t)row*DM;
  float v[8]; float s = 0.f;
  #pragma unroll
  for (int i = 0; i < 8; ++i){ v[i] = xr[lane + i*64]; s += v[i]; }
  #pragma unroll
  for (int o = 32; o > 0; o >>= 1) s += __shfl_xor(s, o);
  float mean = s * (1.f/512.f);
  float q = 0.f;
  #pragma unroll
  for (int i = 0; i < 8; ++i){ float d = v[i]-mean; q += d*d; }
  #pragma unroll
  for (int o = 32; o > 0; o >>= 1) q += __shfl_xor(q, o);
  float inv = rsqrtf(q*(1.f/512.f) + eps);
  float* orow = Out + (size_t)row*DM;
  #pragma unroll
  for (int i = 0; i < 8; ++i){
    int c = lane + i*64;
    float val = (v[i]-mean)*inv*ldv(g, gOff + c, f32) + ldv(bt, bOff + c, f32);
    orow[c] = val;
    if (OutB) OutB[(size_t)row*DM + c] = f2b(val);
  }
}

// ---------------- concat + LayerNorm(1e-5), 4 rows/block, optional shadow ----------------
__global__ __launch_bounds__(256)
void concat_ln_kernel(const float* __restrict__ emb, const float* __restrict__ up,
                      const void* __restrict__ g, const void* __restrict__ bt,
                      float* __restrict__ Out, u16* __restrict__ OutB, const u16* __restrict__ det)
{
  bool f32 = is_f32(det);
  int row = blockIdx.x*4 + (threadIdx.x >> 6);
  int lane = threadIdx.x & 63;
  int b = row / S1, l = row - b*S1;
  const float* xr = (l < L_IN) ? emb + ((size_t)(b*L_IN + l))*DM
                               : up  + ((size_t)(b*54 + (l - L_IN)))*DM;
  float v[8]; float s = 0.f;
  #pragma unroll
  for (int i = 0; i < 8; ++i){ v[i] = xr[lane + i*64]; s += v[i]; }
  #pragma unroll
  for (int o = 32; o > 0; o >>= 1) s += __shfl_xor(s, o);
  float mean = s * (1.f/512.f);
  float q = 0.f;
  #pragma unroll
  for (int i = 0; i < 8; ++i){ float d = v[i]-mean; q += d*d; }
  #pragma unroll
  for (int o = 32; o > 0; o >>= 1) q += __shfl_xor(q, o);
  float inv = rsqrtf(q*(1.f/512.f) + 1e-5f);
  float* orow = Out + (size_t)row*DM;
  #pragma unroll
  for (int i = 0; i < 8; ++i){
    int c = lane + i*64;
    float val = (v[i]-mean)*inv*ldv(g, c, f32) + ldv(bt, c, f32);
    orow[c] = val;
    if (OutB) OutB[(size_t)row*DM + c] = f2b(val);
  }
}

// ---------------- encoder attention: PAM-sparse, 16-lane unit per (b,q,h) ----------------
__global__ __launch_bounds__(256)
void attn_enc_sparse(u16* __restrict__ q, const u16* __restrict__ k,
                     const u16* __restrict__ v, const int* __restrict__ nbr)
{
  int u = blockIdx.x * 16 + (threadIdx.x >> 4);
  int lane16 = threadIdx.x & 15;
  int h = u % NHD;
  int bq = u / NHD;
  int b = bq / S1, qr = bq - b*S1;
  const float scale = 0.088388347648318447f;
  size_t rowoff = (size_t)bq*HD + h*DK + lane16*8;
  uint4 qw = *(const uint4*)(q + rowoff);
  float qd[8]; unpack8(qw, qd);
  const int* nb = nbr + qr*12;
  size_t base = (size_t)b*S1*HD + h*DK + lane16*8;
  float pj[12];
  #pragma unroll
  for (int j = 0; j < 12; ++j){
    int kg = nb[j];
    int kgc = kg < 0 ? 0 : kg;
    uint4 kw = *(const uint4*)(k + (size_t)kgc*HD + base);
    float kd[8]; unpack8(kw, kd);
    float p = qd[0]*kd[0] + qd[1]*kd[1] + qd[2]*kd[2] + qd[3]*kd[3]
            + qd[4]*kd[4] + qd[5]*kd[5] + qd[6]*kd[6] + qd[7]*kd[7];
    p += __shfl_xor(p, 1); p += __shfl_xor(p, 2);
    p += __shfl_xor(p, 4); p += __shfl_xor(p, 8);
    pj[j] = (kg >= 0) ? p*scale : -1e30f;
  }
  float m = -1e30f;
  #pragma unroll
  for (int j = 0; j < 12; ++j) m = fmaxf(m, pj[j]);
  float s = 0.f;
  #pragma unroll
  for (int j = 0; j < 12; ++j){ pj[j] = __expf(pj[j] - m); s += pj[j]; }
  float inv = 1.f / s;
  float o[8];
  #pragma unroll
  for (int i = 0; i < 8; ++i) o[i] = 0.f;
  #pragma unroll
  for (int j = 0; j < 12; ++j){
    int kg = nb[j];
    int kgc = kg < 0 ? 0 : kg;
    uint4 vw = *(const uint4*)(v + (size_t)kgc*HD + base);
    float vd[8]; unpack8(vw, vd);
    #pragma unroll
    for (int i = 0; i < 8; ++i) o[i] += pj[j]*vd[i];
  }
  uint4 ow;
  ow.x = pk2(o[0]*inv, o[1]*inv);
  ow.y = pk2(o[2]*inv, o[3]*inv);
  ow.z = pk2(o[4]*inv, o[5]*inv);
  ow.w = pk2(o[6]*inv, o[7]*inv);
  *(uint4*)(q + rowoff) = ow;
}

// ---------------- decoder attention: MFMA flash (v2) ----------------
#define FQT 64
__global__ __launch_bounds__(256)
void attn_dec_mfma(u16* __restrict__ q, const u16* __restrict__ k,
                   const u16* __restrict__ v)
{
  __shared__ __align__(16) u16 Ks[32][136];
  __shared__ __align__(16) u32 Vt[16][132];
  __shared__ __align__(16) u32 Pls[4][16][16];
  int b = blockIdx.z, h = blockIdx.y;
  int qt0 = blockIdx.x * FQT;
  int tid = threadIdx.x;
  int wave = tid >> 6, lane = tid & 63;
  int lm = lane & 15, quad = lane >> 4;
  const float scale = 0.088388347648318447f;
  const size_t qb0 = (size_t)b*L_IN*HD + (size_t)h*DK;
  const size_t kb0 = (size_t)b*SKV*HD + (size_t)h*DK;

  bf16x8 qf[4];
  {
    int qg = qt0 + wave*16 + lm;
    if (qg < L_IN){
      #pragma unroll
      for (int ks = 0; ks < 4; ++ks)
        qf[ks] = *(const bf16x8*)(q + qb0 + (size_t)qg*HD + ks*32 + quad*8);
    } else {
      #pragma unroll
      for (int ks = 0; ks < 4; ++ks) qf[ks] = (bf16x8){0,0,0,0,0,0,0,0};
    }
  }

  float mold[4], lsum[4];
  #pragma unroll
  for (int r = 0; r < 4; ++r){ mold[r] = -1e30f; lsum[r] = 0.f; }
  f32x4v oacc[8];
  #pragma unroll
  for (int f = 0; f < 8; ++f) oacc[f] = (f32x4v){0.f,0.f,0.f,0.f};

  int kEnd = S1 + qt0 + FQT; if (kEnd > SKV) kEnd = SKV;
  for (int kt0 = 0; kt0 < kEnd; kt0 += 32){
    __syncthreads();
    for (int i = tid*4; i < 32*128; i += 1024){
      int kk = i >> 7, d = i & 127;
      int kg = kt0 + kk;
      ushort4 w = make_ushort4(0,0,0,0);
      if (kg < SKV) w = *(const ushort4*)(k + kb0 + (size_t)kg*HD + d);
      *(ushort4*)&Ks[kk][d] = w;
    }
    for (int t2 = tid; t2 < 512; t2 += 256){
      int g = t2 & 31, p = t2 >> 5;
      int d0 = g*4;
      int kg0 = kt0 + p, kg1 = kt0 + p + 16;
      ushort4 a = make_ushort4(0,0,0,0), c = make_ushort4(0,0,0,0);
      if (kg0 < SKV) a = *(const ushort4*)(v + kb0 + (size_t)kg0*HD + d0);
      if (kg1 < SKV) c = *(const ushort4*)(v + kb0 + (size_t)kg1*HD + d0);
      uint4 o;
      o.x = (u32)a.x | ((u32)c.x << 16);
      o.y = (u32)a.y | ((u32)c.y << 16);
      o.z = (u32)a.z | ((u32)c.z << 16);
      o.w = (u32)a.w | ((u32)c.w << 16);
      *(uint4*)&Vt[p][d0] = o;
    }
    __syncthreads();
    f32x4v sacc[2];
    sacc[0] = (f32x4v){0.f,0.f,0.f,0.f};
    sacc[1] = (f32x4v){0.f,0.f,0.f,0.f};
    #pragma unroll
    for (int t = 0; t < 2; ++t)
      #pragma unroll
      for (int ks = 0; ks < 4; ++ks){
        bf16x8 kf = *(const bf16x8*)&Ks[t*16 + lm][ks*32 + quad*8];
        sacc[t] = __builtin_amdgcn_mfma_f32_16x16x32_bf16(qf[ks], kf, sacc[t], 0, 0, 0);
      }
    float p[2][4];
    #pragma unroll
    for (int r = 0; r < 4; ++r){
      int qg = qt0 + wave*16 + quad*4 + r;
      float s0, s1;
      {
        int kg = kt0 + lm;
        bool ok = (kg < SKV) && (qg < L_IN) && (kg <= S1 + qg);
        s0 = ok ? sacc[0][r]*scale : -1e30f;
      }
      {
        int kg = kt0 + 16 + lm;
        bool ok = (kg < SKV) && (qg < L_IN) && (kg <= S1 + qg);
        s1 = ok ? sacc[1][r]*scale : -1e30f;
      }
      float mn = fmaxf(s0, s1);
      #pragma unroll
      for (int o = 8; o > 0; o >>= 1) mn = fmaxf(mn, __shfl_xor(mn, o));
      float mi = fmaxf(mold[r], mn);
      float alpha = __expf(mold[r] - mi);
      mold[r] = mi;
      p[0][r] = __expf(s0 - mi);
      p[1][r] = __expf(s1 - mi);
      float rs = p[0][r] + p[1][r];
      #pragma unroll
      for (int o = 8; o > 0; o >>= 1) rs += __shfl_xor(rs, o);
      lsum[r] = lsum[r]*alpha + rs;
      #pragma unroll
      for (int f = 0; f < 8; ++f) oacc[f][r] *= alpha;
    }
    #pragma unroll
    for (int r = 0; r < 4; ++r)
      Pls[wave][quad*4+r][lm] = pk2(p[0][r], p[1][r]);
    bf16x8 pa = *(const bf16x8*)&Pls[wave][lm][quad*4];
    #pragma unroll
    for (int f = 0; f < 8; ++f){
      union { u32 u[4]; bf16x8 v8; } vv;
      vv.u[0] = Vt[quad*4+0][f*16 + lm];
      vv.u[1] = Vt[quad*4+1][f*16 + lm];
      vv.u[2] = Vt[quad*4+2][f*16 + lm];
      vv.u[3] = Vt[quad*4+3][f*16 + lm];
      oacc[f] = __builtin_amdgcn_mfma_f32_16x16x32_bf16(pa, vv.v8, oacc[f], 0, 0, 0);
    }
  }
  #pragma unroll
  for (int r = 0; r < 4; ++r){
    int qg = qt0 + wave*16 + quad*4 + r;
    if (qg < L_IN){
      float inv = 1.f / lsum[r];
      #pragma unroll
      for (int f = 0; f < 8; ++f)
        q[qb0 + (size_t)qg*HD + f*16 + lm] = f2b(oacc[f][r]*inv);
    }
  }
}

// ---------------- prediction head: one wave per row, shfl-reduce ----------------
__global__ __launch_bounds__(256)
void pred_kernel(const float* __restrict__ X, const void* __restrict__ w,
                 void* __restrict__ out, const u16* __restrict__ det)
{
  bool f32 = is_f32(det);
  int row = blockIdx.x*4 + (threadIdx.x >> 6);
  int lane = threadIdx.x & 63;
  if (row >= BSZ*L_IN) return;
  const float* xr = X + (size_t)row*DM;
  float a0=0.f,a1=0.f,a2=0.f,a3=0.f,a4=0.f,a5=0.f,a6=0.f;
  #pragma unroll
  for (int i = 0; i < 8; ++i){
    int kk = lane + i*64;
    float xv = xr[kk];
    long long wo = (long long)kk*7;
    a0 += xv*ldv(w, wo+0, f32);
    a1 += xv*ldv(w, wo+1, f32);
    a2 += xv*ldv(w, wo+2, f32);
    a3 += xv*ldv(w, wo+3, f32);
    a4 += xv*ldv(w, wo+4, f32);
    a5 += xv*ldv(w, wo+5, f32);
    a6 += xv*ldv(w, wo+6, f32);
  }
  #pragma unroll
  for (int o = 32; o > 0; o >>= 1){
    a0 += __shfl_xor(a0, o); a1 += __shfl_xor(a1, o); a2 += __shfl_xor(a2, o);
    a3 += __shfl_xor(a3, o); a4 += __shfl_xor(a4, o); a5 += __shfl_xor(a5, o);
    a6 += __shfl_xor(a6, o);
  }
  if (lane == 0){
    long long o0 = (long long)row*7;
    if (f32){
      float* op = (float*)out;
      op[o0+0]=a0; op[o0+1]=a1; op[o0+2]=a2; op[o0+3]=a3;
      op[o0+4]=a4; op[o0+5]=a5; op[o0+6]=a6;
    } else {
      u16* op = (u16*)out;
      op[o0+0]=f2b(a0); op[o0+1]=f2b(a1); op[o0+2]=f2b(a2); op[o0+3]=f2b(a3);
      op[o0+4]=f2b(a4); op[o0+5]=f2b(a5); op[o0+6]=f2b(a6);
    }
  }
}

// ---------------- launch ----------------
extern "C" void kernel_launch(void* const* d_in, const int* in_sizes, int n_in,
                              void* d_out, int out_size, void* d_ws, size_t ws_size,
                              hipStream_t stream)
{
  (void)in_sizes; (void)n_in; (void)out_size;
  #define IN(i) ((const void*)d_in[i])
  const u16* det = (const u16*)d_in[20];
  float* ws   = (float*)d_ws;
  float* encx = ws + OFF_ENCX;
  float* decx = ws + OFF_DECX;
  u16*   qb   = (u16*)(ws + OFF_QB);
  u16*   kb   = (u16*)(ws + OFF_KB);
  u16*   vb   = (u16*)(ws + OFF_VB);
  int*   nbr  = (int*)(ws + OFF_NBR);
  bool haveShadow = ws_size >= WS_NEED;
  bool haveWtAll  = ws_size >= WS_NEED2;
  u16*   encb = haveShadow ? (u16*)(ws + OFF_ENCB) : nullptr;
  u16*   decb = haveShadow ? (u16*)(ws + OFF_DECB) : nullptr;
  u16*   WtAll = (u16*)(ws + OFF_WT);
  // phase-disjoint aliases (fallback path + temporaries)
  float* tmp1  = ws + OFF_VB;
  u16*   WtE3f = (u16*)(ws + OFF_VB + (size_t)BSZ*S1*DM);
  u16*   WtEOf = WtE3f + (size_t)2304*512;
  u16*   WtE1f = WtEOf + (size_t)768*512;
  u16*   WtE2f = WtE1f + (size_t)512*512;
  u16*   WtD3f = (u16*)(ws + OFF_QB + (size_t)BSZ*L_IN*HD/2);
  u16*   WtDOf = WtD3f + (size_t)2304*512;
  u16*   WtD1f = WtDOf + (size_t)768*512;
  u16*   WtD2f = WtD1f + (size_t)512*512;
  u16*   tmph  = (u16*)(ws + OFF_KB);
  float* embE  = ws + OFF_VB;
  float* Wc    = ws + OFF_QB;
  float* bdown = ws + OFF_KB;
  float* bconv = bdown + (size_t)BSZ*L_IN*128;
  float* bup   = bconv + (size_t)BSZ*54*128;

  const int RPe = 111, rpxE = 14;
  const int RPd = 84,  rpxD = 11;

  build_nbr_kernel<<<1, 256, 0, stream>>>(nbr);
  if (haveWtAll)
    wt_all<<<8*2048, 256, 0, stream>>>(IN(22), IN(24), IN(26), IN(28), IN(32), IN(34),
                                       IN(38), IN(40), IN(42), IN(44), IN(48), IN(50),
                                       WtAll, det);

  embed_fast<<<1344, 256, 0, stream>>>(IN(0), IN(1), IN(4), IN(5), IN(6), det, embE, nullptr);
  embed_fast<<<1344, 256, 0, stream>>>(IN(2), IN(3), IN(7), IN(8), IN(9), det, decx, decb);

  // bottleneck
  wc_kernel<<<(3*512*128)/256, 256, 0, stream>>>(IN(12), Wc, det);
  gemm_k<<<dim3(128/BN, (BSZ*L_IN)/BM), 256, 0, stream>>>(
      embE, IN(10), 0, IN(11), 0, bdown, det, 512, 128);
  conv_gemm<<<dim3(2, (BSZ*42)/BM), 256, 0, stream>>>(
      bdown, L_IN, 0, bconv, 54, 0, 42, Wc, IN(13), IN(14), IN(15), IN(16), IN(17), det, 0);
  conv_gemm<<<dim3(2, (BSZ*10)/BM), 256, 0, stream>>>(
      bconv, 54, 0, bconv, 54, 42, 10, Wc + 65536, IN(13), IN(14), IN(15), IN(16), IN(17), det, 1);
  conv_gemm<<<dim3(2, (BSZ*2)/BM), 256, 0, stream>>>(
      bconv, 54, 42, bconv, 54, 52, 2, Wc + 131072, IN(13), IN(14), IN(15), IN(16), IN(17), det, 2);
  gemm_k<<<dim3(512/BN, (BSZ*54)/BM), 256, 0, stream>>>(
      bconv, IN(18), 0, IN(19), 0, bup, det, 128, 512);
  concat_ln_kernel<<<(BSZ*S1)/4, 256, 0, stream>>>(embE, bup, IN(20), IN(21), encx, encb, det);

  // encoder layers
  for (int i = 0; i < 6; ++i){
    long long wO = (long long)i*512*768, oO = (long long)i*768*512;
    long long bO = (long long)i*768, dO = (long long)i*512;
    long long fO = (long long)i*512*512;
    u16 *Wt3, *WtO, *Wt1, *Wt2;
    if (haveWtAll){
      u16* base = WtAll + (size_t)i*WT_SLOT;
      Wt3 = base;
      WtO = base + (size_t)2304*512;
      Wt1 = WtO + (size_t)512*768;
      Wt2 = Wt1 + (size_t)512*512;
    } else {
      wt_batch<<<2048, 256, 0, stream>>>(IN(22), IN(24), IN(26), IN(28), IN(32), IN(34),
                                         wO, oO, fO, WtE3f, WtEOf, WtE1f, WtE2f, det);
      Wt3 = WtE3f; WtO = WtEOf; Wt1 = WtE1f; Wt2 = WtE2f;
    }
    if (haveShadow)
      gemm_qkv<1><<<8*rpxE*18, 256, 0, stream>>>(
          encb, Wt3, IN(23), IN(25), IN(27), bO, qb, kb, vb, det, S1, S1, 0, RPe, 18, rpxE);
    else
      gemm_qkv<0><<<8*rpxE*18, 256, 0, stream>>>(
          encx, Wt3, IN(23), IN(25), IN(27), bO, qb, kb, vb, det, S1, S1, 0, RPe, 18, rpxE);
    attn_enc_sparse<<<(BSZ*S1*NHD)/16, 256, 0, stream>>>(qb, kb, vb, nbr);
    gemm_mfma<2,1,0,64><<<8*rpxE*8, 256, 0, stream>>>(
        qb, WtO, IN(29), dO, encx, tmp1, det, 768, 512, S1, S1, 0, RPe, 8, rpxE);
    ln_kernel<<<(BSZ*S1)/4, 256, 0, stream>>>(tmp1, IN(30), dO, IN(31), dO, 1e-6f, encx, encb, det);
    if (haveShadow)
      gemm_mfma<1,1,1,64><<<8*rpxE*8, 256, 0, stream>>>(
          encb, Wt1, IN(33), dO, nullptr, tmph, det, 512, 512, S1, S1, 0, RPe, 8, rpxE);
    else
      gemm_mfma<1,0,1,64><<<8*rpxE*8, 256, 0, stream>>>(
          encx, Wt1, IN(33), dO, nullptr, tmph, det, 512, 512, S1, S1, 0, RPe, 8, rpxE);
    gemm_mfma<2,1,0,64><<<8*rpxE*8, 256, 0, stream>>>(
        tmph, Wt2, IN(35), dO, encx, tmp1, det, 512, 512, S1, S1, 0, RPe, 8, rpxE);
    ln_kernel<<<(BSZ*S1)/4, 256, 0, stream>>>(tmp1, IN(36), dO, IN(37), dO, 1e-6f, encx, encb, det);
  }

  // decoder layers
  for (int i = 0; i < 2; ++i){
    long long wO = (long long)i*512*768, oO = (long long)i*768*512;
    long long bO = (long long)i*768, dO = (long long)i*512;
    long long fO = (long long)i*512*512;
    u16 *Wt3, *WtO, *Wt1, *Wt2;
    if (haveWtAll){
      u16* base = WtAll + (size_t)(6+i)*WT_SLOT;
      Wt3 = base;
      WtO = base + (size_t)2304*512;
      Wt1 = WtO + (size_t)512*768;
      Wt2 = Wt1 + (size_t)512*512;
    } else {
      wt_batch<<<2048, 256, 0, stream>>>(IN(38), IN(40), IN(42), IN(44), IN(48), IN(50),
                                         wO, oO, fO, WtD3f, WtDOf, WtD1f, WtD2f, det);
      Wt3 = WtD3f; WtO = WtDOf; Wt1 = WtD1f; Wt2 = WtD2f;
    }
    if (haveShadow){
      gemm_mfma<0,1,1,64><<<8*rpxD*12, 256, 0, stream>>>(
          decb, Wt3, IN(39), bO, nullptr, qb, det, 512, 768, L_IN, L_IN, 0, RPd, 12, rpxD);
      gemm_qkv<1><<<8*rpxE*12, 256, 0, stream>>>(
          encb, Wt3 + (size_t)768*512, IN(41), IN(43), IN(43), bO, kb, vb, vb, det, S1, SKV, 0, RPe, 12, rpxE);
      gemm_qkv<1><<<8*rpxD*12, 256, 0, stream>>>(
          decb, Wt3 + (size_t)768*512, IN(41), IN(43), IN(43), bO, kb, vb, vb, det, L_IN, SKV, S1, RPd, 12, rpxD);
    } else {
      gemm_mfma<0,0,1,64><<<8*rpxD*12, 256, 0, stream>>>(
          decx, Wt3, IN(39), bO, nullptr, qb, det, 512, 768, L_IN, L_IN, 0, RPd, 12, rpxD);
      gemm_qkv<0><<<8*rpxE*12, 256, 0, stream>>>(
          encx, Wt3 + (size_t)768*512, IN(41), IN(43), IN(43), bO, kb, vb, vb, det, S1, SKV, 0, RPe, 12, rpxE);
      gemm_qkv<0><<<8*rpxD*12, 256, 0, stream>>>(
          decx, Wt3 + (size_t)768*512, IN(41), IN(43), IN(43), bO, kb, vb, vb, det, L_IN, SKV, S1, RPd, 12, rpxD);
    }
    attn_dec_mfma<<<dim3(3, NHD, BSZ), 256, 0, stream>>>(qb, kb, vb);
    gemm_mfma<2,1,0,64><<<8*rpxD*8, 256, 0, stream>>>(
        qb, WtO, IN(45), dO, decx, tmp1, det, 768, 512, L_IN, L_IN, 0, RPd, 8, rpxD);
    ln_kernel<<<(BSZ*L_IN)/4, 256, 0, stream>>>(tmp1, IN(46), dO, IN(47), dO, 1e-6f, decx, decb, det);
    if (haveShadow)
      gemm_mfma<1,1,1,64><<<8*rpxD*8, 256, 0, stream>>>(
          decb, Wt1, IN(49), dO, nullptr, tmph, det, 512, 512, L_IN, L_IN, 0, RPd, 8, rpxD);
    else
      gemm_mfma<1,0,1,64><<<8*rpxD*8, 256, 0, stream>>>(
          decx, Wt1, IN(49), dO, nullptr, tmph, det, 512, 512, L_IN, L_IN, 0, RPd, 8, rpxD);
    gemm_mfma<2,1,0,64><<<8*rpxD*8, 256, 0, stream>>>(
        tmph, Wt2, IN(51), dO, decx, tmp1, det, 512, 512, L_IN, L_IN, 0, RPd, 8, rpxD);
    ln_kernel<<<(BSZ*L_IN)/4, 256, 0, stream>>>(tmp1, IN(52), dO, IN(53), dO, 1e-6f, decx, decb, det);
  }

  pred_kernel<<<((BSZ*L_IN+3)/4), 256, 0, stream>>>(decx, IN(54), d_out, det);
  #undef IN
}

// Round 5
// 2692.832 us; speedup vs baseline: 1.1741x; 1.0225x over previous
//
#include <hip/hip_runtime.h>
#include <cstdint>
#include <cstddef>

// ---------------- model constants ----------------
#define BSZ   64
#define L_IN  168
#define S1    222
#define SKV   390
#define DM    512
#define HD    768
#define NHD   6
#define DK    128

typedef unsigned short u16;
typedef unsigned int u32;
typedef __attribute__((ext_vector_type(8))) short bf16x8;
typedef __attribute__((ext_vector_type(4))) float f32x4v;

// ---------------- bf16 helpers ----------------
__device__ inline float b2f(u16 u){
  union { u32 i; float f; } v; v.i = ((u32)u) << 16; return v.f;
}
__device__ inline u16 f2b(float f){
  union { float f; u32 i; } v; v.f = f;
  u32 x = v.i;
  return (u16)((x + 0x7fffu + ((x >> 16) & 1u)) >> 16);
}
__device__ inline u32 pk2(float a, float b){
  return ((u32)f2b(b) << 16) | (u32)f2b(a);
}
__device__ inline float ldv(const void* p, long long i, bool f32){
  return f32 ? ((const float*)p)[i] : b2f(((const u16*)p)[i]);
}
__device__ inline float4 ldv4(const void* p, long long i, bool f32){
  if (f32) return *(const float4*)((const float*)p + i);
  ushort4 w = *(const ushort4*)((const u16*)p + i);
  return make_float4(b2f(w.x), b2f(w.y), b2f(w.z), b2f(w.w));
}
__device__ inline bool is_f32(const u16* det){ return det[0] != 0x3F80; }
__device__ inline void unpack8(uint4 w, float* f){
  union { u32 i; float fl; } a;
  a.i = w.x << 16;          f[0] = a.fl;
  a.i = w.x & 0xffff0000u;  f[1] = a.fl;
  a.i = w.y << 16;          f[2] = a.fl;
  a.i = w.y & 0xffff0000u;  f[3] = a.fl;
  a.i = w.z << 16;          f[4] = a.fl;
  a.i = w.z & 0xffff0000u;  f[5] = a.fl;
  a.i = w.w << 16;          f[6] = a.fl;
  a.i = w.w & 0xffff0000u;  f[7] = a.fl;
}

// async global->LDS, 16B per lane; dest must be wave-uniform (HW: base + lane*16)
__device__ inline void gload_lds16(const void* g, void* l){
  __builtin_amdgcn_global_load_lds((const __attribute__((address_space(1))) void*)g,
                                   (__attribute__((address_space(3))) void*)l, 16, 0, 0);
}

// ---------------- workspace layout (float-equivalent offsets) ----------------
constexpr size_t OFF_ENCX = 0;
constexpr size_t OFF_DECX = OFF_ENCX + (size_t)BSZ*S1*DM;
constexpr size_t OFF_QB   = OFF_DECX + (size_t)BSZ*L_IN*DM;
constexpr size_t OFF_KB   = OFF_QB   + (size_t)BSZ*S1*HD/2;
constexpr size_t OFF_VB   = OFF_KB   + (size_t)BSZ*SKV*HD/2;
constexpr size_t OFF_NBR  = OFF_VB   + (size_t)BSZ*SKV*HD/2;
constexpr size_t OFF_ENCB = OFF_NBR  + 4096;
constexpr size_t OFF_DECB = OFF_ENCB + (size_t)BSZ*S1*DM/2;
constexpr size_t OFF_WT   = OFF_DECB + (size_t)BSZ*L_IN*DM/2;     // all-layer Wt: 8 slots x 2,097,152 u16
constexpr size_t WT_SLOT  = 2097152;                               // u16 per layer slot
constexpr size_t WS_NEED  = (OFF_WT) * 4;                          // shadow path
constexpr size_t WS_NEED2 = (OFF_WT + 8*WT_SLOT/2) * 4;            // + wt_all region

// ---------------- PAM sparsity ----------------
__device__ inline int scale_of(int i, int& ii){
  if (i < 168){ ii = i;       return 0; }
  if (i < 210){ ii = i - 168; return 1; }
  if (i < 220){ ii = i - 210; return 2; }
  ii = i - 220; return 3;
}
__device__ inline bool pam_ok(int i, int j){
  int ii, jj;
  int li = scale_of(i, ii);
  int lj = scale_of(j, jj);
  const int n[4] = {168, 42, 10, 2};
  if (li == lj){ int d = ii - jj; return (d <= 1 && d >= -1); }
  if (li == lj + 1){ int lo = ii*4, hi = (ii == n[li]-1) ? n[lj] : ii*4+4; return (jj >= lo && jj < hi); }
  if (lj == li + 1){ int lo = jj*4, hi = (jj == n[lj]-1) ? n[li] : jj*4+4; return (ii >= lo && ii < hi); }
  return false;
}
__global__ void build_nbr_kernel(int* __restrict__ nbr){
  int q = blockIdx.x * 256 + threadIdx.x;
  if (q >= S1) return;
  int cnt = 0;
  int list[12];
  for (int j = 0; j < S1; ++j)
    if (pam_ok(q, j) && cnt < 12) list[cnt++] = j;
  #pragma unroll
  for (int t = 0; t < 12; ++t) nbr[q*12 + t] = (t < cnt) ? list[t] : -1;
}

// ---------------- embedding: register-resident weights, grid-stride rows ----
__global__ __launch_bounds__(256)
void embed_fast(const void* __restrict__ x, const void* __restrict__ t,
                const void* __restrict__ cw, const void* __restrict__ tw,
                const void* __restrict__ tb, const u16* __restrict__ det,
                float* __restrict__ out, u16* __restrict__ out2)
{
  bool f32 = is_f32(det);
  int d0 = threadIdx.x;
  int d1 = threadIdx.x + 256;

  float w0[21], w1[21];
  #pragma unroll
  for (int i = 0; i < 21; ++i){
    w0[i] = ldv(cw, (long long)d0*21 + i, f32);
    w1[i] = ldv(cw, (long long)d1*21 + i, f32);
  }
  float tw0[4], tw1[4];
  #pragma unroll
  for (int f = 0; f < 4; ++f){
    tw0[f] = ldv(tw, (long long)f*DM + d0, f32);
    tw1[f] = ldv(tw, (long long)f*DM + d1, f32);
  }
  float tb0 = ldv(tb, d0, f32);
  float tb1 = ldv(tb, d1, f32);
  float dv0 = __expf(-(float)(d0 & ~1) * (9.210340371976184f/512.f));
  float dv1 = __expf(-(float)(d1 & ~1) * (9.210340371976184f/512.f));
  bool odd0 = (d0 & 1), odd1 = (d1 & 1);

  const int nRows = BSZ * L_IN;
  for (int row = blockIdx.x; row < nRows; row += gridDim.x){
    int b = row / L_IN, l = row - b*L_IN;
    float acc0 = 0.f, acc1 = 0.f;
    #pragma unroll
    for (int tt = 0; tt < 3; ++tt){
      int ls = l + tt - 1;
      ls = (ls < 0) ? ls + L_IN : (ls >= L_IN ? ls - L_IN : ls);
      long long xo = ((long long)(b*L_IN + ls))*7;
      #pragma unroll
      for (int c = 0; c < 7; ++c){
        float xv = ldv(x, xo + c, f32);
        acc0 += xv * w0[c*3 + tt];
        acc1 += xv * w1[c*3 + tt];
      }
    }
    float ang0 = (float)l * dv0;
    float ang1 = (float)l * dv1;
    acc0 += odd0 ? __cosf(ang0) : __sinf(ang0);
    acc1 += odd1 ? __cosf(ang1) : __sinf(ang1);
    long long to = ((long long)row)*4;
    #pragma unroll
    for (int f = 0; f < 4; ++f){
      float tv = ldv(t, to + f, f32);
      acc0 += tv * tw0[f];
      acc1 += tv * tw1[f];
    }
    acc0 += tb0;
    acc1 += tb1;
    size_t o = (size_t)row*DM;
    out[o + d0] = acc0;
    out[o + d1] = acc1;
    if (out2){
      out2[o + d0] = f2b(acc0);
      out2[o + d1] = f2b(acc1);
    }
  }
}

// ---------------- weight transpose helpers ----------------
__device__ inline void trans32(const void* W, long long wOff, int K, int N, int k0, int n0,
                               u16* __restrict__ Wt, bool f32, float* tb, int tid)
{
  int c = tid & 31, r0 = tid >> 5;
  #pragma unroll
  for (int rr = 0; rr < 32; rr += 8)
    tb[(r0+rr)*33 + c] = ldv(W, wOff + (long long)(k0+r0+rr)*N + n0 + c, f32);
  __syncthreads();
  #pragma unroll
  for (int rr = 0; rr < 32; rr += 8)
    Wt[(size_t)(n0+r0+rr)*K + k0 + c] = f2b(tb[c*33 + r0+rr]);
}

__device__ inline void wt_layer_body(int t, const void* wq, const void* wk, const void* wv,
                                     const void* wo, const void* w1, const void* w2,
                                     long long wO, long long oO, long long fO,
                                     u16* Wt3, u16* WtO, u16* Wt1, u16* Wt2,
                                     bool f32, float* tb, int tid)
{
  if (t < 384)       trans32(wq, wO, 512, 768, (t/24)*32, (t%24)*32, Wt3,               f32, tb, tid);
  else if (t < 768)  { int u = t-384;  trans32(wk, wO, 512, 768, (u/24)*32, (u%24)*32, Wt3 + (size_t)768*512,  f32, tb, tid); }
  else if (t < 1152) { int u = t-768;  trans32(wv, wO, 512, 768, (u/24)*32, (u%24)*32, Wt3 + (size_t)1536*512, f32, tb, tid); }
  else if (t < 1536) { int u = t-1152; trans32(wo, oO, 768, 512, (u/16)*32, (u%16)*32, WtO, f32, tb, tid); }
  else if (t < 1792) { int u = t-1536; trans32(w1, fO, 512, 512, (u/16)*32, (u%16)*32, Wt1, f32, tb, tid); }
  else               { int u = t-1792; trans32(w2, fO, 512, 512, (u/16)*32, (u%16)*32, Wt2, f32, tb, tid); }
}

// per-layer fallback
__global__ __launch_bounds__(256)
void wt_batch(const void* wq, const void* wk, const void* wv,
              const void* wo, const void* w1, const void* w2,
              long long wO, long long oO, long long fO,
              u16* __restrict__ Wt3, u16* __restrict__ WtO,
              u16* __restrict__ Wt1, u16* __restrict__ Wt2,
              const u16* __restrict__ det)
{
  __shared__ float tb[32*33];
  bool f32 = is_f32(det);
  wt_layer_body(blockIdx.x, wq, wk, wv, wo, w1, w2, wO, oO, fO, Wt3, WtO, Wt1, Wt2,
                f32, tb, threadIdx.x);
}

// all 8 layers in one launch: slots 0..5 = enc layers, 6..7 = dec layers
__global__ __launch_bounds__(256)
void wt_all(const void* ewq, const void* ewk, const void* ewv, const void* ewo,
            const void* ew1, const void* ew2,
            const void* dwq, const void* dwk, const void* dwv, const void* dwo,
            const void* dw1, const void* dw2,
            u16* __restrict__ WtAll, const u16* __restrict__ det)
{
  __shared__ float tb[32*33];
  bool f32 = is_f32(det);
  int s = blockIdx.x >> 11;
  int t = blockIdx.x & 2047;
  bool enc = s < 6;
  int li = enc ? s : s - 6;
  long long wO = (long long)li*512*768, oO = (long long)li*768*512, fO = (long long)li*512*512;
  u16* base = WtAll + (size_t)s*WT_SLOT;
  wt_layer_body(t,
                enc ? ewq : dwq, enc ? ewk : dwk, enc ? ewv : dwv,
                enc ? ewo : dwo, enc ? ew1 : dw1, enc ? ew2 : dw2,
                wO, oO, fO,
                base, base + (size_t)2304*512,
                base + (size_t)2304*512 + (size_t)512*768,
                base + (size_t)2304*512 + (size_t)512*768 + (size_t)512*512,
                f32, tb, threadIdx.x);
}

// ---------------- XCD-exclusive row-panel swizzle (CN-wide col panels) --------
template<int CN>
__device__ inline bool swzT(int t, int RP, int CP, int rpx, int& row0, int& col0){
  int xcd = t & 7, j = t >> 3;
  int rp = xcd + 8*(j % rpx);
  int cp = j / rpx;
  if (rp >= RP || cp >= CP) return false;
  row0 = rp*128; col0 = cp*CN;
  return true;
}

// ---------------- MFMA GEMM: C = A[M,K] @ W via Wt bf16 [N,K] ----------------
// Tile 128 x CN (CN = 128 or 64). bf16 staging via global_load_lds w=16 with
// pre-swizzled SOURCE (linear LDS dest).
template<int EPI, int ABF, int CBF, int CN>
__global__ __launch_bounds__(256)
void gemm_mfma(const void* __restrict__ Av, const u16* __restrict__ Wt,
               const void* __restrict__ bias, long long bOff, const float* __restrict__ R,
               void* __restrict__ Cv, const u16* __restrict__ det,
               int K, int N, int La, int Lc, int off, int RP, int CP, int rpx)
{
  constexpr int NF = CN/32;                  // n-frags (16-wide) per wave
  __shared__ u16 As[128][64];
  __shared__ u16 Bs[CN][64];
  bool f32 = is_f32(det);
  int tid = threadIdx.x;
  int row0, col0;
  if (!swzT<CN>(blockIdx.x, RP, CP, rpx, row0, col0)) return;
  int wave = tid >> 6, lane = tid & 63;
  int wm = (wave >> 1)*64, wn = (wave & 1)*(CN/2);
  int lm = lane & 15, quad = lane >> 4;
  int sr = tid >> 1;
  int sh = (tid & 1) * 32;
  int swzS = (sr & 7) * 8;
  int r8 = lane >> 3;                 // 0..7 (row within 8-row wave chunk)
  int scw = ((lane & 7)*8) ^ (r8*8);  // pre-swizzled source col (u16 units)
  f32x4v acc[4][NF];
  #pragma unroll
  for (int i = 0; i < 4; ++i)
    #pragma unroll
    for (int j = 0; j < NF; ++j) acc[i][j] = (f32x4v){0.f,0.f,0.f,0.f};

  for (int k0 = 0; k0 < K; k0 += 64){
    if (ABF){
      const u16* base = (const u16*)Av + (size_t)row0*K + k0 + scw;
      #pragma unroll
      for (int j = 0; j < 4; ++j){
        int r = wave*32 + j*8;
        gload_lds16(base + (size_t)(r + r8)*K, &As[r][0]);
      }
    } else {
      const float* src = (const float*)Av + (size_t)(row0+sr)*K + k0 + sh;
      #pragma unroll
      for (int j = 0; j < 4; ++j){
        float4 f0 = *(const float4*)(src + 8*j);
        float4 f1 = *(const float4*)(src + 8*j + 4);
        uint4 o;
        o.x = pk2(f0.x, f0.y); o.y = pk2(f0.z, f0.w);
        o.z = pk2(f1.x, f1.y); o.w = pk2(f1.z, f1.w);
        *(uint4*)&As[sr][(sh + 8*j)^swzS] = o;
      }
    }
    {
      const u16* base = Wt + (size_t)col0*K + k0 + scw;
      #pragma unroll
      for (int j = 0; j < CN/32; ++j){
        int r = wave*(CN/4) + j*8;
        gload_lds16(base + (size_t)(r + r8)*K, &Bs[r][0]);
      }
    }
    __syncthreads();
    bf16x8 af[4][2], bfr[NF][2];
    #pragma unroll
    for (int mi = 0; mi < 4; ++mi){
      int m = wm + mi*16 + lm;
      int sz = (m & 7)*8;
      af[mi][0] = *(const bf16x8*)&As[m][(quad*8) ^ sz];
      af[mi][1] = *(const bf16x8*)&As[m][(32 + quad*8) ^ sz];
    }
    #pragma unroll
    for (int ni = 0; ni < NF; ++ni){
      int n = wn + ni*16 + lm;
      int sz = (n & 7)*8;
      bfr[ni][0] = *(const bf16x8*)&Bs[n][(quad*8) ^ sz];
      bfr[ni][1] = *(const bf16x8*)&Bs[n][(32 + quad*8) ^ sz];
    }
    #pragma unroll
    for (int mi = 0; mi < 4; ++mi)
      #pragma unroll
      for (int ni = 0; ni < NF; ++ni){
        acc[mi][ni] = __builtin_amdgcn_mfma_f32_16x16x32_bf16(af[mi][0], bfr[ni][0], acc[mi][ni], 0, 0, 0);
        acc[mi][ni] = __builtin_amdgcn_mfma_f32_16x16x32_bf16(af[mi][1], bfr[ni][1], acc[mi][ni], 0, 0, 0);
      }
    __syncthreads();
  }
  #pragma unroll
  for (int mi = 0; mi < 4; ++mi){
    #pragma unroll
    for (int r = 0; r < 4; ++r){
      int row = row0 + wm + mi*16 + quad*4 + r;
      int bb = row / La, l = row - bb*La;
      size_t crow = ((size_t)bb*Lc + off + l)*(size_t)N;
      #pragma unroll
      for (int ni = 0; ni < NF; ++ni){
        int col = col0 + wn + ni*16 + lm;
        float vv = acc[mi][ni][r] + ldv(bias, bOff + col, f32);
        if (EPI == 1) vv = 0.5f*vv*(1.f + erff(vv*0.70710678118654752f));
        if (EPI == 2) vv += R[crow + col];
        if (CBF) ((u16*)Cv)[crow + col] = f2b(vv);
        else     ((float*)Cv)[crow + col] = vv;
      }
    }
  }
}

// ---------------- fused QKV / KV MFMA GEMM (K=512), swizzled ----------------
template<int ABF>
__global__ __launch_bounds__(256)
void gemm_qkv(const void* __restrict__ Av, const u16* __restrict__ Wt,
              const void* __restrict__ b0, const void* __restrict__ b1, const void* __restrict__ b2,
              long long bOff, u16* __restrict__ o0, u16* __restrict__ o1, u16* __restrict__ o2,
              const u16* __restrict__ det, int La, int Lc, int off, int RP, int CP, int rpx)
{
  __shared__ u16 As[128][64];
  __shared__ u16 Bs[128][64];
  bool f32 = is_f32(det);
  const int K = 512;
  int tid = threadIdx.x;
  int row0, col0;
  if (!swzT<128>(blockIdx.x, RP, CP, rpx, row0, col0)) return;
  int wave = tid >> 6, lane = tid & 63;
  int wm = (wave >> 1)*64, wn = (wave & 1)*64;
  int lm = lane & 15, quad = lane >> 4;
  int sr = tid >> 1;
  int sh = (tid & 1) * 32;
  int swzS = (sr & 7) * 8;
  int r8 = lane >> 3;
  int scw = ((lane & 7)*8) ^ (r8*8);
  f32x4v acc[4][4];
  #pragma unroll
  for (int i = 0; i < 4; ++i)
    #pragma unroll
    for (int j = 0; j < 4; ++j) acc[i][j] = (f32x4v){0.f,0.f,0.f,0.f};

  for (int k0 = 0; k0 < K; k0 += 64){
    if (ABF){
      const u16* base = (const u16*)Av + (size_t)row0*K + k0 + scw;
      #pragma unroll
      for (int j = 0; j < 4; ++j){
        int r = wave*32 + j*8;
        gload_lds16(base + (size_t)(r + r8)*K, &As[r][0]);
      }
    } else {
      const float* src = (const float*)Av + (size_t)(row0+sr)*K + k0 + sh;
      #pragma unroll
      for (int j = 0; j < 4; ++j){
        float4 f0 = *(const float4*)(src + 8*j);
        float4 f1 = *(const float4*)(src + 8*j + 4);
        uint4 o;
        o.x = pk2(f0.x, f0.y); o.y = pk2(f0.z, f0.w);
        o.z = pk2(f1.x, f1.y); o.w = pk2(f1.z, f1.w);
        *(uint4*)&As[sr][(sh + 8*j)^swzS] = o;
      }
    }
    {
      const u16* base = Wt + (size_t)col0*K + k0 + scw;
      #pragma unroll
      for (int j = 0; j < 4; ++j){
        int r = wave*32 + j*8;
        gload_lds16(base + (size_t)(r + r8)*K, &Bs[r][0]);
      }
    }
    __syncthreads();
    bf16x8 af[4][2], bfr[4][2];
    #pragma unroll
    for (int mi = 0; mi < 4; ++mi){
      int m = wm + mi*16 + lm;
      int sz = (m & 7)*8;
      af[mi][0] = *(const bf16x8*)&As[m][(quad*8) ^ sz];
      af[mi][1] = *(const bf16x8*)&As[m][(32 + quad*8) ^ sz];
    }
    #pragma unroll
    for (int ni = 0; ni < 4; ++ni){
      int n = wn + ni*16 + lm;
      int sz = (n & 7)*8;
      bfr[ni][0] = *(const bf16x8*)&Bs[n][(quad*8) ^ sz];
      bfr[ni][1] = *(const bf16x8*)&Bs[n][(32 + quad*8) ^ sz];
    }
    #pragma unroll
    for (int mi = 0; mi < 4; ++mi)
      #pragma unroll
      for (int ni = 0; ni < 4; ++ni){
        acc[mi][ni] = __builtin_amdgcn_mfma_f32_16x16x32_bf16(af[mi][0], bfr[ni][0], acc[mi][ni], 0, 0, 0);
        acc[mi][ni] = __builtin_amdgcn_mfma_f32_16x16x32_bf16(af[mi][1], bfr[ni][1], acc[mi][ni], 0, 0, 0);
      }
    __syncthreads();
  }
  #pragma unroll
  for (int mi = 0; mi < 4; ++mi){
    #pragma unroll
    for (int r = 0; r < 4; ++r){
      int row = row0 + wm + mi*16 + quad*4 + r;
      int bb = row / La, l = row - bb*La;
      size_t crow = ((size_t)bb*Lc + off + l)*(size_t)HD;
      #pragma unroll
      for (int ni = 0; ni < 4; ++ni){
        int col = col0 + wn + ni*16 + lm;
        int sel = (col >= 1536) ? 2 : (col >= 768 ? 1 : 0);
        int colr = col - sel*768;
        const void* bp = (sel == 0) ? b0 : (sel == 1) ? b1 : b2;
        u16* dst = (sel == 0) ? o0 : (sel == 1) ? o1 : o2;
        float vv = acc[mi][ni][r] + ldv(bp, bOff + colr, f32);
        dst[crow + colr] = f2b(vv);
      }
    }
  }
}

// ---------------- SIMT GEMM (bottleneck) ----------------
#define BM 64
#define BN 64
#define BK 16
__global__ __launch_bounds__(256)
void gemm_k(const float* __restrict__ A, const void* __restrict__ W, long long wOff,
            const void* __restrict__ bias, long long bOff,
            float* __restrict__ C, const u16* __restrict__ det, int K, int N)
{
  __shared__ float As2[BK][BM+4];
  __shared__ float Bs2[BK][BN+4];
  bool f32 = is_f32(det);
  int tid = threadIdx.x;
  int row0 = blockIdx.y * BM, col0 = blockIdx.x * BN;
  int ty = tid >> 4, tx = tid & 15;
  int lr = tid >> 2, lc4 = (tid & 3) << 2;
  int wr = tid >> 4, wc4 = (tid & 15) << 2;
  float acc[4][4] = {};
  for (int k0 = 0; k0 < K; k0 += BK){
    float4 av = *(const float4*)(A + (size_t)(row0 + lr)*K + k0 + lc4);
    As2[lc4+0][lr] = av.x; As2[lc4+1][lr] = av.y;
    As2[lc4+2][lr] = av.z; As2[lc4+3][lr] = av.w;
    float4 wv = ldv4(W, wOff + (long long)(k0 + wr)*N + col0 + wc4, f32);
    *(float4*)&Bs2[wr][wc4] = wv;
    __syncthreads();
    #pragma unroll
    for (int kk = 0; kk < BK; ++kk){
      float4 a  = *(const float4*)&As2[kk][ty << 2];
      float4 bb = *(const float4*)&Bs2[kk][tx << 2];
      acc[0][0] += a.x*bb.x; acc[0][1] += a.x*bb.y; acc[0][2] += a.x*bb.z; acc[0][3] += a.x*bb.w;
      acc[1][0] += a.y*bb.x; acc[1][1] += a.y*bb.y; acc[1][2] += a.y*bb.z; acc[1][3] += a.y*bb.w;
      acc[2][0] += a.z*bb.x; acc[2][1] += a.z*bb.y; acc[2][2] += a.z*bb.z; acc[2][3] += a.z*bb.w;
      acc[3][0] += a.w*bb.x; acc[3][1] += a.w*bb.y; acc[3][2] += a.w*bb.z; acc[3][3] += a.w*bb.w;
    }
    __syncthreads();
  }
  #pragma unroll
  for (int i = 0; i < 4; ++i){
    int r = row0 + (ty << 2) + i;
    size_t crow = (size_t)r*(size_t)N;
    #pragma unroll
    for (int j = 0; j < 4; ++j){
      int c = col0 + (tx << 2) + j;
      C[crow + c] = acc[i][j] + ldv(bias, bOff + c, f32);
    }
  }
}

// ---------------- conv weight reorder ----------------
__global__ void wc_kernel(const void* __restrict__ w, float* __restrict__ Wc,
                          const u16* __restrict__ det)
{
  bool f32 = is_f32(det);
  int idx = blockIdx.x * 256 + threadIdx.x;
  if (idx >= 3*512*128) return;
  int co = idx & 127;
  int kk = (idx >> 7) & 511;
  int lay = idx >> 16;
  int tt = kk >> 7, ci = kk & 127;
  Wc[idx] = ldv(w, (long long)lay*65536 + co*512 + ci*4 + tt, f32);
}

// ---------------- bottleneck conv as GEMM + BN + ELU ----------------
__global__ __launch_bounds__(256)
void conv_gemm(const float* __restrict__ in, int inStride, int inOff,
               float* __restrict__ out, int outStride, int outOff, int Lout,
               const float* __restrict__ Wc,
               const void* __restrict__ cb, const void* __restrict__ bg,
               const void* __restrict__ bb, const void* __restrict__ bm,
               const void* __restrict__ bv, const u16* __restrict__ det, int lay)
{
  __shared__ float As2[BK][BM+4];
  __shared__ float Bs2[BK][BN+4];
  bool f32 = is_f32(det);
  int tid = threadIdx.x;
  int row0 = blockIdx.y * BM, col0 = blockIdx.x * BN;
  int ty = tid >> 4, tx = tid & 15;
  int lr = tid >> 2, lc4 = (tid & 3) << 2;
  int wr = tid >> 4, wc4 = (tid & 15) << 2;
  int rs = row0 + lr;
  int bs = rs / Lout, js = rs - bs*Lout;
  const float* arow = in + ((size_t)(bs*inStride + inOff + js*4))*128;
  float acc[4][4] = {};
  for (int k0 = 0; k0 < 512; k0 += BK){
    float4 av = *(const float4*)(arow + k0 + lc4);
    As2[lc4+0][lr] = av.x; As2[lc4+1][lr] = av.y;
    As2[lc4+2][lr] = av.z; As2[lc4+3][lr] = av.w;
    float4 wv = *(const float4*)(Wc + (size_t)(k0 + wr)*128 + col0 + wc4);
    *(float4*)&Bs2[wr][wc4] = wv;
    __syncthreads();
    #pragma unroll
    for (int kk = 0; kk < BK; ++kk){
      float4 a  = *(const float4*)&As2[kk][ty << 2];
      float4 bb2 = *(const float4*)&Bs2[kk][tx << 2];
      acc[0][0] += a.x*bb2.x; acc[0][1] += a.x*bb2.y; acc[0][2] += a.x*bb2.z; acc[0][3] += a.x*bb2.w;
      acc[1][0] += a.y*bb2.x; acc[1][1] += a.y*bb2.y; acc[1][2] += a.y*bb2.z; acc[1][3] += a.y*bb2.w;
      acc[2][0] += a.z*bb2.x; acc[2][1] += a.z*bb2.y; acc[2][2] += a.z*bb2.z; acc[2][3] += a.z*bb2.w;
      acc[3][0] += a.w*bb2.x; acc[3][1] += a.w*bb2.y; acc[3][2] += a.w*bb2.z; acc[3][3] += a.w*bb2.w;
    }
    __syncthreads();
  }
  #pragma unroll
  for (int i = 0; i < 4; ++i){
    int r = row0 + (ty << 2) + i;
    int b = r / Lout, j = r - b*Lout;
    float* orow = out + ((size_t)(b*outStride + outOff + j))*128;
    #pragma unroll
    for (int jj = 0; jj < 4; ++jj){
      int co = col0 + (tx << 2) + jj;
      long long po = (long long)lay*128 + co;
      float a = acc[i][jj] + ldv(cb, po, f32);
      a = (a - ldv(bm, po, f32)) * rsqrtf(ldv(bv, po, f32) + 1e-5f) * ldv(bg, po, f32) + ldv(bb, po, f32);
      a = a > 0.f ? a : (__expf(a) - 1.f);
      orow[co] = a;
    }
  }
}

// ---------------- LayerNorm (4 rows/block, optional bf16 shadow) ----------------
__global__ __launch_bounds__(256)
void ln_kernel(const float* __restrict__ X, const void* __restrict__ g, long long gOff,
               const void* __restrict__ bt, long long bOff, float eps,
               float* __restrict__ Out, u16* __restrict__ OutB, const u16* __restrict__ det)
{
  bool f32 = is_f32(det);
  int row = blockIdx.x*4 + (threadIdx.x >> 6);
  int lane = threadIdx.x & 63;
  const float* xr = X + (size_t)row*DM;
  float v[8]; float s = 0.f;
  #pragma unroll
  for (int i = 0; i < 8; ++i){ v[i] = xr[lane + i*64]; s += v[i]; }
  #pragma unroll
  for (int o = 32; o > 0; o >>= 1) s += __shfl_xor(s, o);
  float mean = s * (1.f/512.f);
  float q = 0.f;
  #pragma unroll
  for (int i = 0; i < 8; ++i){ float d = v[i]-mean; q += d*d; }
  #pragma unroll
  for (int o = 32; o > 0; o >>= 1) q += __shfl_xor(q, o);
  float inv = rsqrtf(q*(1.f/512.f) + eps);
  float* orow = Out + (size_t)row*DM;
  #pragma unroll
  for (int i = 0; i < 8; ++i){
    int c = lane + i*64;
    float val = (v[i]-mean)*inv*ldv(g, gOff + c, f32) + ldv(bt, bOff + c, f32);
    orow[c] = val;
    if (OutB) OutB[(size_t)row*DM + c] = f2b(val);
  }
}

// ---------------- concat + LayerNorm(1e-5), 4 rows/block, optional shadow ----------------
__global__ __launch_bounds__(256)
void concat_ln_kernel(const float* __restrict__ emb, const float* __restrict__ up,
                      const void* __restrict__ g, const void* __restrict__ bt,
                      float* __restrict__ Out, u16* __restrict__ OutB, const u16* __restrict__ det)
{
  bool f32 = is_f32(det);
  int row = blockIdx.x*4 + (threadIdx.x >> 6);
  int lane = threadIdx.x & 63;
  int b = row / S1, l = row - b*S1;
  const float* xr = (l < L_IN) ? emb + ((size_t)(b*L_IN + l))*DM
                               : up  + ((size_t)(b*54 + (l - L_IN)))*DM;
  float v[8]; float s = 0.f;
  #pragma unroll
  for (int i = 0; i < 8; ++i){ v[i] = xr[lane + i*64]; s += v[i]; }
  #pragma unroll
  for (int o = 32; o > 0; o >>= 1) s += __shfl_xor(s, o);
  float mean = s * (1.f/512.f);
  float q = 0.f;
  #pragma unroll
  for (int i = 0; i < 8; ++i){ float d = v[i]-mean; q += d*d; }
  #pragma unroll
  for (int o = 32; o > 0; o >>= 1) q += __shfl_xor(q, o);
  float inv = rsqrtf(q*(1.f/512.f) + 1e-5f);
  float* orow = Out + (size_t)row*DM;
  #pragma unroll
  for (int i = 0; i < 8; ++i){
    int c = lane + i*64;
    float val = (v[i]-mean)*inv*ldv(g, c, f32) + ldv(bt, c, f32);
    orow[c] = val;
    if (OutB) OutB[(size_t)row*DM + c] = f2b(val);
  }
}

// ---------------- encoder attention: PAM-sparse, 16-lane unit per (b,q,h) ----------------
__global__ __launch_bounds__(256)
void attn_enc_sparse(u16* __restrict__ q, const u16* __restrict__ k,
                     const u16* __restrict__ v, const int* __restrict__ nbr)
{
  int u = blockIdx.x * 16 + (threadIdx.x >> 4);
  int lane16 = threadIdx.x & 15;
  int h = u % NHD;
  int bq = u / NHD;
  int b = bq / S1, qr = bq - b*S1;
  const float scale = 0.088388347648318447f;
  size_t rowoff = (size_t)bq*HD + h*DK + lane16*8;
  uint4 qw = *(const uint4*)(q + rowoff);
  float qd[8]; unpack8(qw, qd);
  const int* nb = nbr + qr*12;
  size_t base = (size_t)b*S1*HD + h*DK + lane16*8;
  float pj[12];
  #pragma unroll
  for (int j = 0; j < 12; ++j){
    int kg = nb[j];
    int kgc = kg < 0 ? 0 : kg;
    uint4 kw = *(const uint4*)(k + (size_t)kgc*HD + base);
    float kd[8]; unpack8(kw, kd);
    float p = qd[0]*kd[0] + qd[1]*kd[1] + qd[2]*kd[2] + qd[3]*kd[3]
            + qd[4]*kd[4] + qd[5]*kd[5] + qd[6]*kd[6] + qd[7]*kd[7];
    p += __shfl_xor(p, 1); p += __shfl_xor(p, 2);
    p += __shfl_xor(p, 4); p += __shfl_xor(p, 8);
    pj[j] = (kg >= 0) ? p*scale : -1e30f;
  }
  float m = -1e30f;
  #pragma unroll
  for (int j = 0; j < 12; ++j) m = fmaxf(m, pj[j]);
  float s = 0.f;
  #pragma unroll
  for (int j = 0; j < 12; ++j){ pj[j] = __expf(pj[j] - m); s += pj[j]; }
  float inv = 1.f / s;
  float o[8];
  #pragma unroll
  for (int i = 0; i < 8; ++i) o[i] = 0.f;
  #pragma unroll
  for (int j = 0; j < 12; ++j){
    int kg = nb[j];
    int kgc = kg < 0 ? 0 : kg;
    uint4 vw = *(const uint4*)(v + (size_t)kgc*HD + base);
    float vd[8]; unpack8(vw, vd);
    #pragma unroll
    for (int i = 0; i < 8; ++i) o[i] += pj[j]*vd[i];
  }
  uint4 ow;
  ow.x = pk2(o[0]*inv, o[1]*inv);
  ow.y = pk2(o[2]*inv, o[3]*inv);
  ow.z = pk2(o[4]*inv, o[5]*inv);
  ow.w = pk2(o[6]*inv, o[7]*inv);
  *(uint4*)(q + rowoff) = ow;
}

// ---------------- decoder attention: MFMA flash (v3) ----------------
// v3: (a) reg-prefetch pipeline (T14): K/V of tile t+1 loaded into registers
// while tile t computes; LDS write happens after the barrier. (b) 1-D grid
// id = qt*384 + h*64 + b so the 3 q-tile blocks sharing one (b,h)'s K/V land
// on the SAME XCD (ids differ by 384 = 48*8) -> L2 absorbs K/V re-reads.
#define FQT 64
__global__ __launch_bounds__(256)
void attn_dec_mfma(u16* __restrict__ q, const u16* __restrict__ k,
                   const u16* __restrict__ v)
{
  __shared__ __align__(16) u16 Ks[32][136];
  __shared__ __align__(16) u32 Vt[16][132];
  __shared__ __align__(16) u32 Pls[4][16][16];
  int id = blockIdx.x;
  int qt = id / 384;
  int rem = id - qt*384;
  int h = rem >> 6;
  int b = rem & 63;
  int qt0 = qt * FQT;
  int tid = threadIdx.x;
  int wave = tid >> 6, lane = tid & 63;
  int lm = lane & 15, quad = lane >> 4;
  const float scale = 0.088388347648318447f;
  const size_t qb0 = (size_t)b*L_IN*HD + (size_t)h*DK;
  const size_t kb0 = (size_t)b*SKV*HD + (size_t)h*DK;

  bf16x8 qf[4];
  {
    int qg = qt0 + wave*16 + lm;
    if (qg < L_IN){
      #pragma unroll
      for (int ks = 0; ks < 4; ++ks)
        qf[ks] = *(const bf16x8*)(q + qb0 + (size_t)qg*HD + ks*32 + quad*8);
    } else {
      #pragma unroll
      for (int ks = 0; ks < 4; ++ks) qf[ks] = (bf16x8){0,0,0,0,0,0,0,0};
    }
  }

  float mold[4], lsum[4];
  #pragma unroll
  for (int r = 0; r < 4; ++r){ mold[r] = -1e30f; lsum[r] = 0.f; }
  f32x4v oacc[8];
  #pragma unroll
  for (int f = 0; f < 8; ++f) oacc[f] = (f32x4v){0.f,0.f,0.f,0.f};

  int kEnd = S1 + qt0 + FQT; if (kEnd > SKV) kEnd = SKV;
  int nt = (kEnd + 31) >> 5;

  // prefetch registers for one KV tile
  ushort4 kr[4];
  ushort4 vr[2][2];
  // load tile 0
  {
    const int kt0 = 0;
    #pragma unroll
    for (int j = 0; j < 4; ++j){
      int i = tid*4 + j*1024;
      int kk = i >> 7, d = i & 127;
      int kg = kt0 + kk;
      kr[j] = make_ushort4(0,0,0,0);
      if (kg < SKV) kr[j] = *(const ushort4*)(k + kb0 + (size_t)kg*HD + d);
    }
    #pragma unroll
    for (int j = 0; j < 2; ++j){
      int t2 = tid + j*256;
      int g = t2 & 31, p = t2 >> 5;
      int d0 = g*4;
      int kg0 = kt0 + p, kg1 = kt0 + p + 16;
      vr[j][0] = make_ushort4(0,0,0,0);
      vr[j][1] = make_ushort4(0,0,0,0);
      if (kg0 < SKV) vr[j][0] = *(const ushort4*)(v + kb0 + (size_t)kg0*HD + d0);
      if (kg1 < SKV) vr[j][1] = *(const ushort4*)(v + kb0 + (size_t)kg1*HD + d0);
    }
  }

  for (int ti = 0; ti < nt; ++ti){
    int kt0 = ti << 5;
    __syncthreads();   // previous tile's LDS reads complete
    // write prefetched regs -> LDS
    #pragma unroll
    for (int j = 0; j < 4; ++j){
      int i = tid*4 + j*1024;
      int kk = i >> 7, d = i & 127;
      *(ushort4*)&Ks[kk][d] = kr[j];
    }
    #pragma unroll
    for (int j = 0; j < 2; ++j){
      int t2 = tid + j*256;
      int g = t2 & 31, p = t2 >> 5;
      int d0 = g*4;
      uint4 o;
      o.x = (u32)vr[j][0].x | ((u32)vr[j][1].x << 16);
      o.y = (u32)vr[j][0].y | ((u32)vr[j][1].y << 16);
      o.z = (u32)vr[j][0].z | ((u32)vr[j][1].z << 16);
      o.w = (u32)vr[j][0].w | ((u32)vr[j][1].w << 16);
      *(uint4*)&Vt[p][d0] = o;
    }
    // issue loads for tile ti+1; latency hides under this tile's compute
    if (ti + 1 < nt){
      const int kn = (ti + 1) << 5;
      #pragma unroll
      for (int j = 0; j < 4; ++j){
        int i = tid*4 + j*1024;
        int kk = i >> 7, d = i & 127;
        int kg = kn + kk;
        kr[j] = make_ushort4(0,0,0,0);
        if (kg < SKV) kr[j] = *(const ushort4*)(k + kb0 + (size_t)kg*HD + d);
      }
      #pragma unroll
      for (int j = 0; j < 2; ++j){
        int t2 = tid + j*256;
        int g = t2 & 31, p = t2 >> 5;
        int d0 = g*4;
        int kg0 = kn + p, kg1 = kn + p + 16;
        vr[j][0] = make_ushort4(0,0,0,0);
        vr[j][1] = make_ushort4(0,0,0,0);
        if (kg0 < SKV) vr[j][0] = *(const ushort4*)(v + kb0 + (size_t)kg0*HD + d0);
        if (kg1 < SKV) vr[j][1] = *(const ushort4*)(v + kb0 + (size_t)kg1*HD + d0);
      }
    }
    __syncthreads();   // staged tile visible
    f32x4v sacc[2];
    sacc[0] = (f32x4v){0.f,0.f,0.f,0.f};
    sacc[1] = (f32x4v){0.f,0.f,0.f,0.f};
    #pragma unroll
    for (int t = 0; t < 2; ++t)
      #pragma unroll
      for (int ks = 0; ks < 4; ++ks){
        bf16x8 kf = *(const bf16x8*)&Ks[t*16 + lm][ks*32 + quad*8];
        sacc[t] = __builtin_amdgcn_mfma_f32_16x16x32_bf16(qf[ks], kf, sacc[t], 0, 0, 0);
      }
    float p[2][4];
    #pragma unroll
    for (int r = 0; r < 4; ++r){
      int qg = qt0 + wave*16 + quad*4 + r;
      float s0, s1;
      {
        int kg = kt0 + lm;
        bool ok = (kg < SKV) && (qg < L_IN) && (kg <= S1 + qg);
        s0 = ok ? sacc[0][r]*scale : -1e30f;
      }
      {
        int kg = kt0 + 16 + lm;
        bool ok = (kg < SKV) && (qg < L_IN) && (kg <= S1 + qg);
        s1 = ok ? sacc[1][r]*scale : -1e30f;
      }
      float mn = fmaxf(s0, s1);
      #pragma unroll
      for (int o = 8; o > 0; o >>= 1) mn = fmaxf(mn, __shfl_xor(mn, o));
      float mi = fmaxf(mold[r], mn);
      float alpha = __expf(mold[r] - mi);
      mold[r] = mi;
      p[0][r] = __expf(s0 - mi);
      p[1][r] = __expf(s1 - mi);
      float rs = p[0][r] + p[1][r];
      #pragma unroll
      for (int o = 8; o > 0; o >>= 1) rs += __shfl_xor(rs, o);
      lsum[r] = lsum[r]*alpha + rs;
      #pragma unroll
      for (int f = 0; f < 8; ++f) oacc[f][r] *= alpha;
    }
    #pragma unroll
    for (int r = 0; r < 4; ++r)
      Pls[wave][quad*4+r][lm] = pk2(p[0][r], p[1][r]);
    bf16x8 pa = *(const bf16x8*)&Pls[wave][lm][quad*4];
    #pragma unroll
    for (int f = 0; f < 8; ++f){
      union { u32 u[4]; bf16x8 v8; } vv;
      vv.u[0] = Vt[quad*4+0][f*16 + lm];
      vv.u[1] = Vt[quad*4+1][f*16 + lm];
      vv.u[2] = Vt[quad*4+2][f*16 + lm];
      vv.u[3] = Vt[quad*4+3][f*16 + lm];
      oacc[f] = __builtin_amdgcn_mfma_f32_16x16x32_bf16(pa, vv.v8, oacc[f], 0, 0, 0);
    }
  }
  #pragma unroll
  for (int r = 0; r < 4; ++r){
    int qg = qt0 + wave*16 + quad*4 + r;
    if (qg < L_IN){
      float inv = 1.f / lsum[r];
      #pragma unroll
      for (int f = 0; f < 8; ++f)
        q[qb0 + (size_t)qg*HD + f*16 + lm] = f2b(oacc[f][r]*inv);
    }
  }
}

// ---------------- prediction head: one wave per row, shfl-reduce ----------------
__global__ __launch_bounds__(256)
void pred_kernel(const float* __restrict__ X, const void* __restrict__ w,
                 void* __restrict__ out, const u16* __restrict__ det)
{
  bool f32 = is_f32(det);
  int row = blockIdx.x*4 + (threadIdx.x >> 6);
  int lane = threadIdx.x & 63;
  if (row >= BSZ*L_IN) return;
  const float* xr = X + (size_t)row*DM;
  float a0=0.f,a1=0.f,a2=0.f,a3=0.f,a4=0.f,a5=0.f,a6=0.f;
  #pragma unroll
  for (int i = 0; i < 8; ++i){
    int kk = lane + i*64;
    float xv = xr[kk];
    long long wo = (long long)kk*7;
    a0 += xv*ldv(w, wo+0, f32);
    a1 += xv*ldv(w, wo+1, f32);
    a2 += xv*ldv(w, wo+2, f32);
    a3 += xv*ldv(w, wo+3, f32);
    a4 += xv*ldv(w, wo+4, f32);
    a5 += xv*ldv(w, wo+5, f32);
    a6 += xv*ldv(w, wo+6, f32);
  }
  #pragma unroll
  for (int o = 32; o > 0; o >>= 1){
    a0 += __shfl_xor(a0, o); a1 += __shfl_xor(a1, o); a2 += __shfl_xor(a2, o);
    a3 += __shfl_xor(a3, o); a4 += __shfl_xor(a4, o); a5 += __shfl_xor(a5, o);
    a6 += __shfl_xor(a6, o);
  }
  if (lane == 0){
    long long o0 = (long long)row*7;
    if (f32){
      float* op = (float*)out;
      op[o0+0]=a0; op[o0+1]=a1; op[o0+2]=a2; op[o0+3]=a3;
      op[o0+4]=a4; op[o0+5]=a5; op[o0+6]=a6;
    } else {
      u16* op = (u16*)out;
      op[o0+0]=f2b(a0); op[o0+1]=f2b(a1); op[o0+2]=f2b(a2); op[o0+3]=f2b(a3);
      op[o0+4]=f2b(a4); op[o0+5]=f2b(a5); op[o0+6]=f2b(a6);
    }
  }
}

// ---------------- launch ----------------
extern "C" void kernel_launch(void* const* d_in, const int* in_sizes, int n_in,
                              void* d_out, int out_size, void* d_ws, size_t ws_size,
                              hipStream_t stream)
{
  (void)in_sizes; (void)n_in; (void)out_size;
  #define IN(i) ((const void*)d_in[i])
  const u16* det = (const u16*)d_in[20];
  float* ws   = (float*)d_ws;
  float* encx = ws + OFF_ENCX;
  float* decx = ws + OFF_DECX;
  u16*   qb   = (u16*)(ws + OFF_QB);
  u16*   kb   = (u16*)(ws + OFF_KB);
  u16*   vb   = (u16*)(ws + OFF_VB);
  int*   nbr  = (int*)(ws + OFF_NBR);
  bool haveShadow = ws_size >= WS_NEED;
  bool haveWtAll  = ws_size >= WS_NEED2;
  u16*   encb = haveShadow ? (u16*)(ws + OFF_ENCB) : nullptr;
  u16*   decb = haveShadow ? (u16*)(ws + OFF_DECB) : nullptr;
  u16*   WtAll = (u16*)(ws + OFF_WT);
  // phase-disjoint aliases (fallback path + temporaries)
  float* tmp1  = ws + OFF_VB;
  u16*   WtE3f = (u16*)(ws + OFF_VB + (size_t)BSZ*S1*DM);
  u16*   WtEOf = WtE3f + (size_t)2304*512;
  u16*   WtE1f = WtEOf + (size_t)768*512;
  u16*   WtE2f = WtE1f + (size_t)512*512;
  u16*   WtD3f = (u16*)(ws + OFF_QB + (size_t)BSZ*L_IN*HD/2);
  u16*   WtDOf = WtD3f + (size_t)2304*512;
  u16*   WtD1f = WtDOf + (size_t)768*512;
  u16*   WtD2f = WtD1f + (size_t)512*512;
  u16*   tmph  = (u16*)(ws + OFF_KB);
  float* embE  = ws + OFF_VB;
  float* Wc    = ws + OFF_QB;
  float* bdown = ws + OFF_KB;
  float* bconv = bdown + (size_t)BSZ*L_IN*128;
  float* bup   = bconv + (size_t)BSZ*54*128;

  const int RPe = 111, rpxE = 14;
  const int RPd = 84,  rpxD = 11;

  build_nbr_kernel<<<1, 256, 0, stream>>>(nbr);
  if (haveWtAll)
    wt_all<<<8*2048, 256, 0, stream>>>(IN(22), IN(24), IN(26), IN(28), IN(32), IN(34),
                                       IN(38), IN(40), IN(42), IN(44), IN(48), IN(50),
                                       WtAll, det);

  embed_fast<<<1344, 256, 0, stream>>>(IN(0), IN(1), IN(4), IN(5), IN(6), det, embE, nullptr);
  embed_fast<<<1344, 256, 0, stream>>>(IN(2), IN(3), IN(7), IN(8), IN(9), det, decx, decb);

  // bottleneck
  wc_kernel<<<(3*512*128)/256, 256, 0, stream>>>(IN(12), Wc, det);
  gemm_k<<<dim3(128/BN, (BSZ*L_IN)/BM), 256, 0, stream>>>(
      embE, IN(10), 0, IN(11), 0, bdown, det, 512, 128);
  conv_gemm<<<dim3(2, (BSZ*42)/BM), 256, 0, stream>>>(
      bdown, L_IN, 0, bconv, 54, 0, 42, Wc, IN(13), IN(14), IN(15), IN(16), IN(17), det, 0);
  conv_gemm<<<dim3(2, (BSZ*10)/BM), 256, 0, stream>>>(
      bconv, 54, 0, bconv, 54, 42, 10, Wc + 65536, IN(13), IN(14), IN(15), IN(16), IN(17), det, 1);
  conv_gemm<<<dim3(2, (BSZ*2)/BM), 256, 0, stream>>>(
      bconv, 54, 42, bconv, 54, 52, 2, Wc + 131072, IN(13), IN(14), IN(15), IN(16), IN(17), det, 2);
  gemm_k<<<dim3(512/BN, (BSZ*54)/BM), 256, 0, stream>>>(
      bconv, IN(18), 0, IN(19), 0, bup, det, 128, 512);
  concat_ln_kernel<<<(BSZ*S1)/4, 256, 0, stream>>>(embE, bup, IN(20), IN(21), encx, encb, det);

  // encoder layers
  for (int i = 0; i < 6; ++i){
    long long wO = (long long)i*512*768, oO = (long long)i*768*512;
    long long bO = (long long)i*768, dO = (long long)i*512;
    long long fO = (long long)i*512*512;
    u16 *Wt3, *WtO, *Wt1, *Wt2;
    if (haveWtAll){
      u16* base = WtAll + (size_t)i*WT_SLOT;
      Wt3 = base;
      WtO = base + (size_t)2304*512;
      Wt1 = WtO + (size_t)512*768;
      Wt2 = Wt1 + (size_t)512*512;
    } else {
      wt_batch<<<2048, 256, 0, stream>>>(IN(22), IN(24), IN(26), IN(28), IN(32), IN(34),
                                         wO, oO, fO, WtE3f, WtEOf, WtE1f, WtE2f, det);
      Wt3 = WtE3f; WtO = WtEOf; Wt1 = WtE1f; Wt2 = WtE2f;
    }
    if (haveShadow)
      gemm_qkv<1><<<8*rpxE*18, 256, 0, stream>>>(
          encb, Wt3, IN(23), IN(25), IN(27), bO, qb, kb, vb, det, S1, S1, 0, RPe, 18, rpxE);
    else
      gemm_qkv<0><<<8*rpxE*18, 256, 0, stream>>>(
          encx, Wt3, IN(23), IN(25), IN(27), bO, qb, kb, vb, det, S1, S1, 0, RPe, 18, rpxE);
    attn_enc_sparse<<<(BSZ*S1*NHD)/16, 256, 0, stream>>>(qb, kb, vb, nbr);
    gemm_mfma<2,1,0,64><<<8*rpxE*8, 256, 0, stream>>>(
        qb, WtO, IN(29), dO, encx, tmp1, det, 768, 512, S1, S1, 0, RPe, 8, rpxE);
    ln_kernel<<<(BSZ*S1)/4, 256, 0, stream>>>(tmp1, IN(30), dO, IN(31), dO, 1e-6f, encx, encb, det);
    if (haveShadow)
      gemm_mfma<1,1,1,64><<<8*rpxE*8, 256, 0, stream>>>(
          encb, Wt1, IN(33), dO, nullptr, tmph, det, 512, 512, S1, S1, 0, RPe, 8, rpxE);
    else
      gemm_mfma<1,0,1,64><<<8*rpxE*8, 256, 0, stream>>>(
          encx, Wt1, IN(33), dO, nullptr, tmph, det, 512, 512, S1, S1, 0, RPe, 8, rpxE);
    gemm_mfma<2,1,0,64><<<8*rpxE*8, 256, 0, stream>>>(
        tmph, Wt2, IN(35), dO, encx, tmp1, det, 512, 512, S1, S1, 0, RPe, 8, rpxE);
    ln_kernel<<<(BSZ*S1)/4, 256, 0, stream>>>(tmp1, IN(36), dO, IN(37), dO, 1e-6f, encx, encb, det);
  }

  // decoder layers
  for (int i = 0; i < 2; ++i){
    long long wO = (long long)i*512*768, oO = (long long)i*768*512;
    long long bO = (long long)i*768, dO = (long long)i*512;
    long long fO = (long long)i*512*512;
    u16 *Wt3, *WtO, *Wt1, *Wt2;
    if (haveWtAll){
      u16* base = WtAll + (size_t)(6+i)*WT_SLOT;
      Wt3 = base;
      WtO = base + (size_t)2304*512;
      Wt1 = WtO + (size_t)512*768;
      Wt2 = Wt1 + (size_t)512*512;
    } else {
      wt_batch<<<2048, 256, 0, stream>>>(IN(38), IN(40), IN(42), IN(44), IN(48), IN(50),
                                         wO, oO, fO, WtD3f, WtDOf, WtD1f, WtD2f, det);
      Wt3 = WtD3f; WtO = WtDOf; Wt1 = WtD1f; Wt2 = WtD2f;
    }
    if (haveShadow){
      gemm_mfma<0,1,1,64><<<8*rpxD*12, 256, 0, stream>>>(
          decb, Wt3, IN(39), bO, nullptr, qb, det, 512, 768, L_IN, L_IN, 0, RPd, 12, rpxD);
      gemm_qkv<1><<<8*rpxE*12, 256, 0, stream>>>(
          encb, Wt3 + (size_t)768*512, IN(41), IN(43), IN(43), bO, kb, vb, vb, det, S1, SKV, 0, RPe, 12, rpxE);
      gemm_qkv<1><<<8*rpxD*12, 256, 0, stream>>>(
          decb, Wt3 + (size_t)768*512, IN(41), IN(43), IN(43), bO, kb, vb, vb, det, L_IN, SKV, S1, RPd, 12, rpxD);
    } else {
      gemm_mfma<0,0,1,64><<<8*rpxD*12, 256, 0, stream>>>(
          decx, Wt3, IN(39), bO, nullptr, qb, det, 512, 768, L_IN, L_IN, 0, RPd, 12, rpxD);
      gemm_qkv<0><<<8*rpxE*12, 256, 0, stream>>>(
          encx, Wt3 + (size_t)768*512, IN(41), IN(43), IN(43), bO, kb, vb, vb, det, S1, SKV, 0, RPe, 12, rpxE);
      gemm_qkv<0><<<8*rpxD*12, 256, 0, stream>>>(
          decx, Wt3 + (size_t)768*512, IN(41), IN(43), IN(43), bO, kb, vb, vb, det, L_IN, SKV, S1, RPd, 12, rpxD);
    }
    attn_dec_mfma<<<3*NHD*BSZ, 256, 0, stream>>>(qb, kb, vb);
    gemm_mfma<2,1,0,64><<<8*rpxD*8, 256, 0, stream>>>(
        qb, WtO, IN(45), dO, decx, tmp1, det, 768, 512, L_IN, L_IN, 0, RPd, 8, rpxD);
    ln_kernel<<<(BSZ*L_IN)/4, 256, 0, stream>>>(tmp1, IN(46), dO, IN(47), dO, 1e-6f, decx, decb, det);
    if (haveShadow)
      gemm_mfma<1,1,1,64><<<8*rpxD*8, 256, 0, stream>>>(
          decb, Wt1, IN(49), dO, nullptr, tmph, det, 512, 512, L_IN, L_IN, 0, RPd, 8, rpxD);
    else
      gemm_mfma<1,0,1,64><<<8*rpxD*8, 256, 0, stream>>>(
          decx, Wt1, IN(49), dO, nullptr, tmph, det, 512, 512, L_IN, L_IN, 0, RPd, 8, rpxD);
    gemm_mfma<2,1,0,64><<<8*rpxD*8, 256, 0, stream>>>(
        tmph, Wt2, IN(51), dO, decx, tmp1, det, 512, 512, L_IN, L_IN, 0, RPd, 8, rpxD);
    ln_kernel<<<(BSZ*L_IN)/4, 256, 0, stream>>>(tmp1, IN(52), dO, IN(53), dO, 1e-6f, decx, decb, det);
  }

  pred_kernel<<<((BSZ*L_IN+3)/4), 256, 0, stream>>>(decx, IN(54), d_out, det);
  #undef IN
}

// Round 6
// 2531.409 us; speedup vs baseline: 1.2490x; 1.0638x over previous
//
#include <hip/hip_runtime.h>
#include <cstdint>
#include <cstddef>

// ---------------- model constants ----------------
#define BSZ   64
#define L_IN  168
#define S1    222
#define SKV   390
#define DM    512
#define HD    768
#define NHD   6
#define DK    128

typedef unsigned short u16;
typedef unsigned int u32;
typedef __attribute__((ext_vector_type(8))) short bf16x8;
typedef __attribute__((ext_vector_type(4))) float f32x4v;

// ---------------- bf16 helpers ----------------
__device__ inline float b2f(u16 u){
  union { u32 i; float f; } v; v.i = ((u32)u) << 16; return v.f;
}
__device__ inline u16 f2b(float f){
  union { float f; u32 i; } v; v.f = f;
  u32 x = v.i;
  return (u16)((x + 0x7fffu + ((x >> 16) & 1u)) >> 16);
}
__device__ inline u32 pk2(float a, float b){
  return ((u32)f2b(b) << 16) | (u32)f2b(a);
}
__device__ inline float ldv(const void* p, long long i, bool f32){
  return f32 ? ((const float*)p)[i] : b2f(((const u16*)p)[i]);
}
__device__ inline float4 ldv4(const void* p, long long i, bool f32){
  if (f32) return *(const float4*)((const float*)p + i);
  ushort4 w = *(const ushort4*)((const u16*)p + i);
  return make_float4(b2f(w.x), b2f(w.y), b2f(w.z), b2f(w.w));
}
__device__ inline bool is_f32(const u16* det){ return det[0] != 0x3F80; }
__device__ inline void unpack8(uint4 w, float* f){
  union { u32 i; float fl; } a;
  a.i = w.x << 16;          f[0] = a.fl;
  a.i = w.x & 0xffff0000u;  f[1] = a.fl;
  a.i = w.y << 16;          f[2] = a.fl;
  a.i = w.y & 0xffff0000u;  f[3] = a.fl;
  a.i = w.z << 16;          f[4] = a.fl;
  a.i = w.z & 0xffff0000u;  f[5] = a.fl;
  a.i = w.w << 16;          f[6] = a.fl;
  a.i = w.w & 0xffff0000u;  f[7] = a.fl;
}

// async global->LDS, 16B per lane; dest must be wave-uniform (HW: base + lane*16)
__device__ inline void gload_lds16(const void* g, void* l){
  __builtin_amdgcn_global_load_lds((const __attribute__((address_space(1))) void*)g,
                                   (__attribute__((address_space(3))) void*)l, 16, 0, 0);
}

// ---------------- workspace layout (float-equivalent offsets) ----------------
constexpr size_t OFF_ENCX = 0;
constexpr size_t OFF_DECX = OFF_ENCX + (size_t)BSZ*S1*DM;
constexpr size_t OFF_QB   = OFF_DECX + (size_t)BSZ*L_IN*DM;
constexpr size_t OFF_KB   = OFF_QB   + (size_t)BSZ*S1*HD/2;
constexpr size_t OFF_VB   = OFF_KB   + (size_t)BSZ*SKV*HD/2;
constexpr size_t OFF_NBR  = OFF_VB   + (size_t)BSZ*SKV*HD/2;
constexpr size_t OFF_ENCB = OFF_NBR  + 4096;
constexpr size_t OFF_DECB = OFF_ENCB + (size_t)BSZ*S1*DM/2;
constexpr size_t OFF_WT   = OFF_DECB + (size_t)BSZ*L_IN*DM/2;     // all-layer Wt: 8 slots x 2,097,152 u16
constexpr size_t WT_SLOT  = 2097152;                               // u16 per layer slot
constexpr size_t WS_NEED  = (OFF_WT) * 4;                          // shadow path
constexpr size_t WS_NEED2 = (OFF_WT + 8*WT_SLOT/2) * 4;            // + wt_all region

// ---------------- PAM sparsity ----------------
__device__ inline int scale_of(int i, int& ii){
  if (i < 168){ ii = i;       return 0; }
  if (i < 210){ ii = i - 168; return 1; }
  if (i < 220){ ii = i - 210; return 2; }
  ii = i - 220; return 3;
}
__device__ inline bool pam_ok(int i, int j){
  int ii, jj;
  int li = scale_of(i, ii);
  int lj = scale_of(j, jj);
  const int n[4] = {168, 42, 10, 2};
  if (li == lj){ int d = ii - jj; return (d <= 1 && d >= -1); }
  if (li == lj + 1){ int lo = ii*4, hi = (ii == n[li]-1) ? n[lj] : ii*4+4; return (jj >= lo && jj < hi); }
  if (lj == li + 1){ int lo = jj*4, hi = (jj == n[lj]-1) ? n[li] : jj*4+4; return (ii >= lo && ii < hi); }
  return false;
}
__global__ void build_nbr_kernel(int* __restrict__ nbr){
  int q = blockIdx.x * 256 + threadIdx.x;
  if (q >= S1) return;
  int cnt = 0;
  int list[12];
  for (int j = 0; j < S1; ++j)
    if (pam_ok(q, j) && cnt < 12) list[cnt++] = j;
  #pragma unroll
  for (int t = 0; t < 12; ++t) nbr[q*12 + t] = (t < cnt) ? list[t] : -1;
}

// ---------------- embedding: register-resident weights, grid-stride rows ----
__global__ __launch_bounds__(256)
void embed_fast(const void* __restrict__ x, const void* __restrict__ t,
                const void* __restrict__ cw, const void* __restrict__ tw,
                const void* __restrict__ tb, const u16* __restrict__ det,
                float* __restrict__ out, u16* __restrict__ out2)
{
  bool f32 = is_f32(det);
  int d0 = threadIdx.x;
  int d1 = threadIdx.x + 256;

  float w0[21], w1[21];
  #pragma unroll
  for (int i = 0; i < 21; ++i){
    w0[i] = ldv(cw, (long long)d0*21 + i, f32);
    w1[i] = ldv(cw, (long long)d1*21 + i, f32);
  }
  float tw0[4], tw1[4];
  #pragma unroll
  for (int f = 0; f < 4; ++f){
    tw0[f] = ldv(tw, (long long)f*DM + d0, f32);
    tw1[f] = ldv(tw, (long long)f*DM + d1, f32);
  }
  float tb0 = ldv(tb, d0, f32);
  float tb1 = ldv(tb, d1, f32);
  float dv0 = __expf(-(float)(d0 & ~1) * (9.210340371976184f/512.f));
  float dv1 = __expf(-(float)(d1 & ~1) * (9.210340371976184f/512.f));
  bool odd0 = (d0 & 1), odd1 = (d1 & 1);

  const int nRows = BSZ * L_IN;
  for (int row = blockIdx.x; row < nRows; row += gridDim.x){
    int b = row / L_IN, l = row - b*L_IN;
    float acc0 = 0.f, acc1 = 0.f;
    #pragma unroll
    for (int tt = 0; tt < 3; ++tt){
      int ls = l + tt - 1;
      ls = (ls < 0) ? ls + L_IN : (ls >= L_IN ? ls - L_IN : ls);
      long long xo = ((long long)(b*L_IN + ls))*7;
      #pragma unroll
      for (int c = 0; c < 7; ++c){
        float xv = ldv(x, xo + c, f32);
        acc0 += xv * w0[c*3 + tt];
        acc1 += xv * w1[c*3 + tt];
      }
    }
    float ang0 = (float)l * dv0;
    float ang1 = (float)l * dv1;
    acc0 += odd0 ? __cosf(ang0) : __sinf(ang0);
    acc1 += odd1 ? __cosf(ang1) : __sinf(ang1);
    long long to = ((long long)row)*4;
    #pragma unroll
    for (int f = 0; f < 4; ++f){
      float tv = ldv(t, to + f, f32);
      acc0 += tv * tw0[f];
      acc1 += tv * tw1[f];
    }
    acc0 += tb0;
    acc1 += tb1;
    size_t o = (size_t)row*DM;
    out[o + d0] = acc0;
    out[o + d1] = acc1;
    if (out2){
      out2[o + d0] = f2b(acc0);
      out2[o + d1] = f2b(acc1);
    }
  }
}

// ---------------- weight transpose helpers ----------------
__device__ inline void trans32(const void* W, long long wOff, int K, int N, int k0, int n0,
                               u16* __restrict__ Wt, bool f32, float* tb, int tid)
{
  int c = tid & 31, r0 = tid >> 5;
  #pragma unroll
  for (int rr = 0; rr < 32; rr += 8)
    tb[(r0+rr)*33 + c] = ldv(W, wOff + (long long)(k0+r0+rr)*N + n0 + c, f32);
  __syncthreads();
  #pragma unroll
  for (int rr = 0; rr < 32; rr += 8)
    Wt[(size_t)(n0+r0+rr)*K + k0 + c] = f2b(tb[c*33 + r0+rr]);
}

__device__ inline void wt_layer_body(int t, const void* wq, const void* wk, const void* wv,
                                     const void* wo, const void* w1, const void* w2,
                                     long long wO, long long oO, long long fO,
                                     u16* Wt3, u16* WtO, u16* Wt1, u16* Wt2,
                                     bool f32, float* tb, int tid)
{
  if (t < 384)       trans32(wq, wO, 512, 768, (t/24)*32, (t%24)*32, Wt3,               f32, tb, tid);
  else if (t < 768)  { int u = t-384;  trans32(wk, wO, 512, 768, (u/24)*32, (u%24)*32, Wt3 + (size_t)768*512,  f32, tb, tid); }
  else if (t < 1152) { int u = t-768;  trans32(wv, wO, 512, 768, (u/24)*32, (u%24)*32, Wt3 + (size_t)1536*512, f32, tb, tid); }
  else if (t < 1536) { int u = t-1152; trans32(wo, oO, 768, 512, (u/16)*32, (u%16)*32, WtO, f32, tb, tid); }
  else if (t < 1792) { int u = t-1536; trans32(w1, fO, 512, 512, (u/16)*32, (u%16)*32, Wt1, f32, tb, tid); }
  else               { int u = t-1792; trans32(w2, fO, 512, 512, (u/16)*32, (u%16)*32, Wt2, f32, tb, tid); }
}

// per-layer fallback
__global__ __launch_bounds__(256)
void wt_batch(const void* wq, const void* wk, const void* wv,
              const void* wo, const void* w1, const void* w2,
              long long wO, long long oO, long long fO,
              u16* __restrict__ Wt3, u16* __restrict__ WtO,
              u16* __restrict__ Wt1, u16* __restrict__ Wt2,
              const u16* __restrict__ det)
{
  __shared__ float tb[32*33];
  bool f32 = is_f32(det);
  wt_layer_body(blockIdx.x, wq, wk, wv, wo, w1, w2, wO, oO, fO, Wt3, WtO, Wt1, Wt2,
                f32, tb, threadIdx.x);
}

// all 8 layers in one launch: slots 0..5 = enc layers, 6..7 = dec layers
__global__ __launch_bounds__(256)
void wt_all(const void* ewq, const void* ewk, const void* ewv, const void* ewo,
            const void* ew1, const void* ew2,
            const void* dwq, const void* dwk, const void* dwv, const void* dwo,
            const void* dw1, const void* dw2,
            u16* __restrict__ WtAll, const u16* __restrict__ det)
{
  __shared__ float tb[32*33];
  bool f32 = is_f32(det);
  int s = blockIdx.x >> 11;
  int t = blockIdx.x & 2047;
  bool enc = s < 6;
  int li = enc ? s : s - 6;
  long long wO = (long long)li*512*768, oO = (long long)li*768*512, fO = (long long)li*512*512;
  u16* base = WtAll + (size_t)s*WT_SLOT;
  wt_layer_body(t,
                enc ? ewq : dwq, enc ? ewk : dwk, enc ? ewv : dwv,
                enc ? ewo : dwo, enc ? ew1 : dw1, enc ? ew2 : dw2,
                wO, oO, fO,
                base, base + (size_t)2304*512,
                base + (size_t)2304*512 + (size_t)512*768,
                base + (size_t)2304*512 + (size_t)512*768 + (size_t)512*512,
                f32, tb, threadIdx.x);
}

// ---------------- XCD-exclusive row-panel swizzle (CN-wide col panels) --------
template<int CN>
__device__ inline bool swzT(int t, int RP, int CP, int rpx, int& row0, int& col0){
  int xcd = t & 7, j = t >> 3;
  int rp = xcd + 8*(j % rpx);
  int cp = j / rpx;
  if (rp >= RP || cp >= CP) return false;
  row0 = rp*128; col0 = cp*CN;
  return true;
}

// ---------------- MFMA GEMM: C = A[M,K] @ W via Wt bf16 [N,K] ----------------
// Tile 128 x CN (CN = 128 or 64). bf16 staging via global_load_lds w=16 with
// pre-swizzled SOURCE (linear LDS dest).
template<int EPI, int ABF, int CBF, int CN>
__global__ __launch_bounds__(256)
void gemm_mfma(const void* __restrict__ Av, const u16* __restrict__ Wt,
               const void* __restrict__ bias, long long bOff, const float* __restrict__ R,
               void* __restrict__ Cv, const u16* __restrict__ det,
               int K, int N, int La, int Lc, int off, int RP, int CP, int rpx)
{
  constexpr int NF = CN/32;                  // n-frags (16-wide) per wave
  __shared__ u16 As[128][64];
  __shared__ u16 Bs[CN][64];
  bool f32 = is_f32(det);
  int tid = threadIdx.x;
  int row0, col0;
  if (!swzT<CN>(blockIdx.x, RP, CP, rpx, row0, col0)) return;
  int wave = tid >> 6, lane = tid & 63;
  int wm = (wave >> 1)*64, wn = (wave & 1)*(CN/2);
  int lm = lane & 15, quad = lane >> 4;
  int sr = tid >> 1;
  int sh = (tid & 1) * 32;
  int swzS = (sr & 7) * 8;
  int r8 = lane >> 3;                 // 0..7 (row within 8-row wave chunk)
  int scw = ((lane & 7)*8) ^ (r8*8);  // pre-swizzled source col (u16 units)
  f32x4v acc[4][NF];
  #pragma unroll
  for (int i = 0; i < 4; ++i)
    #pragma unroll
    for (int j = 0; j < NF; ++j) acc[i][j] = (f32x4v){0.f,0.f,0.f,0.f};

  for (int k0 = 0; k0 < K; k0 += 64){
    if (ABF){
      const u16* base = (const u16*)Av + (size_t)row0*K + k0 + scw;
      #pragma unroll
      for (int j = 0; j < 4; ++j){
        int r = wave*32 + j*8;
        gload_lds16(base + (size_t)(r + r8)*K, &As[r][0]);
      }
    } else {
      const float* src = (const float*)Av + (size_t)(row0+sr)*K + k0 + sh;
      #pragma unroll
      for (int j = 0; j < 4; ++j){
        float4 f0 = *(const float4*)(src + 8*j);
        float4 f1 = *(const float4*)(src + 8*j + 4);
        uint4 o;
        o.x = pk2(f0.x, f0.y); o.y = pk2(f0.z, f0.w);
        o.z = pk2(f1.x, f1.y); o.w = pk2(f1.z, f1.w);
        *(uint4*)&As[sr][(sh + 8*j)^swzS] = o;
      }
    }
    {
      const u16* base = Wt + (size_t)col0*K + k0 + scw;
      #pragma unroll
      for (int j = 0; j < CN/32; ++j){
        int r = wave*(CN/4) + j*8;
        gload_lds16(base + (size_t)(r + r8)*K, &Bs[r][0]);
      }
    }
    __syncthreads();
    bf16x8 af[4][2], bfr[NF][2];
    #pragma unroll
    for (int mi = 0; mi < 4; ++mi){
      int m = wm + mi*16 + lm;
      int sz = (m & 7)*8;
      af[mi][0] = *(const bf16x8*)&As[m][(quad*8) ^ sz];
      af[mi][1] = *(const bf16x8*)&As[m][(32 + quad*8) ^ sz];
    }
    #pragma unroll
    for (int ni = 0; ni < NF; ++ni){
      int n = wn + ni*16 + lm;
      int sz = (n & 7)*8;
      bfr[ni][0] = *(const bf16x8*)&Bs[n][(quad*8) ^ sz];
      bfr[ni][1] = *(const bf16x8*)&Bs[n][(32 + quad*8) ^ sz];
    }
    #pragma unroll
    for (int mi = 0; mi < 4; ++mi)
      #pragma unroll
      for (int ni = 0; ni < NF; ++ni){
        acc[mi][ni] = __builtin_amdgcn_mfma_f32_16x16x32_bf16(af[mi][0], bfr[ni][0], acc[mi][ni], 0, 0, 0);
        acc[mi][ni] = __builtin_amdgcn_mfma_f32_16x16x32_bf16(af[mi][1], bfr[ni][1], acc[mi][ni], 0, 0, 0);
      }
    __syncthreads();
  }
  #pragma unroll
  for (int mi = 0; mi < 4; ++mi){
    #pragma unroll
    for (int r = 0; r < 4; ++r){
      int row = row0 + wm + mi*16 + quad*4 + r;
      int bb = row / La, l = row - bb*La;
      size_t crow = ((size_t)bb*Lc + off + l)*(size_t)N;
      #pragma unroll
      for (int ni = 0; ni < NF; ++ni){
        int col = col0 + wn + ni*16 + lm;
        float vv = acc[mi][ni][r] + ldv(bias, bOff + col, f32);
        if (EPI == 1) vv = 0.5f*vv*(1.f + erff(vv*0.70710678118654752f));
        if (EPI == 2) vv += R[crow + col];
        if (CBF) ((u16*)Cv)[crow + col] = f2b(vv);
        else     ((float*)Cv)[crow + col] = vv;
      }
    }
  }
}

// ---------------- fused QKV / KV MFMA GEMM (K=512), swizzled, CN-tiled --------
template<int ABF, int CN>
__global__ __launch_bounds__(256)
void gemm_qkv(const void* __restrict__ Av, const u16* __restrict__ Wt,
              const void* __restrict__ b0, const void* __restrict__ b1, const void* __restrict__ b2,
              long long bOff, u16* __restrict__ o0, u16* __restrict__ o1, u16* __restrict__ o2,
              const u16* __restrict__ det, int La, int Lc, int off, int RP, int CP, int rpx)
{
  constexpr int NF = CN/32;
  __shared__ u16 As[128][64];
  __shared__ u16 Bs[CN][64];
  bool f32 = is_f32(det);
  const int K = 512;
  int tid = threadIdx.x;
  int row0, col0;
  if (!swzT<CN>(blockIdx.x, RP, CP, rpx, row0, col0)) return;
  int wave = tid >> 6, lane = tid & 63;
  int wm = (wave >> 1)*64, wn = (wave & 1)*(CN/2);
  int lm = lane & 15, quad = lane >> 4;
  int sr = tid >> 1;
  int sh = (tid & 1) * 32;
  int swzS = (sr & 7) * 8;
  int r8 = lane >> 3;
  int scw = ((lane & 7)*8) ^ (r8*8);
  f32x4v acc[4][NF];
  #pragma unroll
  for (int i = 0; i < 4; ++i)
    #pragma unroll
    for (int j = 0; j < NF; ++j) acc[i][j] = (f32x4v){0.f,0.f,0.f,0.f};

  for (int k0 = 0; k0 < K; k0 += 64){
    if (ABF){
      const u16* base = (const u16*)Av + (size_t)row0*K + k0 + scw;
      #pragma unroll
      for (int j = 0; j < 4; ++j){
        int r = wave*32 + j*8;
        gload_lds16(base + (size_t)(r + r8)*K, &As[r][0]);
      }
    } else {
      const float* src = (const float*)Av + (size_t)(row0+sr)*K + k0 + sh;
      #pragma unroll
      for (int j = 0; j < 4; ++j){
        float4 f0 = *(const float4*)(src + 8*j);
        float4 f1 = *(const float4*)(src + 8*j + 4);
        uint4 o;
        o.x = pk2(f0.x, f0.y); o.y = pk2(f0.z, f0.w);
        o.z = pk2(f1.x, f1.y); o.w = pk2(f1.z, f1.w);
        *(uint4*)&As[sr][(sh + 8*j)^swzS] = o;
      }
    }
    {
      const u16* base = Wt + (size_t)col0*K + k0 + scw;
      #pragma unroll
      for (int j = 0; j < CN/32; ++j){
        int r = wave*(CN/4) + j*8;
        gload_lds16(base + (size_t)(r + r8)*K, &Bs[r][0]);
      }
    }
    __syncthreads();
    bf16x8 af[4][2], bfr[NF][2];
    #pragma unroll
    for (int mi = 0; mi < 4; ++mi){
      int m = wm + mi*16 + lm;
      int sz = (m & 7)*8;
      af[mi][0] = *(const bf16x8*)&As[m][(quad*8) ^ sz];
      af[mi][1] = *(const bf16x8*)&As[m][(32 + quad*8) ^ sz];
    }
    #pragma unroll
    for (int ni = 0; ni < NF; ++ni){
      int n = wn + ni*16 + lm;
      int sz = (n & 7)*8;
      bfr[ni][0] = *(const bf16x8*)&Bs[n][(quad*8) ^ sz];
      bfr[ni][1] = *(const bf16x8*)&Bs[n][(32 + quad*8) ^ sz];
    }
    #pragma unroll
    for (int mi = 0; mi < 4; ++mi)
      #pragma unroll
      for (int ni = 0; ni < NF; ++ni){
        acc[mi][ni] = __builtin_amdgcn_mfma_f32_16x16x32_bf16(af[mi][0], bfr[ni][0], acc[mi][ni], 0, 0, 0);
        acc[mi][ni] = __builtin_amdgcn_mfma_f32_16x16x32_bf16(af[mi][1], bfr[ni][1], acc[mi][ni], 0, 0, 0);
      }
    __syncthreads();
  }
  #pragma unroll
  for (int mi = 0; mi < 4; ++mi){
    #pragma unroll
    for (int r = 0; r < 4; ++r){
      int row = row0 + wm + mi*16 + quad*4 + r;
      int bb = row / La, l = row - bb*La;
      size_t crow = ((size_t)bb*Lc + off + l)*(size_t)HD;
      #pragma unroll
      for (int ni = 0; ni < NF; ++ni){
        int col = col0 + wn + ni*16 + lm;
        int sel = (col >= 1536) ? 2 : (col >= 768 ? 1 : 0);
        int colr = col - sel*768;
        const void* bp = (sel == 0) ? b0 : (sel == 1) ? b1 : b2;
        u16* dst = (sel == 0) ? o0 : (sel == 1) ? o1 : o2;
        float vv = acc[mi][ni][r] + ldv(bp, bOff + colr, f32);
        dst[crow + colr] = f2b(vv);
      }
    }
  }
}

// ---------------- SIMT GEMM (bottleneck) ----------------
#define BM 64
#define BN 64
#define BK 16
__global__ __launch_bounds__(256)
void gemm_k(const float* __restrict__ A, const void* __restrict__ W, long long wOff,
            const void* __restrict__ bias, long long bOff,
            float* __restrict__ C, const u16* __restrict__ det, int K, int N)
{
  __shared__ float As2[BK][BM+4];
  __shared__ float Bs2[BK][BN+4];
  bool f32 = is_f32(det);
  int tid = threadIdx.x;
  int row0 = blockIdx.y * BM, col0 = blockIdx.x * BN;
  int ty = tid >> 4, tx = tid & 15;
  int lr = tid >> 2, lc4 = (tid & 3) << 2;
  int wr = tid >> 4, wc4 = (tid & 15) << 2;
  float acc[4][4] = {};
  for (int k0 = 0; k0 < K; k0 += BK){
    float4 av = *(const float4*)(A + (size_t)(row0 + lr)*K + k0 + lc4);
    As2[lc4+0][lr] = av.x; As2[lc4+1][lr] = av.y;
    As2[lc4+2][lr] = av.z; As2[lc4+3][lr] = av.w;
    float4 wv = ldv4(W, wOff + (long long)(k0 + wr)*N + col0 + wc4, f32);
    *(float4*)&Bs2[wr][wc4] = wv;
    __syncthreads();
    #pragma unroll
    for (int kk = 0; kk < BK; ++kk){
      float4 a  = *(const float4*)&As2[kk][ty << 2];
      float4 bb = *(const float4*)&Bs2[kk][tx << 2];
      acc[0][0] += a.x*bb.x; acc[0][1] += a.x*bb.y; acc[0][2] += a.x*bb.z; acc[0][3] += a.x*bb.w;
      acc[1][0] += a.y*bb.x; acc[1][1] += a.y*bb.y; acc[1][2] += a.y*bb.z; acc[1][3] += a.y*bb.w;
      acc[2][0] += a.z*bb.x; acc[2][1] += a.z*bb.y; acc[2][2] += a.z*bb.z; acc[2][3] += a.z*bb.w;
      acc[3][0] += a.w*bb.x; acc[3][1] += a.w*bb.y; acc[3][2] += a.w*bb.z; acc[3][3] += a.w*bb.w;
    }
    __syncthreads();
  }
  #pragma unroll
  for (int i = 0; i < 4; ++i){
    int r = row0 + (ty << 2) + i;
    size_t crow = (size_t)r*(size_t)N;
    #pragma unroll
    for (int j = 0; j < 4; ++j){
      int c = col0 + (tx << 2) + j;
      C[crow + c] = acc[i][j] + ldv(bias, bOff + c, f32);
    }
  }
}

// ---------------- conv weight reorder ----------------
__global__ void wc_kernel(const void* __restrict__ w, float* __restrict__ Wc,
                          const u16* __restrict__ det)
{
  bool f32 = is_f32(det);
  int idx = blockIdx.x * 256 + threadIdx.x;
  if (idx >= 3*512*128) return;
  int co = idx & 127;
  int kk = (idx >> 7) & 511;
  int lay = idx >> 16;
  int tt = kk >> 7, ci = kk & 127;
  Wc[idx] = ldv(w, (long long)lay*65536 + co*512 + ci*4 + tt, f32);
}

// ---------------- bottleneck conv as GEMM + BN + ELU ----------------
__global__ __launch_bounds__(256)
void conv_gemm(const float* __restrict__ in, int inStride, int inOff,
               float* __restrict__ out, int outStride, int outOff, int Lout,
               const float* __restrict__ Wc,
               const void* __restrict__ cb, const void* __restrict__ bg,
               const void* __restrict__ bb, const void* __restrict__ bm,
               const void* __restrict__ bv, const u16* __restrict__ det, int lay)
{
  __shared__ float As2[BK][BM+4];
  __shared__ float Bs2[BK][BN+4];
  bool f32 = is_f32(det);
  int tid = threadIdx.x;
  int row0 = blockIdx.y * BM, col0 = blockIdx.x * BN;
  int ty = tid >> 4, tx = tid & 15;
  int lr = tid >> 2, lc4 = (tid & 3) << 2;
  int wr = tid >> 4, wc4 = (tid & 15) << 2;
  int rs = row0 + lr;
  int bs = rs / Lout, js = rs - bs*Lout;
  const float* arow = in + ((size_t)(bs*inStride + inOff + js*4))*128;
  float acc[4][4] = {};
  for (int k0 = 0; k0 < 512; k0 += BK){
    float4 av = *(const float4*)(arow + k0 + lc4);
    As2[lc4+0][lr] = av.x; As2[lc4+1][lr] = av.y;
    As2[lc4+2][lr] = av.z; As2[lc4+3][lr] = av.w;
    float4 wv = *(const float4*)(Wc + (size_t)(k0 + wr)*128 + col0 + wc4);
    *(float4*)&Bs2[wr][wc4] = wv;
    __syncthreads();
    #pragma unroll
    for (int kk = 0; kk < BK; ++kk){
      float4 a  = *(const float4*)&As2[kk][ty << 2];
      float4 bb2 = *(const float4*)&Bs2[kk][tx << 2];
      acc[0][0] += a.x*bb2.x; acc[0][1] += a.x*bb2.y; acc[0][2] += a.x*bb2.z; acc[0][3] += a.x*bb2.w;
      acc[1][0] += a.y*bb2.x; acc[1][1] += a.y*bb2.y; acc[1][2] += a.y*bb2.z; acc[1][3] += a.y*bb2.w;
      acc[2][0] += a.z*bb2.x; acc[2][1] += a.z*bb2.y; acc[2][2] += a.z*bb2.z; acc[2][3] += a.z*bb2.w;
      acc[3][0] += a.w*bb2.x; acc[3][1] += a.w*bb2.y; acc[3][2] += a.w*bb2.z; acc[3][3] += a.w*bb2.w;
    }
    __syncthreads();
  }
  #pragma unroll
  for (int i = 0; i < 4; ++i){
    int r = row0 + (ty << 2) + i;
    int b = r / Lout, j = r - b*Lout;
    float* orow = out + ((size_t)(b*outStride + outOff + j))*128;
    #pragma unroll
    for (int jj = 0; jj < 4; ++jj){
      int co = col0 + (tx << 2) + jj;
      long long po = (long long)lay*128 + co;
      float a = acc[i][jj] + ldv(cb, po, f32);
      a = (a - ldv(bm, po, f32)) * rsqrtf(ldv(bv, po, f32) + 1e-5f) * ldv(bg, po, f32) + ldv(bb, po, f32);
      a = a > 0.f ? a : (__expf(a) - 1.f);
      orow[co] = a;
    }
  }
}

// ---------------- LayerNorm (4 rows/block, optional bf16 shadow) ----------------
__global__ __launch_bounds__(256)
void ln_kernel(const float* __restrict__ X, const void* __restrict__ g, long long gOff,
               const void* __restrict__ bt, long long bOff, float eps,
               float* __restrict__ Out, u16* __restrict__ OutB, const u16* __restrict__ det)
{
  bool f32 = is_f32(det);
  int row = blockIdx.x*4 + (threadIdx.x >> 6);
  int lane = threadIdx.x & 63;
  const float* xr = X + (size_t)row*DM;
  float v[8]; float s = 0.f;
  #pragma unroll
  for (int i = 0; i < 8; ++i){ v[i] = xr[lane + i*64]; s += v[i]; }
  #pragma unroll
  for (int o = 32; o > 0; o >>= 1) s += __shfl_xor(s, o);
  float mean = s * (1.f/512.f);
  float q = 0.f;
  #pragma unroll
  for (int i = 0; i < 8; ++i){ float d = v[i]-mean; q += d*d; }
  #pragma unroll
  for (int o = 32; o > 0; o >>= 1) q += __shfl_xor(q, o);
  float inv = rsqrtf(q*(1.f/512.f) + eps);
  float* orow = Out + (size_t)row*DM;
  #pragma unroll
  for (int i = 0; i < 8; ++i){
    int c = lane + i*64;
    float val = (v[i]-mean)*inv*ldv(g, gOff + c, f32) + ldv(bt, bOff + c, f32);
    orow[c] = val;
    if (OutB) OutB[(size_t)row*DM + c] = f2b(val);
  }
}

// ---------------- concat + LayerNorm(1e-5), 4 rows/block, optional shadow ----------------
__global__ __launch_bounds__(256)
void concat_ln_kernel(const float* __restrict__ emb, const float* __restrict__ up,
                      const void* __restrict__ g, const void* __restrict__ bt,
                      float* __restrict__ Out, u16* __restrict__ OutB, const u16* __restrict__ det)
{
  bool f32 = is_f32(det);
  int row = blockIdx.x*4 + (threadIdx.x >> 6);
  int lane = threadIdx.x & 63;
  int b = row / S1, l = row - b*S1;
  const float* xr = (l < L_IN) ? emb + ((size_t)(b*L_IN + l))*DM
                               : up  + ((size_t)(b*54 + (l - L_IN)))*DM;
  float v[8]; float s = 0.f;
  #pragma unroll
  for (int i = 0; i < 8; ++i){ v[i] = xr[lane + i*64]; s += v[i]; }
  #pragma unroll
  for (int o = 32; o > 0; o >>= 1) s += __shfl_xor(s, o);
  float mean = s * (1.f/512.f);
  float q = 0.f;
  #pragma unroll
  for (int i = 0; i < 8; ++i){ float d = v[i]-mean; q += d*d; }
  #pragma unroll
  for (int o = 32; o > 0; o >>= 1) q += __shfl_xor(q, o);
  float inv = rsqrtf(q*(1.f/512.f) + 1e-5f);
  float* orow = Out + (size_t)row*DM;
  #pragma unroll
  for (int i = 0; i < 8; ++i){
    int c = lane + i*64;
    float val = (v[i]-mean)*inv*ldv(g, c, f32) + ldv(bt, c, f32);
    orow[c] = val;
    if (OutB) OutB[(size_t)row*DM + c] = f2b(val);
  }
}

// ---------------- encoder attention: PAM-sparse, 16-lane unit per (b,q,h) ----------------
__global__ __launch_bounds__(256)
void attn_enc_sparse(u16* __restrict__ q, const u16* __restrict__ k,
                     const u16* __restrict__ v, const int* __restrict__ nbr)
{
  int u = blockIdx.x * 16 + (threadIdx.x >> 4);
  int lane16 = threadIdx.x & 15;
  int h = u % NHD;
  int bq = u / NHD;
  int b = bq / S1, qr = bq - b*S1;
  const float scale = 0.088388347648318447f;
  size_t rowoff = (size_t)bq*HD + h*DK + lane16*8;
  uint4 qw = *(const uint4*)(q + rowoff);
  float qd[8]; unpack8(qw, qd);
  const int* nb = nbr + qr*12;
  size_t base = (size_t)b*S1*HD + h*DK + lane16*8;
  float pj[12];
  #pragma unroll
  for (int j = 0; j < 12; ++j){
    int kg = nb[j];
    int kgc = kg < 0 ? 0 : kg;
    uint4 kw = *(const uint4*)(k + (size_t)kgc*HD + base);
    float kd[8]; unpack8(kw, kd);
    float p = qd[0]*kd[0] + qd[1]*kd[1] + qd[2]*kd[2] + qd[3]*kd[3]
            + qd[4]*kd[4] + qd[5]*kd[5] + qd[6]*kd[6] + qd[7]*kd[7];
    p += __shfl_xor(p, 1); p += __shfl_xor(p, 2);
    p += __shfl_xor(p, 4); p += __shfl_xor(p, 8);
    pj[j] = (kg >= 0) ? p*scale : -1e30f;
  }
  float m = -1e30f;
  #pragma unroll
  for (int j = 0; j < 12; ++j) m = fmaxf(m, pj[j]);
  float s = 0.f;
  #pragma unroll
  for (int j = 0; j < 12; ++j){ pj[j] = __expf(pj[j] - m); s += pj[j]; }
  float inv = 1.f / s;
  float o[8];
  #pragma unroll
  for (int i = 0; i < 8; ++i) o[i] = 0.f;
  #pragma unroll
  for (int j = 0; j < 12; ++j){
    int kg = nb[j];
    int kgc = kg < 0 ? 0 : kg;
    uint4 vw = *(const uint4*)(v + (size_t)kgc*HD + base);
    float vd[8]; unpack8(vw, vd);
    #pragma unroll
    for (int i = 0; i < 8; ++i) o[i] += pj[j]*vd[i];
  }
  uint4 ow;
  ow.x = pk2(o[0]*inv, o[1]*inv);
  ow.y = pk2(o[2]*inv, o[3]*inv);
  ow.z = pk2(o[4]*inv, o[5]*inv);
  ow.w = pk2(o[6]*inv, o[7]*inv);
  *(uint4*)(q + rowoff) = ow;
}

// ---------------- decoder attention: MFMA flash (v3) ----------------
// (a) reg-prefetch pipeline (T14); (b) XCD-coherent 1-D grid.
#define FQT 64
__global__ __launch_bounds__(256)
void attn_dec_mfma(u16* __restrict__ q, const u16* __restrict__ k,
                   const u16* __restrict__ v)
{
  __shared__ __align__(16) u16 Ks[32][136];
  __shared__ __align__(16) u32 Vt[16][132];
  __shared__ __align__(16) u32 Pls[4][16][16];
  int id = blockIdx.x;
  int qt = id / 384;
  int rem = id - qt*384;
  int h = rem >> 6;
  int b = rem & 63;
  int qt0 = qt * FQT;
  int tid = threadIdx.x;
  int wave = tid >> 6, lane = tid & 63;
  int lm = lane & 15, quad = lane >> 4;
  const float scale = 0.088388347648318447f;
  const size_t qb0 = (size_t)b*L_IN*HD + (size_t)h*DK;
  const size_t kb0 = (size_t)b*SKV*HD + (size_t)h*DK;

  bf16x8 qf[4];
  {
    int qg = qt0 + wave*16 + lm;
    if (qg < L_IN){
      #pragma unroll
      for (int ks = 0; ks < 4; ++ks)
        qf[ks] = *(const bf16x8*)(q + qb0 + (size_t)qg*HD + ks*32 + quad*8);
    } else {
      #pragma unroll
      for (int ks = 0; ks < 4; ++ks) qf[ks] = (bf16x8){0,0,0,0,0,0,0,0};
    }
  }

  float mold[4], lsum[4];
  #pragma unroll
  for (int r = 0; r < 4; ++r){ mold[r] = -1e30f; lsum[r] = 0.f; }
  f32x4v oacc[8];
  #pragma unroll
  for (int f = 0; f < 8; ++f) oacc[f] = (f32x4v){0.f,0.f,0.f,0.f};

  int kEnd = S1 + qt0 + FQT; if (kEnd > SKV) kEnd = SKV;
  int nt = (kEnd + 31) >> 5;

  ushort4 kr[4];
  ushort4 vr[2][2];
  {
    const int kt0 = 0;
    #pragma unroll
    for (int j = 0; j < 4; ++j){
      int i = tid*4 + j*1024;
      int kk = i >> 7, d = i & 127;
      int kg = kt0 + kk;
      kr[j] = make_ushort4(0,0,0,0);
      if (kg < SKV) kr[j] = *(const ushort4*)(k + kb0 + (size_t)kg*HD + d);
    }
    #pragma unroll
    for (int j = 0; j < 2; ++j){
      int t2 = tid + j*256;
      int g = t2 & 31, p = t2 >> 5;
      int d0 = g*4;
      int kg0 = kt0 + p, kg1 = kt0 + p + 16;
      vr[j][0] = make_ushort4(0,0,0,0);
      vr[j][1] = make_ushort4(0,0,0,0);
      if (kg0 < SKV) vr[j][0] = *(const ushort4*)(v + kb0 + (size_t)kg0*HD + d0);
      if (kg1 < SKV) vr[j][1] = *(const ushort4*)(v + kb0 + (size_t)kg1*HD + d0);
    }
  }

  for (int ti = 0; ti < nt; ++ti){
    int kt0 = ti << 5;
    __syncthreads();
    #pragma unroll
    for (int j = 0; j < 4; ++j){
      int i = tid*4 + j*1024;
      int kk = i >> 7, d = i & 127;
      *(ushort4*)&Ks[kk][d] = kr[j];
    }
    #pragma unroll
    for (int j = 0; j < 2; ++j){
      int t2 = tid + j*256;
      int g = t2 & 31, p = t2 >> 5;
      int d0 = g*4;
      uint4 o;
      o.x = (u32)vr[j][0].x | ((u32)vr[j][1].x << 16);
      o.y = (u32)vr[j][0].y | ((u32)vr[j][1].y << 16);
      o.z = (u32)vr[j][0].z | ((u32)vr[j][1].z << 16);
      o.w = (u32)vr[j][0].w | ((u32)vr[j][1].w << 16);
      *(uint4*)&Vt[p][d0] = o;
    }
    if (ti + 1 < nt){
      const int kn = (ti + 1) << 5;
      #pragma unroll
      for (int j = 0; j < 4; ++j){
        int i = tid*4 + j*1024;
        int kk = i >> 7, d = i & 127;
        int kg = kn + kk;
        kr[j] = make_ushort4(0,0,0,0);
        if (kg < SKV) kr[j] = *(const ushort4*)(k + kb0 + (size_t)kg*HD + d);
      }
      #pragma unroll
      for (int j = 0; j < 2; ++j){
        int t2 = tid + j*256;
        int g = t2 & 31, p = t2 >> 5;
        int d0 = g*4;
        int kg0 = kn + p, kg1 = kn + p + 16;
        vr[j][0] = make_ushort4(0,0,0,0);
        vr[j][1] = make_ushort4(0,0,0,0);
        if (kg0 < SKV) vr[j][0] = *(const ushort4*)(v + kb0 + (size_t)kg0*HD + d0);
        if (kg1 < SKV) vr[j][1] = *(const ushort4*)(v + kb0 + (size_t)kg1*HD + d0);
      }
    }
    __syncthreads();
    f32x4v sacc[2];
    sacc[0] = (f32x4v){0.f,0.f,0.f,0.f};
    sacc[1] = (f32x4v){0.f,0.f,0.f,0.f};
    #pragma unroll
    for (int t = 0; t < 2; ++t)
      #pragma unroll
      for (int ks = 0; ks < 4; ++ks){
        bf16x8 kf = *(const bf16x8*)&Ks[t*16 + lm][ks*32 + quad*8];
        sacc[t] = __builtin_amdgcn_mfma_f32_16x16x32_bf16(qf[ks], kf, sacc[t], 0, 0, 0);
      }
    float p[2][4];
    #pragma unroll
    for (int r = 0; r < 4; ++r){
      int qg = qt0 + wave*16 + quad*4 + r;
      float s0, s1;
      {
        int kg = kt0 + lm;
        bool ok = (kg < SKV) && (qg < L_IN) && (kg <= S1 + qg);
        s0 = ok ? sacc[0][r]*scale : -1e30f;
      }
      {
        int kg = kt0 + 16 + lm;
        bool ok = (kg < SKV) && (qg < L_IN) && (kg <= S1 + qg);
        s1 = ok ? sacc[1][r]*scale : -1e30f;
      }
      float mn = fmaxf(s0, s1);
      #pragma unroll
      for (int o = 8; o > 0; o >>= 1) mn = fmaxf(mn, __shfl_xor(mn, o));
      float mi = fmaxf(mold[r], mn);
      float alpha = __expf(mold[r] - mi);
      mold[r] = mi;
      p[0][r] = __expf(s0 - mi);
      p[1][r] = __expf(s1 - mi);
      float rs = p[0][r] + p[1][r];
      #pragma unroll
      for (int o = 8; o > 0; o >>= 1) rs += __shfl_xor(rs, o);
      lsum[r] = lsum[r]*alpha + rs;
      #pragma unroll
      for (int f = 0; f < 8; ++f) oacc[f][r] *= alpha;
    }
    #pragma unroll
    for (int r = 0; r < 4; ++r)
      Pls[wave][quad*4+r][lm] = pk2(p[0][r], p[1][r]);
    bf16x8 pa = *(const bf16x8*)&Pls[wave][lm][quad*4];
    #pragma unroll
    for (int f = 0; f < 8; ++f){
      union { u32 u[4]; bf16x8 v8; } vv;
      vv.u[0] = Vt[quad*4+0][f*16 + lm];
      vv.u[1] = Vt[quad*4+1][f*16 + lm];
      vv.u[2] = Vt[quad*4+2][f*16 + lm];
      vv.u[3] = Vt[quad*4+3][f*16 + lm];
      oacc[f] = __builtin_amdgcn_mfma_f32_16x16x32_bf16(pa, vv.v8, oacc[f], 0, 0, 0);
    }
  }
  #pragma unroll
  for (int r = 0; r < 4; ++r){
    int qg = qt0 + wave*16 + quad*4 + r;
    if (qg < L_IN){
      float inv = 1.f / lsum[r];
      #pragma unroll
      for (int f = 0; f < 8; ++f)
        q[qb0 + (size_t)qg*HD + f*16 + lm] = f2b(oacc[f][r]*inv);
    }
  }
}

// ---------------- prediction head: one wave per row, shfl-reduce ----------------
__global__ __launch_bounds__(256)
void pred_kernel(const float* __restrict__ X, const void* __restrict__ w,
                 void* __restrict__ out, const u16* __restrict__ det)
{
  bool f32 = is_f32(det);
  int row = blockIdx.x*4 + (threadIdx.x >> 6);
  int lane = threadIdx.x & 63;
  if (row >= BSZ*L_IN) return;
  const float* xr = X + (size_t)row*DM;
  float a0=0.f,a1=0.f,a2=0.f,a3=0.f,a4=0.f,a5=0.f,a6=0.f;
  #pragma unroll
  for (int i = 0; i < 8; ++i){
    int kk = lane + i*64;
    float xv = xr[kk];
    long long wo = (long long)kk*7;
    a0 += xv*ldv(w, wo+0, f32);
    a1 += xv*ldv(w, wo+1, f32);
    a2 += xv*ldv(w, wo+2, f32);
    a3 += xv*ldv(w, wo+3, f32);
    a4 += xv*ldv(w, wo+4, f32);
    a5 += xv*ldv(w, wo+5, f32);
    a6 += xv*ldv(w, wo+6, f32);
  }
  #pragma unroll
  for (int o = 32; o > 0; o >>= 1){
    a0 += __shfl_xor(a0, o); a1 += __shfl_xor(a1, o); a2 += __shfl_xor(a2, o);
    a3 += __shfl_xor(a3, o); a4 += __shfl_xor(a4, o); a5 += __shfl_xor(a5, o);
    a6 += __shfl_xor(a6, o);
  }
  if (lane == 0){
    long long o0 = (long long)row*7;
    if (f32){
      float* op = (float*)out;
      op[o0+0]=a0; op[o0+1]=a1; op[o0+2]=a2; op[o0+3]=a3;
      op[o0+4]=a4; op[o0+5]=a5; op[o0+6]=a6;
    } else {
      u16* op = (u16*)out;
      op[o0+0]=f2b(a0); op[o0+1]=f2b(a1); op[o0+2]=f2b(a2); op[o0+3]=f2b(a3);
      op[o0+4]=f2b(a4); op[o0+5]=f2b(a5); op[o0+6]=f2b(a6);
    }
  }
}

// ---------------- launch ----------------
extern "C" void kernel_launch(void* const* d_in, const int* in_sizes, int n_in,
                              void* d_out, int out_size, void* d_ws, size_t ws_size,
                              hipStream_t stream)
{
  (void)in_sizes; (void)n_in; (void)out_size;
  #define IN(i) ((const void*)d_in[i])
  const u16* det = (const u16*)d_in[20];
  float* ws   = (float*)d_ws;
  float* encx = ws + OFF_ENCX;
  float* decx = ws + OFF_DECX;
  u16*   qb   = (u16*)(ws + OFF_QB);
  u16*   kb   = (u16*)(ws + OFF_KB);
  u16*   vb   = (u16*)(ws + OFF_VB);
  int*   nbr  = (int*)(ws + OFF_NBR);
  bool haveShadow = ws_size >= WS_NEED;
  bool haveWtAll  = ws_size >= WS_NEED2;
  u16*   encb = haveShadow ? (u16*)(ws + OFF_ENCB) : nullptr;
  u16*   decb = haveShadow ? (u16*)(ws + OFF_DECB) : nullptr;
  u16*   WtAll = (u16*)(ws + OFF_WT);
  // phase-disjoint aliases (fallback path + temporaries)
  float* tmp1  = ws + OFF_VB;
  u16*   WtE3f = (u16*)(ws + OFF_VB + (size_t)BSZ*S1*DM);
  u16*   WtEOf = WtE3f + (size_t)2304*512;
  u16*   WtE1f = WtEOf + (size_t)768*512;
  u16*   WtE2f = WtE1f + (size_t)512*512;
  u16*   WtD3f = (u16*)(ws + OFF_QB + (size_t)BSZ*L_IN*HD/2);
  u16*   WtDOf = WtD3f + (size_t)2304*512;
  u16*   WtD1f = WtDOf + (size_t)768*512;
  u16*   WtD2f = WtD1f + (size_t)512*512;
  u16*   tmph  = (u16*)(ws + OFF_KB);
  float* embE  = ws + OFF_VB;
  float* Wc    = ws + OFF_QB;
  float* bdown = ws + OFF_KB;
  float* bconv = bdown + (size_t)BSZ*L_IN*128;
  float* bup   = bconv + (size_t)BSZ*54*128;

  const int RPe = 111, rpxE = 14;
  const int RPd = 84,  rpxD = 11;

  build_nbr_kernel<<<1, 256, 0, stream>>>(nbr);
  if (haveWtAll)
    wt_all<<<8*2048, 256, 0, stream>>>(IN(22), IN(24), IN(26), IN(28), IN(32), IN(34),
                                       IN(38), IN(40), IN(42), IN(44), IN(48), IN(50),
                                       WtAll, det);

  embed_fast<<<1344, 256, 0, stream>>>(IN(0), IN(1), IN(4), IN(5), IN(6), det, embE, nullptr);
  embed_fast<<<1344, 256, 0, stream>>>(IN(2), IN(3), IN(7), IN(8), IN(9), det, decx, decb);

  // bottleneck
  wc_kernel<<<(3*512*128)/256, 256, 0, stream>>>(IN(12), Wc, det);
  gemm_k<<<dim3(128/BN, (BSZ*L_IN)/BM), 256, 0, stream>>>(
      embE, IN(10), 0, IN(11), 0, bdown, det, 512, 128);
  conv_gemm<<<dim3(2, (BSZ*42)/BM), 256, 0, stream>>>(
      bdown, L_IN, 0, bconv, 54, 0, 42, Wc, IN(13), IN(14), IN(15), IN(16), IN(17), det, 0);
  conv_gemm<<<dim3(2, (BSZ*10)/BM), 256, 0, stream>>>(
      bconv, 54, 0, bconv, 54, 42, 10, Wc + 65536, IN(13), IN(14), IN(15), IN(16), IN(17), det, 1);
  conv_gemm<<<dim3(2, (BSZ*2)/BM), 256, 0, stream>>>(
      bconv, 54, 42, bconv, 54, 52, 2, Wc + 131072, IN(13), IN(14), IN(15), IN(16), IN(17), det, 2);
  gemm_k<<<dim3(512/BN, (BSZ*54)/BM), 256, 0, stream>>>(
      bconv, IN(18), 0, IN(19), 0, bup, det, 128, 512);
  concat_ln_kernel<<<(BSZ*S1)/4, 256, 0, stream>>>(embE, bup, IN(20), IN(21), encx, encb, det);

  // encoder layers
  for (int i = 0; i < 6; ++i){
    long long wO = (long long)i*512*768, oO = (long long)i*768*512;
    long long bO = (long long)i*768, dO = (long long)i*512;
    long long fO = (long long)i*512*512;
    u16 *Wt3, *WtO, *Wt1, *Wt2;
    if (haveWtAll){
      u16* base = WtAll + (size_t)i*WT_SLOT;
      Wt3 = base;
      WtO = base + (size_t)2304*512;
      Wt1 = WtO + (size_t)512*768;
      Wt2 = Wt1 + (size_t)512*512;
    } else {
      wt_batch<<<2048, 256, 0, stream>>>(IN(22), IN(24), IN(26), IN(28), IN(32), IN(34),
                                         wO, oO, fO, WtE3f, WtEOf, WtE1f, WtE2f, det);
      Wt3 = WtE3f; WtO = WtEOf; Wt1 = WtE1f; Wt2 = WtE2f;
    }
    if (haveShadow)
      gemm_qkv<1,64><<<8*rpxE*36, 256, 0, stream>>>(
          encb, Wt3, IN(23), IN(25), IN(27), bO, qb, kb, vb, det, S1, S1, 0, RPe, 36, rpxE);
    else
      gemm_qkv<0,64><<<8*rpxE*36, 256, 0, stream>>>(
          encx, Wt3, IN(23), IN(25), IN(27), bO, qb, kb, vb, det, S1, S1, 0, RPe, 36, rpxE);
    attn_enc_sparse<<<(BSZ*S1*NHD)/16, 256, 0, stream>>>(qb, kb, vb, nbr);
    gemm_mfma<2,1,0,64><<<8*rpxE*8, 256, 0, stream>>>(
        qb, WtO, IN(29), dO, encx, tmp1, det, 768, 512, S1, S1, 0, RPe, 8, rpxE);
    ln_kernel<<<(BSZ*S1)/4, 256, 0, stream>>>(tmp1, IN(30), dO, IN(31), dO, 1e-6f, encx, encb, det);
    if (haveShadow)
      gemm_mfma<1,1,1,64><<<8*rpxE*8, 256, 0, stream>>>(
          encb, Wt1, IN(33), dO, nullptr, tmph, det, 512, 512, S1, S1, 0, RPe, 8, rpxE);
    else
      gemm_mfma<1,0,1,64><<<8*rpxE*8, 256, 0, stream>>>(
          encx, Wt1, IN(33), dO, nullptr, tmph, det, 512, 512, S1, S1, 0, RPe, 8, rpxE);
    gemm_mfma<2,1,0,64><<<8*rpxE*8, 256, 0, stream>>>(
        tmph, Wt2, IN(35), dO, encx, tmp1, det, 512, 512, S1, S1, 0, RPe, 8, rpxE);
    ln_kernel<<<(BSZ*S1)/4, 256, 0, stream>>>(tmp1, IN(36), dO, IN(37), dO, 1e-6f, encx, encb, det);
  }

  // decoder layers
  for (int i = 0; i < 2; ++i){
    long long wO = (long long)i*512*768, oO = (long long)i*768*512;
    long long bO = (long long)i*768, dO = (long long)i*512;
    long long fO = (long long)i*512*512;
    u16 *Wt3, *WtO, *Wt1, *Wt2;
    if (haveWtAll){
      u16* base = WtAll + (size_t)(6+i)*WT_SLOT;
      Wt3 = base;
      WtO = base + (size_t)2304*512;
      Wt1 = WtO + (size_t)512*768;
      Wt2 = Wt1 + (size_t)512*512;
    } else {
      wt_batch<<<2048, 256, 0, stream>>>(IN(38), IN(40), IN(42), IN(44), IN(48), IN(50),
                                         wO, oO, fO, WtD3f, WtDOf, WtD1f, WtD2f, det);
      Wt3 = WtD3f; WtO = WtDOf; Wt1 = WtD1f; Wt2 = WtD2f;
    }
    if (haveShadow){
      gemm_mfma<0,1,1,64><<<8*rpxD*12, 256, 0, stream>>>(
          decb, Wt3, IN(39), bO, nullptr, qb, det, 512, 768, L_IN, L_IN, 0, RPd, 12, rpxD);
      gemm_qkv<1,64><<<8*rpxE*24, 256, 0, stream>>>(
          encb, Wt3 + (size_t)768*512, IN(41), IN(43), IN(43), bO, kb, vb, vb, det, S1, SKV, 0, RPe, 24, rpxE);
      gemm_qkv<1,64><<<8*rpxD*24, 256, 0, stream>>>(
          decb, Wt3 + (size_t)768*512, IN(41), IN(43), IN(43), bO, kb, vb, vb, det, L_IN, SKV, S1, RPd, 24, rpxD);
    } else {
      gemm_mfma<0,0,1,64><<<8*rpxD*12, 256, 0, stream>>>(
          decx, Wt3, IN(39), bO, nullptr, qb, det, 512, 768, L_IN, L_IN, 0, RPd, 12, rpxD);
      gemm_qkv<0,64><<<8*rpxE*24, 256, 0, stream>>>(
          encx, Wt3 + (size_t)768*512, IN(41), IN(43), IN(43), bO, kb, vb, vb, det, S1, SKV, 0, RPe, 24, rpxE);
      gemm_qkv<0,64><<<8*rpxD*24, 256, 0, stream>>>(
          decx, Wt3 + (size_t)768*512, IN(41), IN(43), IN(43), bO, kb, vb, vb, det, L_IN, SKV, S1, RPd, 24, rpxD);
    }
    attn_dec_mfma<<<3*NHD*BSZ, 256, 0, stream>>>(qb, kb, vb);
    gemm_mfma<2,1,0,64><<<8*rpxD*8, 256, 0, stream>>>(
        qb, WtO, IN(45), dO, decx, tmp1, det, 768, 512, L_IN, L_IN, 0, RPd, 8, rpxD);
    ln_kernel<<<(BSZ*L_IN)/4, 256, 0, stream>>>(tmp1, IN(46), dO, IN(47), dO, 1e-6f, decx, decb, det);
    if (haveShadow)
      gemm_mfma<1,1,1,64><<<8*rpxD*8, 256, 0, stream>>>(
          decb, Wt1, IN(49), dO, nullptr, tmph, det, 512, 512, L_IN, L_IN, 0, RPd, 8, rpxD);
    else
      gemm_mfma<1,0,1,64><<<8*rpxD*8, 256, 0, stream>>>(
          decx, Wt1, IN(49), dO, nullptr, tmph, det, 512, 512, L_IN, L_IN, 0, RPd, 8, rpxD);
    gemm_mfma<2,1,0,64><<<8*rpxD*8, 256, 0, stream>>>(
        tmph, Wt2, IN(51), dO, decx, tmp1, det, 512, 512, L_IN, L_IN, 0, RPd, 8, rpxD);
    ln_kernel<<<(BSZ*L_IN)/4, 256, 0, stream>>>(tmp1, IN(52), dO, IN(53), dO, 1e-6f, decx, decb, det);
  }

  pred_kernel<<<((BSZ*L_IN+3)/4), 256, 0, stream>>>(decx, IN(54), d_out, det);
  #undef IN
}

// Round 7
// 2359.641 us; speedup vs baseline: 1.3399x; 1.0728x over previous
//
#include <hip/hip_runtime.h>
#include <cstdint>
#include <cstddef>

// ---------------- model constants ----------------
#define BSZ   64
#define L_IN  168
#define S1    222
#define SKV   390
#define DM    512
#define HD    768
#define NHD   6
#define DK    128

typedef unsigned short u16;
typedef unsigned int u32;
typedef __attribute__((ext_vector_type(8))) short bf16x8;
typedef __attribute__((ext_vector_type(4))) float f32x4v;

// ---------------- bf16 helpers ----------------
__device__ inline float b2f(u16 u){
  union { u32 i; float f; } v; v.i = ((u32)u) << 16; return v.f;
}
__device__ inline u16 f2b(float f){
  union { float f; u32 i; } v; v.f = f;
  u32 x = v.i;
  return (u16)((x + 0x7fffu + ((x >> 16) & 1u)) >> 16);
}
__device__ inline u32 pk2(float a, float b){
  return ((u32)f2b(b) << 16) | (u32)f2b(a);
}
__device__ inline float ldv(const void* p, long long i, bool f32){
  return f32 ? ((const float*)p)[i] : b2f(((const u16*)p)[i]);
}
__device__ inline float4 ldv4(const void* p, long long i, bool f32){
  if (f32) return *(const float4*)((const float*)p + i);
  ushort4 w = *(const ushort4*)((const u16*)p + i);
  return make_float4(b2f(w.x), b2f(w.y), b2f(w.z), b2f(w.w));
}
__device__ inline bool is_f32(const u16* det){ return det[0] != 0x3F80; }
__device__ inline void unpack8(uint4 w, float* f){
  union { u32 i; float fl; } a;
  a.i = w.x << 16;          f[0] = a.fl;
  a.i = w.x & 0xffff0000u;  f[1] = a.fl;
  a.i = w.y << 16;          f[2] = a.fl;
  a.i = w.y & 0xffff0000u;  f[3] = a.fl;
  a.i = w.z << 16;          f[4] = a.fl;
  a.i = w.z & 0xffff0000u;  f[5] = a.fl;
  a.i = w.w << 16;          f[6] = a.fl;
  a.i = w.w & 0xffff0000u;  f[7] = a.fl;
}

// async global->LDS, 16B per lane; dest must be wave-uniform (HW: base + lane*16)
__device__ inline void gload_lds16(const void* g, void* l){
  __builtin_amdgcn_global_load_lds((const __attribute__((address_space(1))) void*)g,
                                   (__attribute__((address_space(3))) void*)l, 16, 0, 0);
}

// ---------------- workspace layout (float-equivalent offsets) ----------------
constexpr size_t OFF_ENCX = 0;
constexpr size_t OFF_DECX = OFF_ENCX + (size_t)BSZ*S1*DM;
constexpr size_t OFF_QB   = OFF_DECX + (size_t)BSZ*L_IN*DM;
constexpr size_t OFF_KB   = OFF_QB   + (size_t)BSZ*S1*HD/2;
constexpr size_t OFF_VB   = OFF_KB   + (size_t)BSZ*SKV*HD/2;
constexpr size_t OFF_NBR  = OFF_VB   + (size_t)BSZ*SKV*HD/2;
constexpr size_t OFF_ENCB = OFF_NBR  + 4096;
constexpr size_t OFF_DECB = OFF_ENCB + (size_t)BSZ*S1*DM/2;
constexpr size_t OFF_WT   = OFF_DECB + (size_t)BSZ*L_IN*DM/2;     // all-layer Wt: 8 slots x 2,097,152 u16
constexpr size_t WT_SLOT  = 2097152;                               // u16 per layer slot
constexpr size_t WS_NEED  = (OFF_WT) * 4;                          // shadow path
constexpr size_t WS_NEED2 = (OFF_WT + 8*WT_SLOT/2) * 4;            // + wt_all region

// ---------------- PAM sparsity ----------------
__device__ inline int scale_of(int i, int& ii){
  if (i < 168){ ii = i;       return 0; }
  if (i < 210){ ii = i - 168; return 1; }
  if (i < 220){ ii = i - 210; return 2; }
  ii = i - 220; return 3;
}
__device__ inline bool pam_ok(int i, int j){
  int ii, jj;
  int li = scale_of(i, ii);
  int lj = scale_of(j, jj);
  const int n[4] = {168, 42, 10, 2};
  if (li == lj){ int d = ii - jj; return (d <= 1 && d >= -1); }
  if (li == lj + 1){ int lo = ii*4, hi = (ii == n[li]-1) ? n[lj] : ii*4+4; return (jj >= lo && jj < hi); }
  if (lj == li + 1){ int lo = jj*4, hi = (jj == n[lj]-1) ? n[li] : jj*4+4; return (ii >= lo && ii < hi); }
  return false;
}
// wave-parallel: one wave per query row; 4 ballot rounds cover j=0..255,
// ctzll extraction preserves ascending-j order (identical to serial scan).
__global__ __launch_bounds__(256)
void build_nbr_kernel(int* __restrict__ nbr){
  int wid = (blockIdx.x * 256 + threadIdx.x) >> 6;
  int lane = threadIdx.x & 63;
  if (wid >= S1) return;
  int q = wid;
  int cnt = 0;
  int list[12];
  #pragma unroll
  for (int r = 0; r < 4; ++r){
    int j = r*64 + lane;
    bool ok = (j < S1) && pam_ok(q, j);
    unsigned long long m = __ballot(ok);
    while (m && cnt < 12){
      int bit = __builtin_ctzll(m);
      m &= m - 1;
      list[cnt++] = r*64 + bit;
    }
  }
  if (lane == 0){
    #pragma unroll
    for (int t = 0; t < 12; ++t) nbr[q*12 + t] = (t < cnt) ? list[t] : -1;
  }
}

// ---------------- embedding: register-resident weights, grid-stride rows ----
__global__ __launch_bounds__(256)
void embed_fast(const void* __restrict__ x, const void* __restrict__ t,
                const void* __restrict__ cw, const void* __restrict__ tw,
                const void* __restrict__ tb, const u16* __restrict__ det,
                float* __restrict__ out, u16* __restrict__ out2)
{
  bool f32 = is_f32(det);
  int d0 = threadIdx.x;
  int d1 = threadIdx.x + 256;

  float w0[21], w1[21];
  #pragma unroll
  for (int i = 0; i < 21; ++i){
    w0[i] = ldv(cw, (long long)d0*21 + i, f32);
    w1[i] = ldv(cw, (long long)d1*21 + i, f32);
  }
  float tw0[4], tw1[4];
  #pragma unroll
  for (int f = 0; f < 4; ++f){
    tw0[f] = ldv(tw, (long long)f*DM + d0, f32);
    tw1[f] = ldv(tw, (long long)f*DM + d1, f32);
  }
  float tb0 = ldv(tb, d0, f32);
  float tb1 = ldv(tb, d1, f32);
  float dv0 = __expf(-(float)(d0 & ~1) * (9.210340371976184f/512.f));
  float dv1 = __expf(-(float)(d1 & ~1) * (9.210340371976184f/512.f));
  bool odd0 = (d0 & 1), odd1 = (d1 & 1);

  const int nRows = BSZ * L_IN;
  for (int row = blockIdx.x; row < nRows; row += gridDim.x){
    int b = row / L_IN, l = row - b*L_IN;
    float acc0 = 0.f, acc1 = 0.f;
    #pragma unroll
    for (int tt = 0; tt < 3; ++tt){
      int ls = l + tt - 1;
      ls = (ls < 0) ? ls + L_IN : (ls >= L_IN ? ls - L_IN : ls);
      long long xo = ((long long)(b*L_IN + ls))*7;
      #pragma unroll
      for (int c = 0; c < 7; ++c){
        float xv = ldv(x, xo + c, f32);
        acc0 += xv * w0[c*3 + tt];
        acc1 += xv * w1[c*3 + tt];
      }
    }
    float ang0 = (float)l * dv0;
    float ang1 = (float)l * dv1;
    acc0 += odd0 ? __cosf(ang0) : __sinf(ang0);
    acc1 += odd1 ? __cosf(ang1) : __sinf(ang1);
    long long to = ((long long)row)*4;
    #pragma unroll
    for (int f = 0; f < 4; ++f){
      float tv = ldv(t, to + f, f32);
      acc0 += tv * tw0[f];
      acc1 += tv * tw1[f];
    }
    acc0 += tb0;
    acc1 += tb1;
    size_t o = (size_t)row*DM;
    out[o + d0] = acc0;
    out[o + d1] = acc1;
    if (out2){
      out2[o + d0] = f2b(acc0);
      out2[o + d1] = f2b(acc1);
    }
  }
}

// ---------------- weight transpose helpers ----------------
__device__ inline void trans32(const void* W, long long wOff, int K, int N, int k0, int n0,
                               u16* __restrict__ Wt, bool f32, float* tb, int tid)
{
  int c = tid & 31, r0 = tid >> 5;
  #pragma unroll
  for (int rr = 0; rr < 32; rr += 8)
    tb[(r0+rr)*33 + c] = ldv(W, wOff + (long long)(k0+r0+rr)*N + n0 + c, f32);
  __syncthreads();
  #pragma unroll
  for (int rr = 0; rr < 32; rr += 8)
    Wt[(size_t)(n0+r0+rr)*K + k0 + c] = f2b(tb[c*33 + r0+rr]);
}

__device__ inline void wt_layer_body(int t, const void* wq, const void* wk, const void* wv,
                                     const void* wo, const void* w1, const void* w2,
                                     long long wO, long long oO, long long fO,
                                     u16* Wt3, u16* WtO, u16* Wt1, u16* Wt2,
                                     bool f32, float* tb, int tid)
{
  if (t < 384)       trans32(wq, wO, 512, 768, (t/24)*32, (t%24)*32, Wt3,               f32, tb, tid);
  else if (t < 768)  { int u = t-384;  trans32(wk, wO, 512, 768, (u/24)*32, (u%24)*32, Wt3 + (size_t)768*512,  f32, tb, tid); }
  else if (t < 1152) { int u = t-768;  trans32(wv, wO, 512, 768, (u/24)*32, (u%24)*32, Wt3 + (size_t)1536*512, f32, tb, tid); }
  else if (t < 1536) { int u = t-1152; trans32(wo, oO, 768, 512, (u/16)*32, (u%16)*32, WtO, f32, tb, tid); }
  else if (t < 1792) { int u = t-1536; trans32(w1, fO, 512, 512, (u/16)*32, (u%16)*32, Wt1, f32, tb, tid); }
  else               { int u = t-1792; trans32(w2, fO, 512, 512, (u/16)*32, (u%16)*32, Wt2, f32, tb, tid); }
}

// per-layer fallback
__global__ __launch_bounds__(256)
void wt_batch(const void* wq, const void* wk, const void* wv,
              const void* wo, const void* w1, const void* w2,
              long long wO, long long oO, long long fO,
              u16* __restrict__ Wt3, u16* __restrict__ WtO,
              u16* __restrict__ Wt1, u16* __restrict__ Wt2,
              const u16* __restrict__ det)
{
  __shared__ float tb[32*33];
  bool f32 = is_f32(det);
  wt_layer_body(blockIdx.x, wq, wk, wv, wo, w1, w2, wO, oO, fO, Wt3, WtO, Wt1, Wt2,
                f32, tb, threadIdx.x);
}

// all 8 layers in one launch: slots 0..5 = enc layers, 6..7 = dec layers
__global__ __launch_bounds__(256)
void wt_all(const void* ewq, const void* ewk, const void* ewv, const void* ewo,
            const void* ew1, const void* ew2,
            const void* dwq, const void* dwk, const void* dwv, const void* dwo,
            const void* dw1, const void* dw2,
            u16* __restrict__ WtAll, const u16* __restrict__ det)
{
  __shared__ float tb[32*33];
  bool f32 = is_f32(det);
  int s = blockIdx.x >> 11;
  int t = blockIdx.x & 2047;
  bool enc = s < 6;
  int li = enc ? s : s - 6;
  long long wO = (long long)li*512*768, oO = (long long)li*768*512, fO = (long long)li*512*512;
  u16* base = WtAll + (size_t)s*WT_SLOT;
  wt_layer_body(t,
                enc ? ewq : dwq, enc ? ewk : dwk, enc ? ewv : dwv,
                enc ? ewo : dwo, enc ? ew1 : dw1, enc ? ew2 : dw2,
                wO, oO, fO,
                base, base + (size_t)2304*512,
                base + (size_t)2304*512 + (size_t)512*768,
                base + (size_t)2304*512 + (size_t)512*768 + (size_t)512*512,
                f32, tb, threadIdx.x);
}

// ---------------- XCD-exclusive row-panel swizzle (CN-wide col panels) --------
template<int CN>
__device__ inline bool swzT(int t, int RP, int CP, int rpx, int& row0, int& col0){
  int xcd = t & 7, j = t >> 3;
  int rp = xcd + 8*(j % rpx);
  int cp = j / rpx;
  if (rp >= RP || cp >= CP) return false;
  row0 = rp*128; col0 = cp*CN;
  return true;
}

// ---------------- MFMA GEMM: C = A[M,K] @ W via Wt bf16 [N,K] ----------------
// Tile 128 x CN (CN = 128 or 64). bf16 staging via global_load_lds w=16 with
// pre-swizzled SOURCE (linear LDS dest).
template<int EPI, int ABF, int CBF, int CN>
__global__ __launch_bounds__(256)
void gemm_mfma(const void* __restrict__ Av, const u16* __restrict__ Wt,
               const void* __restrict__ bias, long long bOff, const float* __restrict__ R,
               void* __restrict__ Cv, const u16* __restrict__ det,
               int K, int N, int La, int Lc, int off, int RP, int CP, int rpx)
{
  constexpr int NF = CN/32;                  // n-frags (16-wide) per wave
  __shared__ u16 As[128][64];
  __shared__ u16 Bs[CN][64];
  bool f32 = is_f32(det);
  int tid = threadIdx.x;
  int row0, col0;
  if (!swzT<CN>(blockIdx.x, RP, CP, rpx, row0, col0)) return;
  int wave = tid >> 6, lane = tid & 63;
  int wm = (wave >> 1)*64, wn = (wave & 1)*(CN/2);
  int lm = lane & 15, quad = lane >> 4;
  int sr = tid >> 1;
  int sh = (tid & 1) * 32;
  int swzS = (sr & 7) * 8;
  int r8 = lane >> 3;                 // 0..7 (row within 8-row wave chunk)
  int scw = ((lane & 7)*8) ^ (r8*8);  // pre-swizzled source col (u16 units)
  f32x4v acc[4][NF];
  #pragma unroll
  for (int i = 0; i < 4; ++i)
    #pragma unroll
    for (int j = 0; j < NF; ++j) acc[i][j] = (f32x4v){0.f,0.f,0.f,0.f};

  for (int k0 = 0; k0 < K; k0 += 64){
    if (ABF){
      const u16* base = (const u16*)Av + (size_t)row0*K + k0 + scw;
      #pragma unroll
      for (int j = 0; j < 4; ++j){
        int r = wave*32 + j*8;
        gload_lds16(base + (size_t)(r + r8)*K, &As[r][0]);
      }
    } else {
      const float* src = (const float*)Av + (size_t)(row0+sr)*K + k0 + sh;
      #pragma unroll
      for (int j = 0; j < 4; ++j){
        float4 f0 = *(const float4*)(src + 8*j);
        float4 f1 = *(const float4*)(src + 8*j + 4);
        uint4 o;
        o.x = pk2(f0.x, f0.y); o.y = pk2(f0.z, f0.w);
        o.z = pk2(f1.x, f1.y); o.w = pk2(f1.z, f1.w);
        *(uint4*)&As[sr][(sh + 8*j)^swzS] = o;
      }
    }
    {
      const u16* base = Wt + (size_t)col0*K + k0 + scw;
      #pragma unroll
      for (int j = 0; j < CN/32; ++j){
        int r = wave*(CN/4) + j*8;
        gload_lds16(base + (size_t)(r + r8)*K, &Bs[r][0]);
      }
    }
    __syncthreads();
    bf16x8 af[4][2], bfr[NF][2];
    #pragma unroll
    for (int mi = 0; mi < 4; ++mi){
      int m = wm + mi*16 + lm;
      int sz = (m & 7)*8;
      af[mi][0] = *(const bf16x8*)&As[m][(quad*8) ^ sz];
      af[mi][1] = *(const bf16x8*)&As[m][(32 + quad*8) ^ sz];
    }
    #pragma unroll
    for (int ni = 0; ni < NF; ++ni){
      int n = wn + ni*16 + lm;
      int sz = (n & 7)*8;
      bfr[ni][0] = *(const bf16x8*)&Bs[n][(quad*8) ^ sz];
      bfr[ni][1] = *(const bf16x8*)&Bs[n][(32 + quad*8) ^ sz];
    }
    #pragma unroll
    for (int mi = 0; mi < 4; ++mi)
      #pragma unroll
      for (int ni = 0; ni < NF; ++ni){
        acc[mi][ni] = __builtin_amdgcn_mfma_f32_16x16x32_bf16(af[mi][0], bfr[ni][0], acc[mi][ni], 0, 0, 0);
        acc[mi][ni] = __builtin_amdgcn_mfma_f32_16x16x32_bf16(af[mi][1], bfr[ni][1], acc[mi][ni], 0, 0, 0);
      }
    __syncthreads();
  }
  #pragma unroll
  for (int mi = 0; mi < 4; ++mi){
    #pragma unroll
    for (int r = 0; r < 4; ++r){
      int row = row0 + wm + mi*16 + quad*4 + r;
      int bb = row / La, l = row - bb*La;
      size_t crow = ((size_t)bb*Lc + off + l)*(size_t)N;
      #pragma unroll
      for (int ni = 0; ni < NF; ++ni){
        int col = col0 + wn + ni*16 + lm;
        float vv = acc[mi][ni][r] + ldv(bias, bOff + col, f32);
        if (EPI == 1) vv = 0.5f*vv*(1.f + erff(vv*0.70710678118654752f));
        if (EPI == 2) vv += R[crow + col];
        if (CBF) ((u16*)Cv)[crow + col] = f2b(vv);
        else     ((float*)Cv)[crow + col] = vv;
      }
    }
  }
}

// ---------------- fused QKV / KV MFMA GEMM (K=512), swizzled, CN-tiled --------
template<int ABF, int CN>
__global__ __launch_bounds__(256)
void gemm_qkv(const void* __restrict__ Av, const u16* __restrict__ Wt,
              const void* __restrict__ b0, const void* __restrict__ b1, const void* __restrict__ b2,
              long long bOff, u16* __restrict__ o0, u16* __restrict__ o1, u16* __restrict__ o2,
              const u16* __restrict__ det, int La, int Lc, int off, int RP, int CP, int rpx)
{
  constexpr int NF = CN/32;
  __shared__ u16 As[128][64];
  __shared__ u16 Bs[CN][64];
  bool f32 = is_f32(det);
  const int K = 512;
  int tid = threadIdx.x;
  int row0, col0;
  if (!swzT<CN>(blockIdx.x, RP, CP, rpx, row0, col0)) return;
  int wave = tid >> 6, lane = tid & 63;
  int wm = (wave >> 1)*64, wn = (wave & 1)*(CN/2);
  int lm = lane & 15, quad = lane >> 4;
  int sr = tid >> 1;
  int sh = (tid & 1) * 32;
  int swzS = (sr & 7) * 8;
  int r8 = lane >> 3;
  int scw = ((lane & 7)*8) ^ (r8*8);
  f32x4v acc[4][NF];
  #pragma unroll
  for (int i = 0; i < 4; ++i)
    #pragma unroll
    for (int j = 0; j < NF; ++j) acc[i][j] = (f32x4v){0.f,0.f,0.f,0.f};

  for (int k0 = 0; k0 < K; k0 += 64){
    if (ABF){
      const u16* base = (const u16*)Av + (size_t)row0*K + k0 + scw;
      #pragma unroll
      for (int j = 0; j < 4; ++j){
        int r = wave*32 + j*8;
        gload_lds16(base + (size_t)(r + r8)*K, &As[r][0]);
      }
    } else {
      const float* src = (const float*)Av + (size_t)(row0+sr)*K + k0 + sh;
      #pragma unroll
      for (int j = 0; j < 4; ++j){
        float4 f0 = *(const float4*)(src + 8*j);
        float4 f1 = *(const float4*)(src + 8*j + 4);
        uint4 o;
        o.x = pk2(f0.x, f0.y); o.y = pk2(f0.z, f0.w);
        o.z = pk2(f1.x, f1.y); o.w = pk2(f1.z, f1.w);
        *(uint4*)&As[sr][(sh + 8*j)^swzS] = o;
      }
    }
    {
      const u16* base = Wt + (size_t)col0*K + k0 + scw;
      #pragma unroll
      for (int j = 0; j < CN/32; ++j){
        int r = wave*(CN/4) + j*8;
        gload_lds16(base + (size_t)(r + r8)*K, &Bs[r][0]);
      }
    }
    __syncthreads();
    bf16x8 af[4][2], bfr[NF][2];
    #pragma unroll
    for (int mi = 0; mi < 4; ++mi){
      int m = wm + mi*16 + lm;
      int sz = (m & 7)*8;
      af[mi][0] = *(const bf16x8*)&As[m][(quad*8) ^ sz];
      af[mi][1] = *(const bf16x8*)&As[m][(32 + quad*8) ^ sz];
    }
    #pragma unroll
    for (int ni = 0; ni < NF; ++ni){
      int n = wn + ni*16 + lm;
      int sz = (n & 7)*8;
      bfr[ni][0] = *(const bf16x8*)&Bs[n][(quad*8) ^ sz];
      bfr[ni][1] = *(const bf16x8*)&Bs[n][(32 + quad*8) ^ sz];
    }
    #pragma unroll
    for (int mi = 0; mi < 4; ++mi)
      #pragma unroll
      for (int ni = 0; ni < NF; ++ni){
        acc[mi][ni] = __builtin_amdgcn_mfma_f32_16x16x32_bf16(af[mi][0], bfr[ni][0], acc[mi][ni], 0, 0, 0);
        acc[mi][ni] = __builtin_amdgcn_mfma_f32_16x16x32_bf16(af[mi][1], bfr[ni][1], acc[mi][ni], 0, 0, 0);
      }
    __syncthreads();
  }
  #pragma unroll
  for (int mi = 0; mi < 4; ++mi){
    #pragma unroll
    for (int r = 0; r < 4; ++r){
      int row = row0 + wm + mi*16 + quad*4 + r;
      int bb = row / La, l = row - bb*La;
      size_t crow = ((size_t)bb*Lc + off + l)*(size_t)HD;
      #pragma unroll
      for (int ni = 0; ni < NF; ++ni){
        int col = col0 + wn + ni*16 + lm;
        int sel = (col >= 1536) ? 2 : (col >= 768 ? 1 : 0);
        int colr = col - sel*768;
        const void* bp = (sel == 0) ? b0 : (sel == 1) ? b1 : b2;
        u16* dst = (sel == 0) ? o0 : (sel == 1) ? o1 : o2;
        float vv = acc[mi][ni][r] + ldv(bp, bOff + colr, f32);
        dst[crow + colr] = f2b(vv);
      }
    }
  }
}

// ---------------- SIMT GEMM (bottleneck) ----------------
#define BM 64
#define BN 64
#define BK 16
__global__ __launch_bounds__(256)
void gemm_k(const float* __restrict__ A, const void* __restrict__ W, long long wOff,
            const void* __restrict__ bias, long long bOff,
            float* __restrict__ C, const u16* __restrict__ det, int K, int N)
{
  __shared__ float As2[BK][BM+4];
  __shared__ float Bs2[BK][BN+4];
  bool f32 = is_f32(det);
  int tid = threadIdx.x;
  int row0 = blockIdx.y * BM, col0 = blockIdx.x * BN;
  int ty = tid >> 4, tx = tid & 15;
  int lr = tid >> 2, lc4 = (tid & 3) << 2;
  int wr = tid >> 4, wc4 = (tid & 15) << 2;
  float acc[4][4] = {};
  for (int k0 = 0; k0 < K; k0 += BK){
    float4 av = *(const float4*)(A + (size_t)(row0 + lr)*K + k0 + lc4);
    As2[lc4+0][lr] = av.x; As2[lc4+1][lr] = av.y;
    As2[lc4+2][lr] = av.z; As2[lc4+3][lr] = av.w;
    float4 wv = ldv4(W, wOff + (long long)(k0 + wr)*N + col0 + wc4, f32);
    *(float4*)&Bs2[wr][wc4] = wv;
    __syncthreads();
    #pragma unroll
    for (int kk = 0; kk < BK; ++kk){
      float4 a  = *(const float4*)&As2[kk][ty << 2];
      float4 bb = *(const float4*)&Bs2[kk][tx << 2];
      acc[0][0] += a.x*bb.x; acc[0][1] += a.x*bb.y; acc[0][2] += a.x*bb.z; acc[0][3] += a.x*bb.w;
      acc[1][0] += a.y*bb.x; acc[1][1] += a.y*bb.y; acc[1][2] += a.y*bb.z; acc[1][3] += a.y*bb.w;
      acc[2][0] += a.z*bb.x; acc[2][1] += a.z*bb.y; acc[2][2] += a.z*bb.z; acc[2][3] += a.z*bb.w;
      acc[3][0] += a.w*bb.x; acc[3][1] += a.w*bb.y; acc[3][2] += a.w*bb.z; acc[3][3] += a.w*bb.w;
    }
    __syncthreads();
  }
  #pragma unroll
  for (int i = 0; i < 4; ++i){
    int r = row0 + (ty << 2) + i;
    size_t crow = (size_t)r*(size_t)N;
    #pragma unroll
    for (int j = 0; j < 4; ++j){
      int c = col0 + (tx << 2) + j;
      C[crow + c] = acc[i][j] + ldv(bias, bOff + c, f32);
    }
  }
}

// ---------------- conv weight reorder ----------------
__global__ void wc_kernel(const void* __restrict__ w, float* __restrict__ Wc,
                          const u16* __restrict__ det)
{
  bool f32 = is_f32(det);
  int idx = blockIdx.x * 256 + threadIdx.x;
  if (idx >= 3*512*128) return;
  int co = idx & 127;
  int kk = (idx >> 7) & 511;
  int lay = idx >> 16;
  int tt = kk >> 7, ci = kk & 127;
  Wc[idx] = ldv(w, (long long)lay*65536 + co*512 + ci*4 + tt, f32);
}

// ---------------- bottleneck conv as GEMM + BN + ELU ----------------
__global__ __launch_bounds__(256)
void conv_gemm(const float* __restrict__ in, int inStride, int inOff,
               float* __restrict__ out, int outStride, int outOff, int Lout,
               const float* __restrict__ Wc,
               const void* __restrict__ cb, const void* __restrict__ bg,
               const void* __restrict__ bb, const void* __restrict__ bm,
               const void* __restrict__ bv, const u16* __restrict__ det, int lay)
{
  __shared__ float As2[BK][BM+4];
  __shared__ float Bs2[BK][BN+4];
  bool f32 = is_f32(det);
  int tid = threadIdx.x;
  int row0 = blockIdx.y * BM, col0 = blockIdx.x * BN;
  int ty = tid >> 4, tx = tid & 15;
  int lr = tid >> 2, lc4 = (tid & 3) << 2;
  int wr = tid >> 4, wc4 = (tid & 15) << 2;
  int rs = row0 + lr;
  int bs = rs / Lout, js = rs - bs*Lout;
  const float* arow = in + ((size_t)(bs*inStride + inOff + js*4))*128;
  float acc[4][4] = {};
  for (int k0 = 0; k0 < 512; k0 += BK){
    float4 av = *(const float4*)(arow + k0 + lc4);
    As2[lc4+0][lr] = av.x; As2[lc4+1][lr] = av.y;
    As2[lc4+2][lr] = av.z; As2[lc4+3][lr] = av.w;
    float4 wv = *(const float4*)(Wc + (size_t)(k0 + wr)*128 + col0 + wc4);
    *(float4*)&Bs2[wr][wc4] = wv;
    __syncthreads();
    #pragma unroll
    for (int kk = 0; kk < BK; ++kk){
      float4 a  = *(const float4*)&As2[kk][ty << 2];
      float4 bb2 = *(const float4*)&Bs2[kk][tx << 2];
      acc[0][0] += a.x*bb2.x; acc[0][1] += a.x*bb2.y; acc[0][2] += a.x*bb2.z; acc[0][3] += a.x*bb2.w;
      acc[1][0] += a.y*bb2.x; acc[1][1] += a.y*bb2.y; acc[1][2] += a.y*bb2.z; acc[1][3] += a.y*bb2.w;
      acc[2][0] += a.z*bb2.x; acc[2][1] += a.z*bb2.y; acc[2][2] += a.z*bb2.z; acc[2][3] += a.z*bb2.w;
      acc[3][0] += a.w*bb2.x; acc[3][1] += a.w*bb2.y; acc[3][2] += a.w*bb2.z; acc[3][3] += a.w*bb2.w;
    }
    __syncthreads();
  }
  #pragma unroll
  for (int i = 0; i < 4; ++i){
    int r = row0 + (ty << 2) + i;
    int b = r / Lout, j = r - b*Lout;
    float* orow = out + ((size_t)(b*outStride + outOff + j))*128;
    #pragma unroll
    for (int jj = 0; jj < 4; ++jj){
      int co = col0 + (tx << 2) + jj;
      long long po = (long long)lay*128 + co;
      float a = acc[i][jj] + ldv(cb, po, f32);
      a = (a - ldv(bm, po, f32)) * rsqrtf(ldv(bv, po, f32) + 1e-5f) * ldv(bg, po, f32) + ldv(bb, po, f32);
      a = a > 0.f ? a : (__expf(a) - 1.f);
      orow[co] = a;
    }
  }
}

// ---------------- LayerNorm (4 rows/block, optional bf16 shadow) ----------------
__global__ __launch_bounds__(256)
void ln_kernel(const float* __restrict__ X, const void* __restrict__ g, long long gOff,
               const void* __restrict__ bt, long long bOff, float eps,
               float* __restrict__ Out, u16* __restrict__ OutB, const u16* __restrict__ det)
{
  bool f32 = is_f32(det);
  int row = blockIdx.x*4 + (threadIdx.x >> 6);
  int lane = threadIdx.x & 63;
  const float* xr = X + (size_t)row*DM;
  float v[8]; float s = 0.f;
  #pragma unroll
  for (int i = 0; i < 8; ++i){ v[i] = xr[lane + i*64]; s += v[i]; }
  #pragma unroll
  for (int o = 32; o > 0; o >>= 1) s += __shfl_xor(s, o);
  float mean = s * (1.f/512.f);
  float q = 0.f;
  #pragma unroll
  for (int i = 0; i < 8; ++i){ float d = v[i]-mean; q += d*d; }
  #pragma unroll
  for (int o = 32; o > 0; o >>= 1) q += __shfl_xor(q, o);
  float inv = rsqrtf(q*(1.f/512.f) + eps);
  float* orow = Out + (size_t)row*DM;
  #pragma unroll
  for (int i = 0; i < 8; ++i){
    int c = lane + i*64;
    float val = (v[i]-mean)*inv*ldv(g, gOff + c, f32) + ldv(bt, bOff + c, f32);
    orow[c] = val;
    if (OutB) OutB[(size_t)row*DM + c] = f2b(val);
  }
}

// ---------------- concat + LayerNorm(1e-5), 4 rows/block, optional shadow ----------------
__global__ __launch_bounds__(256)
void concat_ln_kernel(const float* __restrict__ emb, const float* __restrict__ up,
                      const void* __restrict__ g, const void* __restrict__ bt,
                      float* __restrict__ Out, u16* __restrict__ OutB, const u16* __restrict__ det)
{
  bool f32 = is_f32(det);
  int row = blockIdx.x*4 + (threadIdx.x >> 6);
  int lane = threadIdx.x & 63;
  int b = row / S1, l = row - b*S1;
  const float* xr = (l < L_IN) ? emb + ((size_t)(b*L_IN + l))*DM
                               : up  + ((size_t)(b*54 + (l - L_IN)))*DM;
  float v[8]; float s = 0.f;
  #pragma unroll
  for (int i = 0; i < 8; ++i){ v[i] = xr[lane + i*64]; s += v[i]; }
  #pragma unroll
  for (int o = 32; o > 0; o >>= 1) s += __shfl_xor(s, o);
  float mean = s * (1.f/512.f);
  float q = 0.f;
  #pragma unroll
  for (int i = 0; i < 8; ++i){ float d = v[i]-mean; q += d*d; }
  #pragma unroll
  for (int o = 32; o > 0; o >>= 1) q += __shfl_xor(q, o);
  float inv = rsqrtf(q*(1.f/512.f) + 1e-5f);
  float* orow = Out + (size_t)row*DM;
  #pragma unroll
  for (int i = 0; i < 8; ++i){
    int c = lane + i*64;
    float val = (v[i]-mean)*inv*ldv(g, c, f32) + ldv(bt, c, f32);
    orow[c] = val;
    if (OutB) OutB[(size_t)row*DM + c] = f2b(val);
  }
}

// ---------------- encoder attention: PAM-sparse, 16-lane unit per (b,q,h) ----------------
__global__ __launch_bounds__(256)
void attn_enc_sparse(u16* __restrict__ q, const u16* __restrict__ k,
                     const u16* __restrict__ v, const int* __restrict__ nbr)
{
  int u = blockIdx.x * 16 + (threadIdx.x >> 4);
  int lane16 = threadIdx.x & 15;
  int h = u % NHD;
  int bq = u / NHD;
  int b = bq / S1, qr = bq - b*S1;
  const float scale = 0.088388347648318447f;
  size_t rowoff = (size_t)bq*HD + h*DK + lane16*8;
  uint4 qw = *(const uint4*)(q + rowoff);
  float qd[8]; unpack8(qw, qd);
  const int* nb = nbr + qr*12;
  size_t base = (size_t)b*S1*HD + h*DK + lane16*8;
  float pj[12];
  #pragma unroll
  for (int j = 0; j < 12; ++j){
    int kg = nb[j];
    int kgc = kg < 0 ? 0 : kg;
    uint4 kw = *(const uint4*)(k + (size_t)kgc*HD + base);
    float kd[8]; unpack8(kw, kd);
    float p = qd[0]*kd[0] + qd[1]*kd[1] + qd[2]*kd[2] + qd[3]*kd[3]
            + qd[4]*kd[4] + qd[5]*kd[5] + qd[6]*kd[6] + qd[7]*kd[7];
    p += __shfl_xor(p, 1); p += __shfl_xor(p, 2);
    p += __shfl_xor(p, 4); p += __shfl_xor(p, 8);
    pj[j] = (kg >= 0) ? p*scale : -1e30f;
  }
  float m = -1e30f;
  #pragma unroll
  for (int j = 0; j < 12; ++j) m = fmaxf(m, pj[j]);
  float s = 0.f;
  #pragma unroll
  for (int j = 0; j < 12; ++j){ pj[j] = __expf(pj[j] - m); s += pj[j]; }
  float inv = 1.f / s;
  float o[8];
  #pragma unroll
  for (int i = 0; i < 8; ++i) o[i] = 0.f;
  #pragma unroll
  for (int j = 0; j < 12; ++j){
    int kg = nb[j];
    int kgc = kg < 0 ? 0 : kg;
    uint4 vw = *(const uint4*)(v + (size_t)kgc*HD + base);
    float vd[8]; unpack8(vw, vd);
    #pragma unroll
    for (int i = 0; i < 8; ++i) o[i] += pj[j]*vd[i];
  }
  uint4 ow;
  ow.x = pk2(o[0]*inv, o[1]*inv);
  ow.y = pk2(o[2]*inv, o[3]*inv);
  ow.z = pk2(o[4]*inv, o[5]*inv);
  ow.w = pk2(o[6]*inv, o[7]*inv);
  *(uint4*)(q + rowoff) = ow;
}

// ---------------- decoder attention: MFMA flash (v3) ----------------
// (a) reg-prefetch pipeline (T14); (b) XCD-coherent 1-D grid.
#define FQT 64
__global__ __launch_bounds__(256)
void attn_dec_mfma(u16* __restrict__ q, const u16* __restrict__ k,
                   const u16* __restrict__ v)
{
  __shared__ __align__(16) u16 Ks[32][136];
  __shared__ __align__(16) u32 Vt[16][132];
  __shared__ __align__(16) u32 Pls[4][16][16];
  int id = blockIdx.x;
  int qt = id / 384;
  int rem = id - qt*384;
  int h = rem >> 6;
  int b = rem & 63;
  int qt0 = qt * FQT;
  int tid = threadIdx.x;
  int wave = tid >> 6, lane = tid & 63;
  int lm = lane & 15, quad = lane >> 4;
  const float scale = 0.088388347648318447f;
  const size_t qb0 = (size_t)b*L_IN*HD + (size_t)h*DK;
  const size_t kb0 = (size_t)b*SKV*HD + (size_t)h*DK;

  bf16x8 qf[4];
  {
    int qg = qt0 + wave*16 + lm;
    if (qg < L_IN){
      #pragma unroll
      for (int ks = 0; ks < 4; ++ks)
        qf[ks] = *(const bf16x8*)(q + qb0 + (size_t)qg*HD + ks*32 + quad*8);
    } else {
      #pragma unroll
      for (int ks = 0; ks < 4; ++ks) qf[ks] = (bf16x8){0,0,0,0,0,0,0,0};
    }
  }

  float mold[4], lsum[4];
  #pragma unroll
  for (int r = 0; r < 4; ++r){ mold[r] = -1e30f; lsum[r] = 0.f; }
  f32x4v oacc[8];
  #pragma unroll
  for (int f = 0; f < 8; ++f) oacc[f] = (f32x4v){0.f,0.f,0.f,0.f};

  int kEnd = S1 + qt0 + FQT; if (kEnd > SKV) kEnd = SKV;
  int nt = (kEnd + 31) >> 5;

  ushort4 kr[4];
  ushort4 vr[2][2];
  {
    const int kt0 = 0;
    #pragma unroll
    for (int j = 0; j < 4; ++j){
      int i = tid*4 + j*1024;
      int kk = i >> 7, d = i & 127;
      int kg = kt0 + kk;
      kr[j] = make_ushort4(0,0,0,0);
      if (kg < SKV) kr[j] = *(const ushort4*)(k + kb0 + (size_t)kg*HD + d);
    }
    #pragma unroll
    for (int j = 0; j < 2; ++j){
      int t2 = tid + j*256;
      int g = t2 & 31, p = t2 >> 5;
      int d0 = g*4;
      int kg0 = kt0 + p, kg1 = kt0 + p + 16;
      vr[j][0] = make_ushort4(0,0,0,0);
      vr[j][1] = make_ushort4(0,0,0,0);
      if (kg0 < SKV) vr[j][0] = *(const ushort4*)(v + kb0 + (size_t)kg0*HD + d0);
      if (kg1 < SKV) vr[j][1] = *(const ushort4*)(v + kb0 + (size_t)kg1*HD + d0);
    }
  }

  for (int ti = 0; ti < nt; ++ti){
    int kt0 = ti << 5;
    __syncthreads();
    #pragma unroll
    for (int j = 0; j < 4; ++j){
      int i = tid*4 + j*1024;
      int kk = i >> 7, d = i & 127;
      *(ushort4*)&Ks[kk][d] = kr[j];
    }
    #pragma unroll
    for (int j = 0; j < 2; ++j){
      int t2 = tid + j*256;
      int g = t2 & 31, p = t2 >> 5;
      int d0 = g*4;
      uint4 o;
      o.x = (u32)vr[j][0].x | ((u32)vr[j][1].x << 16);
      o.y = (u32)vr[j][0].y | ((u32)vr[j][1].y << 16);
      o.z = (u32)vr[j][0].z | ((u32)vr[j][1].z << 16);
      o.w = (u32)vr[j][0].w | ((u32)vr[j][1].w << 16);
      *(uint4*)&Vt[p][d0] = o;
    }
    if (ti + 1 < nt){
      const int kn = (ti + 1) << 5;
      #pragma unroll
      for (int j = 0; j < 4; ++j){
        int i = tid*4 + j*1024;
        int kk = i >> 7, d = i & 127;
        int kg = kn + kk;
        kr[j] = make_ushort4(0,0,0,0);
        if (kg < SKV) kr[j] = *(const ushort4*)(k + kb0 + (size_t)kg*HD + d);
      }
      #pragma unroll
      for (int j = 0; j < 2; ++j){
        int t2 = tid + j*256;
        int g = t2 & 31, p = t2 >> 5;
        int d0 = g*4;
        int kg0 = kn + p, kg1 = kn + p + 16;
        vr[j][0] = make_ushort4(0,0,0,0);
        vr[j][1] = make_ushort4(0,0,0,0);
        if (kg0 < SKV) vr[j][0] = *(const ushort4*)(v + kb0 + (size_t)kg0*HD + d0);
        if (kg1 < SKV) vr[j][1] = *(const ushort4*)(v + kb0 + (size_t)kg1*HD + d0);
      }
    }
    __syncthreads();
    f32x4v sacc[2];
    sacc[0] = (f32x4v){0.f,0.f,0.f,0.f};
    sacc[1] = (f32x4v){0.f,0.f,0.f,0.f};
    #pragma unroll
    for (int t = 0; t < 2; ++t)
      #pragma unroll
      for (int ks = 0; ks < 4; ++ks){
        bf16x8 kf = *(const bf16x8*)&Ks[t*16 + lm][ks*32 + quad*8];
        sacc[t] = __builtin_amdgcn_mfma_f32_16x16x32_bf16(qf[ks], kf, sacc[t], 0, 0, 0);
      }
    float p[2][4];
    #pragma unroll
    for (int r = 0; r < 4; ++r){
      int qg = qt0 + wave*16 + quad*4 + r;
      float s0, s1;
      {
        int kg = kt0 + lm;
        bool ok = (kg < SKV) && (qg < L_IN) && (kg <= S1 + qg);
        s0 = ok ? sacc[0][r]*scale : -1e30f;
      }
      {
        int kg = kt0 + 16 + lm;
        bool ok = (kg < SKV) && (qg < L_IN) && (kg <= S1 + qg);
        s1 = ok ? sacc[1][r]*scale : -1e30f;
      }
      float mn = fmaxf(s0, s1);
      #pragma unroll
      for (int o = 8; o > 0; o >>= 1) mn = fmaxf(mn, __shfl_xor(mn, o));
      float mi = fmaxf(mold[r], mn);
      float alpha = __expf(mold[r] - mi);
      mold[r] = mi;
      p[0][r] = __expf(s0 - mi);
      p[1][r] = __expf(s1 - mi);
      float rs = p[0][r] + p[1][r];
      #pragma unroll
      for (int o = 8; o > 0; o >>= 1) rs += __shfl_xor(rs, o);
      lsum[r] = lsum[r]*alpha + rs;
      #pragma unroll
      for (int f = 0; f < 8; ++f) oacc[f][r] *= alpha;
    }
    #pragma unroll
    for (int r = 0; r < 4; ++r)
      Pls[wave][quad*4+r][lm] = pk2(p[0][r], p[1][r]);
    bf16x8 pa = *(const bf16x8*)&Pls[wave][lm][quad*4];
    #pragma unroll
    for (int f = 0; f < 8; ++f){
      union { u32 u[4]; bf16x8 v8; } vv;
      vv.u[0] = Vt[quad*4+0][f*16 + lm];
      vv.u[1] = Vt[quad*4+1][f*16 + lm];
      vv.u[2] = Vt[quad*4+2][f*16 + lm];
      vv.u[3] = Vt[quad*4+3][f*16 + lm];
      oacc[f] = __builtin_amdgcn_mfma_f32_16x16x32_bf16(pa, vv.v8, oacc[f], 0, 0, 0);
    }
  }
  #pragma unroll
  for (int r = 0; r < 4; ++r){
    int qg = qt0 + wave*16 + quad*4 + r;
    if (qg < L_IN){
      float inv = 1.f / lsum[r];
      #pragma unroll
      for (int f = 0; f < 8; ++f)
        q[qb0 + (size_t)qg*HD + f*16 + lm] = f2b(oacc[f][r]*inv);
    }
  }
}

// ---------------- prediction head: one wave per row, shfl-reduce ----------------
__global__ __launch_bounds__(256)
void pred_kernel(const float* __restrict__ X, const void* __restrict__ w,
                 void* __restrict__ out, const u16* __restrict__ det)
{
  bool f32 = is_f32(det);
  int row = blockIdx.x*4 + (threadIdx.x >> 6);
  int lane = threadIdx.x & 63;
  if (row >= BSZ*L_IN) return;
  const float* xr = X + (size_t)row*DM;
  float a0=0.f,a1=0.f,a2=0.f,a3=0.f,a4=0.f,a5=0.f,a6=0.f;
  #pragma unroll
  for (int i = 0; i < 8; ++i){
    int kk = lane + i*64;
    float xv = xr[kk];
    long long wo = (long long)kk*7;
    a0 += xv*ldv(w, wo+0, f32);
    a1 += xv*ldv(w, wo+1, f32);
    a2 += xv*ldv(w, wo+2, f32);
    a3 += xv*ldv(w, wo+3, f32);
    a4 += xv*ldv(w, wo+4, f32);
    a5 += xv*ldv(w, wo+5, f32);
    a6 += xv*ldv(w, wo+6, f32);
  }
  #pragma unroll
  for (int o = 32; o > 0; o >>= 1){
    a0 += __shfl_xor(a0, o); a1 += __shfl_xor(a1, o); a2 += __shfl_xor(a2, o);
    a3 += __shfl_xor(a3, o); a4 += __shfl_xor(a4, o); a5 += __shfl_xor(a5, o);
    a6 += __shfl_xor(a6, o);
  }
  if (lane == 0){
    long long o0 = (long long)row*7;
    if (f32){
      float* op = (float*)out;
      op[o0+0]=a0; op[o0+1]=a1; op[o0+2]=a2; op[o0+3]=a3;
      op[o0+4]=a4; op[o0+5]=a5; op[o0+6]=a6;
    } else {
      u16* op = (u16*)out;
      op[o0+0]=f2b(a0); op[o0+1]=f2b(a1); op[o0+2]=f2b(a2); op[o0+3]=f2b(a3);
      op[o0+4]=f2b(a4); op[o0+5]=f2b(a5); op[o0+6]=f2b(a6);
    }
  }
}

// ---------------- launch ----------------
extern "C" void kernel_launch(void* const* d_in, const int* in_sizes, int n_in,
                              void* d_out, int out_size, void* d_ws, size_t ws_size,
                              hipStream_t stream)
{
  (void)in_sizes; (void)n_in; (void)out_size;
  #define IN(i) ((const void*)d_in[i])
  const u16* det = (const u16*)d_in[20];
  float* ws   = (float*)d_ws;
  float* encx = ws + OFF_ENCX;
  float* decx = ws + OFF_DECX;
  u16*   qb   = (u16*)(ws + OFF_QB);
  u16*   kb   = (u16*)(ws + OFF_KB);
  u16*   vb   = (u16*)(ws + OFF_VB);
  int*   nbr  = (int*)(ws + OFF_NBR);
  bool haveShadow = ws_size >= WS_NEED;
  bool haveWtAll  = ws_size >= WS_NEED2;
  u16*   encb = haveShadow ? (u16*)(ws + OFF_ENCB) : nullptr;
  u16*   decb = haveShadow ? (u16*)(ws + OFF_DECB) : nullptr;
  u16*   WtAll = (u16*)(ws + OFF_WT);
  // phase-disjoint aliases (fallback path + temporaries)
  float* tmp1  = ws + OFF_VB;
  u16*   WtE3f = (u16*)(ws + OFF_VB + (size_t)BSZ*S1*DM);
  u16*   WtEOf = WtE3f + (size_t)2304*512;
  u16*   WtE1f = WtEOf + (size_t)768*512;
  u16*   WtE2f = WtE1f + (size_t)512*512;
  u16*   WtD3f = (u16*)(ws + OFF_QB + (size_t)BSZ*L_IN*HD/2);
  u16*   WtDOf = WtD3f + (size_t)2304*512;
  u16*   WtD1f = WtDOf + (size_t)768*512;
  u16*   WtD2f = WtD1f + (size_t)512*512;
  u16*   tmph  = (u16*)(ws + OFF_KB);
  float* embE  = ws + OFF_VB;
  float* Wc    = ws + OFF_QB;
  float* bdown = ws + OFF_KB;
  float* bconv = bdown + (size_t)BSZ*L_IN*128;
  float* bup   = bconv + (size_t)BSZ*54*128;

  const int RPe = 111, rpxE = 14;
  const int RPd = 84,  rpxD = 11;

  build_nbr_kernel<<<(S1*64 + 255)/256, 256, 0, stream>>>(nbr);
  if (haveWtAll)
    wt_all<<<8*2048, 256, 0, stream>>>(IN(22), IN(24), IN(26), IN(28), IN(32), IN(34),
                                       IN(38), IN(40), IN(42), IN(44), IN(48), IN(50),
                                       WtAll, det);

  embed_fast<<<1344, 256, 0, stream>>>(IN(0), IN(1), IN(4), IN(5), IN(6), det, embE, nullptr);
  embed_fast<<<1344, 256, 0, stream>>>(IN(2), IN(3), IN(7), IN(8), IN(9), det, decx, decb);

  // bottleneck
  wc_kernel<<<(3*512*128)/256, 256, 0, stream>>>(IN(12), Wc, det);
  gemm_k<<<dim3(128/BN, (BSZ*L_IN)/BM), 256, 0, stream>>>(
      embE, IN(10), 0, IN(11), 0, bdown, det, 512, 128);
  conv_gemm<<<dim3(2, (BSZ*42)/BM), 256, 0, stream>>>(
      bdown, L_IN, 0, bconv, 54, 0, 42, Wc, IN(13), IN(14), IN(15), IN(16), IN(17), det, 0);
  conv_gemm<<<dim3(2, (BSZ*10)/BM), 256, 0, stream>>>(
      bconv, 54, 0, bconv, 54, 42, 10, Wc + 65536, IN(13), IN(14), IN(15), IN(16), IN(17), det, 1);
  conv_gemm<<<dim3(2, (BSZ*2)/BM), 256, 0, stream>>>(
      bconv, 54, 42, bconv, 54, 52, 2, Wc + 131072, IN(13), IN(14), IN(15), IN(16), IN(17), det, 2);
  gemm_k<<<dim3(512/BN, (BSZ*54)/BM), 256, 0, stream>>>(
      bconv, IN(18), 0, IN(19), 0, bup, det, 128, 512);
  concat_ln_kernel<<<(BSZ*S1)/4, 256, 0, stream>>>(embE, bup, IN(20), IN(21), encx, encb, det);

  // encoder layers
  for (int i = 0; i < 6; ++i){
    long long wO = (long long)i*512*768, oO = (long long)i*768*512;
    long long bO = (long long)i*768, dO = (long long)i*512;
    long long fO = (long long)i*512*512;
    u16 *Wt3, *WtO, *Wt1, *Wt2;
    if (haveWtAll){
      u16* base = WtAll + (size_t)i*WT_SLOT;
      Wt3 = base;
      WtO = base + (size_t)2304*512;
      Wt1 = WtO + (size_t)512*768;
      Wt2 = Wt1 + (size_t)512*512;
    } else {
      wt_batch<<<2048, 256, 0, stream>>>(IN(22), IN(24), IN(26), IN(28), IN(32), IN(34),
                                         wO, oO, fO, WtE3f, WtEOf, WtE1f, WtE2f, det);
      Wt3 = WtE3f; WtO = WtEOf; Wt1 = WtE1f; Wt2 = WtE2f;
    }
    if (haveShadow)
      gemm_qkv<1,64><<<8*rpxE*36, 256, 0, stream>>>(
          encb, Wt3, IN(23), IN(25), IN(27), bO, qb, kb, vb, det, S1, S1, 0, RPe, 36, rpxE);
    else
      gemm_qkv<0,64><<<8*rpxE*36, 256, 0, stream>>>(
          encx, Wt3, IN(23), IN(25), IN(27), bO, qb, kb, vb, det, S1, S1, 0, RPe, 36, rpxE);
    attn_enc_sparse<<<(BSZ*S1*NHD)/16, 256, 0, stream>>>(qb, kb, vb, nbr);
    gemm_mfma<2,1,0,64><<<8*rpxE*8, 256, 0, stream>>>(
        qb, WtO, IN(29), dO, encx, tmp1, det, 768, 512, S1, S1, 0, RPe, 8, rpxE);
    ln_kernel<<<(BSZ*S1)/4, 256, 0, stream>>>(tmp1, IN(30), dO, IN(31), dO, 1e-6f, encx, encb, det);
    if (haveShadow)
      gemm_mfma<1,1,1,64><<<8*rpxE*8, 256, 0, stream>>>(
          encb, Wt1, IN(33), dO, nullptr, tmph, det, 512, 512, S1, S1, 0, RPe, 8, rpxE);
    else
      gemm_mfma<1,0,1,64><<<8*rpxE*8, 256, 0, stream>>>(
          encx, Wt1, IN(33), dO, nullptr, tmph, det, 512, 512, S1, S1, 0, RPe, 8, rpxE);
    gemm_mfma<2,1,0,64><<<8*rpxE*8, 256, 0, stream>>>(
        tmph, Wt2, IN(35), dO, encx, tmp1, det, 512, 512, S1, S1, 0, RPe, 8, rpxE);
    ln_kernel<<<(BSZ*S1)/4, 256, 0, stream>>>(tmp1, IN(36), dO, IN(37), dO, 1e-6f, encx, encb, det);
  }

  // decoder layers
  for (int i = 0; i < 2; ++i){
    long long wO = (long long)i*512*768, oO = (long long)i*768*512;
    long long bO = (long long)i*768, dO = (long long)i*512;
    long long fO = (long long)i*512*512;
    u16 *Wt3, *WtO, *Wt1, *Wt2;
    if (haveWtAll){
      u16* base = WtAll + (size_t)(6+i)*WT_SLOT;
      Wt3 = base;
      WtO = base + (size_t)2304*512;
      Wt1 = WtO + (size_t)512*768;
      Wt2 = Wt1 + (size_t)512*512;
    } else {
      wt_batch<<<2048, 256, 0, stream>>>(IN(38), IN(40), IN(42), IN(44), IN(48), IN(50),
                                         wO, oO, fO, WtD3f, WtDOf, WtD1f, WtD2f, det);
      Wt3 = WtD3f; WtO = WtDOf; Wt1 = WtD1f; Wt2 = WtD2f;
    }
    if (haveShadow){
      gemm_mfma<0,1,1,64><<<8*rpxD*12, 256, 0, stream>>>(
          decb, Wt3, IN(39), bO, nullptr, qb, det, 512, 768, L_IN, L_IN, 0, RPd, 12, rpxD);
      gemm_qkv<1,64><<<8*rpxE*24, 256, 0, stream>>>(
          encb, Wt3 + (size_t)768*512, IN(41), IN(43), IN(43), bO, kb, vb, vb, det, S1, SKV, 0, RPe, 24, rpxE);
      gemm_qkv<1,64><<<8*rpxD*24, 256, 0, stream>>>(
          decb, Wt3 + (size_t)768*512, IN(41), IN(43), IN(43), bO, kb, vb, vb, det, L_IN, SKV, S1, RPd, 24, rpxD);
    } else {
      gemm_mfma<0,0,1,64><<<8*rpxD*12, 256, 0, stream>>>(
          decx, Wt3, IN(39), bO, nullptr, qb, det, 512, 768, L_IN, L_IN, 0, RPd, 12, rpxD);
      gemm_qkv<0,64><<<8*rpxE*24, 256, 0, stream>>>(
          encx, Wt3 + (size_t)768*512, IN(41), IN(43), IN(43), bO, kb, vb, vb, det, S1, SKV, 0, RPe, 24, rpxE);
      gemm_qkv<0,64><<<8*rpxD*24, 256, 0, stream>>>(
          decx, Wt3 + (size_t)768*512, IN(41), IN(43), IN(43), bO, kb, vb, vb, det, L_IN, SKV, S1, RPd, 24, rpxD);
    }
    attn_dec_mfma<<<3*NHD*BSZ, 256, 0, stream>>>(qb, kb, vb);
    gemm_mfma<2,1,0,64><<<8*rpxD*8, 256, 0, stream>>>(
        qb, WtO, IN(45), dO, decx, tmp1, det, 768, 512, L_IN, L_IN, 0, RPd, 8, rpxD);
    ln_kernel<<<(BSZ*L_IN)/4, 256, 0, stream>>>(tmp1, IN(46), dO, IN(47), dO, 1e-6f, decx, decb, det);
    if (haveShadow)
      gemm_mfma<1,1,1,64><<<8*rpxD*8, 256, 0, stream>>>(
          decb, Wt1, IN(49), dO, nullptr, tmph, det, 512, 512, L_IN, L_IN, 0, RPd, 8, rpxD);
    else
      gemm_mfma<1,0,1,64><<<8*rpxD*8, 256, 0, stream>>>(
          decx, Wt1, IN(49), dO, nullptr, tmph, det, 512, 512, L_IN, L_IN, 0, RPd, 8, rpxD);
    gemm_mfma<2,1,0,64><<<8*rpxD*8, 256, 0, stream>>>(
        tmph, Wt2, IN(51), dO, decx, tmp1, det, 512, 512, L_IN, L_IN, 0, RPd, 8, rpxD);
    ln_kernel<<<(BSZ*L_IN)/4, 256, 0, stream>>>(tmp1, IN(52), dO, IN(53), dO, 1e-6f, decx, decb, det);
  }

  pred_kernel<<<((BSZ*L_IN+3)/4), 256, 0, stream>>>(decx, IN(54), d_out, det);
  #undef IN
}